// Round 1
// 957.173 us; speedup vs baseline: 1.0303x; 1.0303x over previous
//
#include <hip/hip_runtime.h>
#include <math.h>

#define BSZ 16
#define NPTS 2048
#define NG 128
#define GS 32
#define NBRK 38

typedef _Float16 f16;
typedef _Float16 f16x8 __attribute__((ext_vector_type(8)));
typedef float f32x4 __attribute__((ext_vector_type(4)));

// ---------- helpers ----------
__device__ __forceinline__ unsigned fkey(float x) {
    unsigned u = __float_as_uint(x);
    return (u >> 31) ? ~u : (u | 0x80000000u);
}
__device__ __forceinline__ float fkey_inv(unsigned k) {
    unsigned u = (k >> 31) ? (k ^ 0x80000000u) : ~k;
    return __uint_as_float(u);
}

// 64-lane min via DPP (no LDS/DS pipe): row_shr 1/2/4/8 prefix + row_bcast 15/31,
// then readlane 63 broadcasts the full-wave min. gfx9-lineage DPP (CDNA keeps it).
__device__ __forceinline__ unsigned wave_min_u32(unsigned v) {
    unsigned t;
    t = (unsigned)__builtin_amdgcn_update_dpp(-1, (int)v, 0x111, 0xF, 0xF, false);
    v = v < t ? v : t;
    t = (unsigned)__builtin_amdgcn_update_dpp(-1, (int)v, 0x112, 0xF, 0xF, false);
    v = v < t ? v : t;
    t = (unsigned)__builtin_amdgcn_update_dpp(-1, (int)v, 0x114, 0xF, 0xF, false);
    v = v < t ? v : t;
    t = (unsigned)__builtin_amdgcn_update_dpp(-1, (int)v, 0x118, 0xF, 0xF, false);
    v = v < t ? v : t;
    t = (unsigned)__builtin_amdgcn_update_dpp(-1, (int)v, 0x142, 0xA, 0xF, false);
    v = v < t ? v : t;
    t = (unsigned)__builtin_amdgcn_update_dpp(-1, (int)v, 0x143, 0xC, 0xF, false);
    v = v < t ? v : t;
    return (unsigned)__builtin_amdgcn_readlane((int)v, 63);
}

// 64-lane max via DPP, same structure (identity old-value = 0 for unsigned max).
__device__ __forceinline__ unsigned wave_max_u32(unsigned v) {
    unsigned t;
    t = (unsigned)__builtin_amdgcn_update_dpp(0, (int)v, 0x111, 0xF, 0xF, false);
    v = v > t ? v : t;
    t = (unsigned)__builtin_amdgcn_update_dpp(0, (int)v, 0x112, 0xF, 0xF, false);
    v = v > t ? v : t;
    t = (unsigned)__builtin_amdgcn_update_dpp(0, (int)v, 0x114, 0xF, 0xF, false);
    v = v > t ? v : t;
    t = (unsigned)__builtin_amdgcn_update_dpp(0, (int)v, 0x118, 0xF, 0xF, false);
    v = v > t ? v : t;
    t = (unsigned)__builtin_amdgcn_update_dpp(0, (int)v, 0x142, 0xA, 0xF, false);
    v = v > t ? v : t;
    t = (unsigned)__builtin_amdgcn_update_dpp(0, (int)v, 0x143, 0xC, 0xF, false);
    v = v > t ? v : t;
    return (unsigned)__builtin_amdgcn_readlane((int)v, 63);
}

// ---------- FPS v3: one wave per batch, zero barriers in the loop ----------
// 32 points/lane in registers; per iter: update mind + value-only max (8 ops/pt),
// DPP wave-max of the value (dist>=0 so bits|0x80000000 is monotonic), then a
// second pass finds the min global index with an exactly-equal mind (bit-exact
// == reference argmax first-occurrence tie-break), DPP wave-min of the index.
// Next center coords come from an LDS-staged copy (uniform broadcast read) --
// no dependent global gather, no __syncthreads, no ds_swizzle shuffle chain.
__global__ __launch_bounds__(64, 1) void fps_wave_kernel(const float* __restrict__ pts,
                                                         float* __restrict__ center) {
    int b = blockIdx.x;
    const float* P = pts + (size_t)b * NPTS * 3;
    int lane = threadIdx.x;          // 64 threads = exactly one wave
    __shared__ __align__(16) float Pl[NPTS * 3];
#pragma unroll
    for (int i = 0; i < 24; ++i) {   // 1536 float4 = 24 KB, coalesced
        int v4 = lane + i * 64;
        ((f32x4*)Pl)[v4] = ((const f32x4*)P)[v4];
    }
    __syncthreads();                 // single wave: cheap waitcnt+barrier
    float px[32], py[32], pz[32], mind[32];
#pragma unroll
    for (int m = 0; m < 32; ++m) {
        int j = lane + (m << 6);
        px[m] = Pl[j * 3 + 0];
        py[m] = Pl[j * 3 + 1];
        pz[m] = Pl[j * 3 + 2];
        mind[m] = 1e10f;
    }
    float cx = Pl[0], cy = Pl[1], cz = Pl[2];   // far = 0
    float* C = center + (size_t)b * NG * 3;
    for (int g = 0; g < NG; ++g) {
        if (lane == 0) {
            C[g * 3 + 0] = cx; C[g * 3 + 1] = cy; C[g * 3 + 2] = cz;
        }
        if (g == NG - 1) break;      // last selection is unused
        float best = -1.0f;
#pragma unroll
        for (int m = 0; m < 32; ++m) {
            float dx = px[m] - cx, dy = py[m] - cy, dz = pz[m] - cz;
            float d = dx * dx + dy * dy + dz * dz;
            float md = fminf(mind[m], d);
            mind[m] = md;
            best = fmaxf(best, md);
        }
        // dist >= 0 always, so | 0x80000000 is an order-preserving u32 key
        unsigned gkey = wave_max_u32(__float_as_uint(best) | 0x80000000u);
        float gbest = __uint_as_float(gkey & 0x7FFFFFFFu);
        unsigned bj = 0xFFFFFFFFu;
#pragma unroll
        for (int m = 0; m < 32; ++m) {
            unsigned j = (unsigned)(lane + (m << 6));
            if (mind[m] == gbest && j < bj) bj = j;   // ascending j: first match sticks
        }
        bj = wave_min_u32(bj);
        cx = Pl[bj * 3 + 0]; cy = Pl[bj * 3 + 1]; cz = Pl[bj * 3 + 2];  // uniform bcast
    }
}

// ---------- KNN v7: 32-bit packed keys + DPP wave-min, zero DS ops ----------
// key = (quantized_dist << 11) | idx ; u32 order == (d, idx) lex order up to the
// 1/8192 distance quantum (idx breaks quantized ties; matches stable top_k
// except between points closer than 1.2e-4 in squared distance -- negligible).
// Per-lane top-4 key cache + watermark refill (rare); wave per query; no barriers.
__global__ void knn_kernel_v7(const float* __restrict__ Q, int q_bstride, int q_off, int nq,
                              const float* __restrict__ DB, int k,
                              int* __restrict__ out, int nbatch) {
    const unsigned KINF = 0xFFFFFFFFu;
    int wave = threadIdx.x >> 6, lane = threadIdx.x & 63;
    int qidx = blockIdx.x * 4 + wave;
    if (qidx >= nbatch * nq) return;     // wave-uniform
    int b = qidx / nq, qi = qidx % nq;
    const float* q = Q + ((size_t)b * q_bstride + q_off + qi) * 3;
    float qx = q[0], qy = q[1], qz = q[2];
    float qq = qx * qx + qy * qy + qz * qz;
    const float* db = DB + (size_t)b * NPTS * 3;

    unsigned key[32];
    unsigned c0 = KINF, c1 = KINF, c2 = KINF, c3 = KINF;
#pragma unroll
    for (int m = 0; m < 32; ++m) {
        int j = lane + (m << 6);
        float bx = db[j * 3 + 0], by = db[j * 3 + 1], bz = db[j * 3 + 2];
        float dv = qq + bx * bx + by * by + bz * bz - 2.0f * (qx * bx + qy * by + qz * bz);
        unsigned qd = (unsigned)fminf(fmaxf(dv, 0.f) * 8192.0f, 2097151.f);
        unsigned kk = (qd << 11) | (unsigned)j;
        key[m] = kk;
        if (kk < c3) {
            if (kk < c2) {
                c3 = c2;
                if (kk < c1) {
                    c2 = c1;
                    if (kk < c0) { c1 = c0; c0 = kk; } else c1 = kk;
                } else c2 = kk;
            } else c3 = kk;
        }
    }
    unsigned hw = c3;        // high-water: largest key ever cached (init: 4th best)
    int ncached = 4;
    int* o = out + (size_t)qidx * k;

    for (int r = 0; r < k; ++r) {
        bool need = (c0 == KINF) && (ncached < 32);
        if (__any(need)) {
            unsigned best = KINF;
#pragma unroll
            for (int m = 0; m < 32; ++m) {
                unsigned v = key[m];
                best = (v > hw && v < best) ? v : best;
            }
            if (need) {
                c0 = best;
                hw = best;
                ncached = (best == KINF) ? 32 : ncached + 1;
            }
        }
        unsigned g = wave_min_u32(c0);
        if (lane == 0) o[r] = (int)(g & 0x7FFu);
        if (((g & 0x7FFu) & 63u) == (unsigned)lane) {  // owner pops its c0 (== g)
            c0 = c1; c1 = c2; c2 = c3; c3 = KINF;
        }
    }
}

// ---------- gather points via index array ----------
__global__ void gather_points_kernel(const float* __restrict__ pts, int db_bstride,
                                     const int* __restrict__ idx, int idx_bstride, int idx_off,
                                     int m, float* __restrict__ out, int nbatch) {
    int t = blockIdx.x * blockDim.x + threadIdx.x;
    if (t >= nbatch * m) return;
    int b = t / m, j = t % m;
    int s = idx[(size_t)b * idx_bstride + idx_off + j];
    const float* p = pts + ((size_t)b * db_bstride + s) * 3;
    out[(size_t)t * 3 + 0] = p[0];
    out[(size_t)t * 3 + 1] = p[1];
    out[(size_t)t * 3 + 2] = p[2];
}

// ---------- fp32 -> fp16 weight conversion (strided slice) ----------
__global__ void cvt_w_kernel(const float* __restrict__ in, int ld, int off, int K,
                             f16* __restrict__ out, int total) {
    int t = blockIdx.x * blockDim.x + threadIdx.x;
    if (t >= total) return;
    int n = t / K, k = t % K;
    out[t] = (f16)in[(size_t)n * ld + off + k];
}

// ---------- layer1: H1 = relu(bn(x @ W1^T + b1)) in fp16, fused ----------
__global__ void layer1_kernel(const float* __restrict__ X, const float* __restrict__ W1,
                              const float* __restrict__ b1, const float* __restrict__ g1,
                              const float* __restrict__ be1, const float* __restrict__ m1,
                              const float* __restrict__ v1, f16* __restrict__ H1, int M) {
    __shared__ float w[384], bb[128], sg[128], sb[128], sm[128], sv[128];
    for (int i = threadIdx.x; i < 384; i += 256) w[i] = W1[i];
    if (threadIdx.x < 128) {
        int c = threadIdx.x;
        bb[c] = b1[c]; sg[c] = g1[c]; sb[c] = be1[c]; sm[c] = m1[c]; sv[c] = v1[c];
    }
    __syncthreads();
    int t = blockIdx.x * 256 + threadIdx.x;
    if (t >= M * 16) return;
    int row = t >> 4, cg = (t & 15) * 8;
    float x0 = X[(size_t)row * 3], x1 = X[(size_t)row * 3 + 1], x2 = X[(size_t)row * 3 + 2];
    f16x8 outv;
#pragma unroll
    for (int j = 0; j < 8; ++j) {
        int c = cg + j;
        float tv = x0 * w[c * 3] + x1 * w[c * 3 + 1] + x2 * w[c * 3 + 2] + bb[c];
        float vv = (tv - sm[c]) * rsqrtf(sv[c] + 1e-5f) * sg[c] + sb[c];
        outv[j] = (f16)fmaxf(vv, 0.f);
    }
    *(f16x8*)&H1[(size_t)row * 128 + cg] = outv;
}

// ---------- MFMA GEMM ----------
__global__ __launch_bounds__(256) void mfma_gemm_kernel(
        const f16* __restrict__ A, const f16* __restrict__ W, int K, int N,
        const float* __restrict__ bias, const float* __restrict__ bias2d,
        const float* __restrict__ bng, const float* __restrict__ bnb,
        const float* __restrict__ bnm, const float* __restrict__ bnv,
        f16* __restrict__ Cout, unsigned* __restrict__ maxkey,
        int rows_per_batch, int relu) {
    __shared__ f16 Als[128 * 40];
    __shared__ f16 Bls[128 * 40];
    int tid = threadIdx.x;
    int lane = tid & 63;
    int wave = tid >> 6;
    int wm = wave & 1, wn = wave >> 1;
    int c16 = lane & 15, quad = lane >> 4;
    int row0 = blockIdx.y * 128, col0 = blockIdx.x * 128;
    int sr = tid >> 2;
    int skc = (tid & 3) * 8;

    f32x4 acc[4][4];
#pragma unroll
    for (int i = 0; i < 4; ++i)
#pragma unroll
        for (int j = 0; j < 4; ++j) acc[i][j] = (f32x4){0.f, 0.f, 0.f, 0.f};

    for (int k0 = 0; k0 < K; k0 += 32) {
#pragma unroll
        for (int i = 0; i < 2; ++i) {
            int r2 = sr + i * 64;
            f16x8 av = *(const f16x8*)(A + (size_t)(row0 + r2) * K + k0 + skc);
            *(f16x8*)&Als[r2 * 40 + skc] = av;
            f16x8 bv = *(const f16x8*)(W + (size_t)(col0 + r2) * K + k0 + skc);
            *(f16x8*)&Bls[r2 * 40 + skc] = bv;
        }
        __syncthreads();
        f16x8 af[4], bf[4];
#pragma unroll
        for (int s = 0; s < 4; ++s) {
            af[s] = *(const f16x8*)&Als[(wm * 64 + s * 16 + c16) * 40 + quad * 8];
            bf[s] = *(const f16x8*)&Bls[(wn * 64 + s * 16 + c16) * 40 + quad * 8];
        }
#pragma unroll
        for (int ms = 0; ms < 4; ++ms)
#pragma unroll
            for (int ns = 0; ns < 4; ++ns)
                acc[ms][ns] = __builtin_amdgcn_mfma_f32_16x16x32_f16(af[ms], bf[ns],
                                                                     acc[ms][ns], 0, 0, 0);
        __syncthreads();
    }

    int b = row0 / rows_per_batch;
#pragma unroll
    for (int ns = 0; ns < 4; ++ns) {
        int col = col0 + wn * 64 + ns * 16 + c16;
        float bv = bias ? bias[col] : 0.f;
        float b2v = bias2d ? bias2d[(size_t)b * N + col] : 0.f;
        float mx = -3e38f;
#pragma unroll
        for (int ms = 0; ms < 4; ++ms) {
#pragma unroll
            for (int j = 0; j < 4; ++j) {
                float v = acc[ms][ns][j] + bv + b2v;
                if (bng) v = (v - bnm[col]) * rsqrtf(bnv[col] + 1e-5f) * bng[col] + bnb[col];
                if (relu) v = fmaxf(v, 0.f);
                if (Cout)
                    Cout[(size_t)(row0 + wm * 64 + ms * 16 + quad * 4 + j) * N + col] = (f16)v;
                mx = fmaxf(mx, v);
            }
        }
        if (maxkey) {
            mx = fmaxf(mx, __shfl_xor(mx, 16, 64));
            mx = fmaxf(mx, __shfl_xor(mx, 32, 64));
            if (quad == 0) atomicMax(&maxkey[(size_t)b * N + col], fkey(mx));
        }
    }
}

// ---------- skinny GEMM v2: wave per column, coalesced float4 ----------
__global__ void skinny_v2_kernel(const float* __restrict__ A, const float* __restrict__ W,
                                 int ldw, int woff, const float* __restrict__ bias,
                                 float* __restrict__ C, int K, int N, int relu) {
    int wave = threadIdx.x >> 6, lane = threadIdx.x & 63;
    int col = blockIdx.x * 4 + wave;
    if (col >= N) return;
    const float* w = W + (size_t)col * ldw + woff;
    float acc[16];
#pragma unroll
    for (int m = 0; m < 16; ++m) acc[m] = 0.f;
    for (int k0 = 0; k0 < K; k0 += 256) {
        f32x4 wv = *(const f32x4*)(w + k0 + lane * 4);
#pragma unroll
        for (int m = 0; m < 16; ++m) {
            f32x4 av = *(const f32x4*)(A + (size_t)m * K + k0 + lane * 4);
            acc[m] += av[0] * wv[0] + av[1] * wv[1] + av[2] * wv[2] + av[3] * wv[3];
        }
    }
#pragma unroll
    for (int m = 0; m < 16; ++m)
#pragma unroll
        for (int s = 1; s < 64; s <<= 1) acc[m] += __shfl_xor(acc[m], s, 64);
    if (lane == 0) {
        float bv = bias[col];
#pragma unroll
        for (int m = 0; m < 16; ++m) {
            float v = acc[m] + bv;
            if (relu) v = fmaxf(v, 0.f);
            C[(size_t)m * N + col] = v;
        }
    }
}

__global__ void decode_kernel(const unsigned* __restrict__ k, float* __restrict__ f, int n) {
    int t = blockIdx.x * blockDim.x + threadIdx.x;
    if (t < n) f[t] = fkey_inv(k[t]);
}

// ---------- chamfer v2: 8 lanes per A-point, j-strided, shfl-min ----------
__global__ void chamfer_min_kernel(const float* __restrict__ A, int na,
                                   const float* __restrict__ Bp, int nb,
                                   float* __restrict__ slot) {
    int t = blockIdx.x * 256 + threadIdx.x;
    int pt = t >> 3, sl = t & 7;
    float val = 0.f;
    if (pt < BSZ * na) {
        int b = pt / na;
        const float* a = A + (size_t)pt * 3;
        float ax = a[0], ay = a[1], az = a[2];
        float aa = ax * ax + ay * ay + az * az;
        const float* Bb = Bp + (size_t)b * nb * 3;
        float m = 3e38f;
        for (int j = sl; j < nb; j += 8) {
            float bx = Bb[j * 3 + 0], by = Bb[j * 3 + 1], bz = Bb[j * 3 + 2];
            float d = aa + bx * bx + by * by + bz * bz - 2.0f * (ax * bx + ay * by + az * bz);
            m = fminf(m, d);
        }
#pragma unroll
        for (int s = 1; s < 8; s <<= 1) m = fminf(m, __shfl_xor(m, s, 64));
        if (sl == 0) val = sqrtf(fmaxf(m, 1e-12f));
    }
    __shared__ float sdata[256];
    sdata[threadIdx.x] = val;
    __syncthreads();
    for (int s = 128; s > 0; s >>= 1) {
        if (threadIdx.x < s) sdata[threadIdx.x] += sdata[threadIdx.x + s];
        __syncthreads();
    }
    if (threadIdx.x == 0) atomicAdd(slot, sdata[0]);
}

// ---------- smooth-L1 latent loss sum ----------
__global__ void latent_kernel(const float* __restrict__ f1, const float* __restrict__ f2,
                              int n, float* __restrict__ slot) {
    int t = blockIdx.x * blockDim.x + threadIdx.x;
    float val = 0.f;
    if (t < n) {
        float d = f1[t] - f2[t];
        float ad = fabsf(d);
        val = (ad < 1.f) ? (0.5f * d * d) : (ad - 0.5f);
    }
    __shared__ float sdata[256];
    sdata[threadIdx.x] = val;
    __syncthreads();
    for (int s = 128; s > 0; s >>= 1) {
        if (threadIdx.x < s) sdata[threadIdx.x] += sdata[threadIdx.x + s];
        __syncthreads();
    }
    if (threadIdx.x == 0) atomicAdd(slot, sdata[0]);
}

// ---------- 3x3 symmetric smallest eigenvector (double, analytic) ----------
__device__ void smallest_evec(double cxx, double cxy, double cxz,
                              double cyy, double cyz, double czz, double ev[3]) {
    double p1 = cxy * cxy + cxz * cxz + cyz * cyz;
    double q = (cxx + cyy + czz) / 3.0;
    double p2 = (cxx - q) * (cxx - q) + (cyy - q) * (cyy - q) + (czz - q) * (czz - q) + 2.0 * p1;
    double lam = q;
    if (p2 > 0.0) {
        double p = sqrt(p2 / 6.0);
        double b00 = (cxx - q) / p, b11 = (cyy - q) / p, b22 = (czz - q) / p;
        double b01 = cxy / p, b02 = cxz / p, b12 = cyz / p;
        double detB = b00 * (b11 * b22 - b12 * b12) - b01 * (b01 * b22 - b12 * b02)
                    + b02 * (b01 * b12 - b11 * b02);
        double r = detB * 0.5;
        r = r < -1.0 ? -1.0 : (r > 1.0 ? 1.0 : r);
        double phi = acos(r) / 3.0;
        lam = q + 2.0 * p * cos(phi + 2.0943951023931953);
    }
    double r0x = cxx - lam, r0y = cxy, r0z = cxz;
    double r1x = cxy, r1y = cyy - lam, r1z = cyz;
    double r2x = cxz, r2y = cyz, r2z = czz - lam;
    double c0x = r0y * r1z - r0z * r1y, c0y = r0z * r1x - r0x * r1z, c0z = r0x * r1y - r0y * r1x;
    double c1x = r0y * r2z - r0z * r2y, c1y = r0z * r2x - r0x * r2z, c1z = r0x * r2y - r0y * r2x;
    double c2x = r1y * r2z - r1z * r2y, c2y = r1z * r2x - r1x * r2z, c2z = r1x * r2y - r1y * r2x;
    double n0 = c0x * c0x + c0y * c0y + c0z * c0z;
    double n1 = c1x * c1x + c1y * c1y + c1z * c1z;
    double n2 = c2x * c2x + c2y * c2y + c2z * c2z;
    double bx = c0x, by = c0y, bz = c0z, bn = n0;
    if (n1 > bn) { bx = c1x; by = c1y; bz = c1z; bn = n1; }
    if (n2 > bn) { bx = c2x; by = c2y; bz = c2z; bn = n2; }
    if (bn < 1e-280) { ev[0] = 1.0; ev[1] = 0.0; ev[2] = 0.0; return; }
    double inv = 1.0 / sqrt(bn);
    ev[0] = bx * inv; ev[1] = by * inv; ev[2] = bz * inv;
}

// ---------- normals ----------
__global__ void normals_kernel(const float* __restrict__ pred, const int* __restrict__ knn,
                               float* __restrict__ nrm) {
    int t = blockIdx.x * blockDim.x + threadIdx.x;
    if (t >= BSZ * NPTS) return;
    int b = t / NPTS, i = t % NPTS;
    const float* P = pred + (size_t)b * NPTS * 3;
    const int* id = knn + (size_t)t * 32;
    float px[32], py[32], pz[32];
    double sx = 0, sy = 0, sz = 0;
    for (int k = 0; k < 32; ++k) {
        int j = id[k];
        px[k] = P[j * 3 + 0]; py[k] = P[j * 3 + 1]; pz[k] = P[j * 3 + 2];
        sx += px[k]; sy += py[k]; sz += pz[k];
    }
    double mx = sx / 32.0, my = sy / 32.0, mz = sz / 32.0;
    double cxx = 0, cxy = 0, cxz = 0, cyy = 0, cyz = 0, czz = 0;
    for (int k = 0; k < 32; ++k) {
        double dx = px[k] - mx, dy = py[k] - my, dz = pz[k] - mz;
        cxx += dx * dx; cxy += dx * dy; cxz += dx * dz;
        cyy += dy * dy; cyz += dy * dz; czz += dz * dz;
    }
    cxx /= 32.0; cxy /= 32.0; cxz /= 32.0; cyy /= 32.0; cyz /= 32.0; czz /= 32.0;
    double ev[3];
    smallest_evec(cxx, cxy, cxz, cyy, cyz, czz, ev);
    float qx = P[i * 3 + 0], qy = P[i * 3 + 1], qz = P[i * 3 + 2];
    double proj = 0.0;
    for (int k = 0; k < 32; ++k)
        proj += (px[k] - qx) * ev[0] + (py[k] - qy) * ev[1] + (pz[k] - qz) * ev[2];
    double s = (proj >= 0.0) ? 1.0 : -1.0;
    nrm[(size_t)t * 3 + 0] = (float)(ev[0] * s);
    nrm[(size_t)t * 3 + 1] = (float)(ev[1] * s);
    nrm[(size_t)t * 3 + 2] = (float)(ev[2] * s);
}

// ---------- manifold loss: reads first 8 of the 32-NN list ----------
__global__ void manifold_kernel(const float* __restrict__ nrm, const int* __restrict__ knn,
                                int kstride, float* __restrict__ slot) {
    int t = blockIdx.x * blockDim.x + threadIdx.x;
    float val = 0.f;
    if (t < BSZ * NPTS) {
        int b = t / NPTS;
        const float* NB = nrm + (size_t)b * NPTS * 3;
        const int* id = knn + (size_t)t * kstride;
        int j0 = id[0];
        float ax = NB[j0 * 3 + 0], ay = NB[j0 * 3 + 1], az = NB[j0 * 3 + 2];
        float an = fmaxf(sqrtf(ax * ax + ay * ay + az * az), 1e-6f);
        float x[8]; float s = 0.f;
        for (int k = 0; k < 8; ++k) {
            int j = id[k];
            float bx = NB[j * 3 + 0], by = NB[j * 3 + 1], bz = NB[j * 3 + 2];
            float bn_ = fmaxf(sqrtf(bx * bx + by * by + bz * bz), 1e-6f);
            float c = (ax * bx + ay * by + az * bz) / (an * bn_);
            x[k] = 1.f - c; s += x[k];
        }
        float mean = s / 8.f;
        float var = 0.f;
        for (int k = 0; k < 8; ++k) { float d = x[k] - mean; var += d * d; }
        val = sqrtf(var / 7.f);
    }
    __shared__ float sdata[256];
    sdata[threadIdx.x] = val;
    __syncthreads();
    for (int s2 = 128; s2 > 0; s2 >>= 1) {
        if (threadIdx.x < s2) sdata[threadIdx.x] += sdata[threadIdx.x + s2];
        __syncthreads();
    }
    if (threadIdx.x == 0) atomicAdd(slot, sdata[0]);
}

__global__ void finalize_kernel(const float* __restrict__ acc, float* __restrict__ out) {
    float l_recon = 0.5f * (acc[0] / (16.f * 2048.f) + acc[1] / (16.f * 2432.f));
    float l_match = 0.5f * (acc[2] / (16.f * 1024.f) + acc[3] / (16.f * 1216.f));
    float l_latent = acc[4] / (16.f * 1024.f);
    float l_man = 0.1f * (acc[5] / (16.f * 2048.f));
    out[0] = l_recon + l_match + l_latent + l_man;
    out[1] = l_recon;
    out[2] = l_match;
    out[3] = l_latent;
    out[4] = l_man;
}

// ================= host =================
extern "C" void kernel_launch(void* const* d_in, const int* in_sizes, int n_in,
                              void* d_out, int out_size, void* d_ws, size_t ws_size,
                              hipStream_t stream) {
    (void)in_sizes; (void)n_in; (void)out_size; (void)ws_size;
    const float* pts = (const float*)d_in[0];
    const float* W1 = (const float*)d_in[1];
    const float* b1 = (const float*)d_in[2];
    const float* g1 = (const float*)d_in[3];
    const float* be1 = (const float*)d_in[4];
    const float* m1 = (const float*)d_in[5];
    const float* v1 = (const float*)d_in[6];
    const float* W2 = (const float*)d_in[7];
    const float* b2 = (const float*)d_in[8];
    const float* W3 = (const float*)d_in[9];
    const float* b3 = (const float*)d_in[10];
    const float* g2 = (const float*)d_in[11];
    const float* be2 = (const float*)d_in[12];
    const float* m2 = (const float*)d_in[13];
    const float* v2 = (const float*)d_in[14];
    const float* W4 = (const float*)d_in[15];
    const float* b4 = (const float*)d_in[16];
    const float* D1W = (const float*)d_in[17];
    const float* D1b = (const float*)d_in[18];
    const float* D2W = (const float*)d_in[19];
    const float* D2b = (const float*)d_in[20];
    const float* D3W = (const float*)d_in[21];
    const float* D3b = (const float*)d_in[22];
    const float* D4W = (const float*)d_in[23];
    const float* D4b = (const float*)d_in[24];

    char* ws = (char*)d_ws;
    size_t off = 0;
    auto alloc = [&](size_t bytes) -> void* {
        void* p = ws + off;
        off += (bytes + 255) & ~(size_t)255;
        return p;
    };
    float* center   = (float*)alloc((size_t)BSZ * NG * 3 * 4);
    int*   knnc     = (int*)  alloc((size_t)BSZ * NG * GS * 4);
    float* rebuild0 = (float*)alloc((size_t)BSZ * 2048 * 3 * 4);
    float* rebuild1 = (float*)alloc((size_t)BSZ * 1024 * 3 * 4);
    f16*   W2h      = (f16*)  alloc((size_t)256 * 128 * 2);
    f16*   W3h      = (f16*)  alloc((size_t)512 * 256 * 2);
    f16*   W4h      = (f16*)  alloc((size_t)1024 * 512 * 2);
    f16*   H1h      = (f16*)  alloc((size_t)BSZ * 2048 * 128 * 2);
    f16*   H2h      = (f16*)  alloc((size_t)BSZ * 2048 * 256 * 2);
    f16*   H3h      = (f16*)  alloc((size_t)BSZ * 2048 * 512 * 2);
    unsigned* gmaxkey = (unsigned*)alloc((size_t)BSZ * 256 * 4);
    float* gmaxb    = (float*)alloc((size_t)BSZ * 256 * 4);
    float* gpart    = (float*)alloc((size_t)BSZ * 512 * 4);
    unsigned* featkey = (unsigned*)alloc((size_t)BSZ * 1024 * 4);
    float* feat     = (float*)alloc((size_t)BSZ * 1024 * 4);
    float* featrec  = (float*)alloc((size_t)BSZ * 1024 * 4);
    float* dh1      = (float*)alloc((size_t)BSZ * 2048 * 4);
    float* dh2      = (float*)alloc((size_t)BSZ * 2048 * 4);
    float* dh3      = (float*)alloc((size_t)BSZ * 2048 * 4);
    float* pred     = (float*)alloc((size_t)BSZ * 6144 * 4);
    int*   idxa     = (int*)  alloc((size_t)BSZ * 64 * NBRK * 4);
    float* gatha    = (float*)alloc((size_t)BSZ * 64 * NBRK * 3 * 4);
    int*   idxb     = (int*)  alloc((size_t)BSZ * 32 * NBRK * 4);
    float* gathb    = (float*)alloc((size_t)BSZ * 32 * NBRK * 3 * 4);
    int*   idxc     = (int*)  alloc((size_t)BSZ * 32 * 32 * 4);
    float* gathc    = (float*)alloc((size_t)BSZ * 1024 * 3 * 4);
    int*   knn32    = (int*)  alloc((size_t)BSZ * 2048 * 32 * 4);
    float* nrmbuf   = (float*)alloc((size_t)BSZ * 2048 * 3 * 4);
    float* accum    = (float*)alloc(8 * 4);

    hipMemsetAsync(accum, 0, 8 * 4, stream);

    cvt_w_kernel<<<(256 * 128 + 255) / 256, 256, 0, stream>>>(W2, 128, 0, 128, W2h, 256 * 128);
    cvt_w_kernel<<<(512 * 256 + 255) / 256, 256, 0, stream>>>(W3, 512, 256, 256, W3h, 512 * 256);
    cvt_w_kernel<<<(1024 * 512 + 255) / 256, 256, 0, stream>>>(W4, 512, 0, 512, W4h, 1024 * 512);

    auto knn = [&](const float* Q, int q_bstride, int q_off, int nq,
                   const float* DB, int k, int* out) {
        int total = BSZ * nq;
        knn_kernel_v7<<<(total + 3) / 4, 256, 0, stream>>>(Q, q_bstride, q_off, nq,
                                                           DB, k, out, BSZ);
    };

    // FPS + grouping
    fps_wave_kernel<<<BSZ, 64, 0, stream>>>(pts, center);
    knn(center, NG, 0, NG, pts, GS, knnc);
    gather_points_kernel<<<(BSZ * 2048 + 255) / 256, 256, 0, stream>>>(pts, NPTS, knnc, NG * GS,
                                                                       0, 2048, rebuild0, BSZ);
    gather_points_kernel<<<(BSZ * 1024 + 255) / 256, 256, 0, stream>>>(pts, NPTS, knnc, NG * GS,
                                                                       2048, 1024, rebuild1, BSZ);

    auto enc = [&](const float* X, int n, float* featout) {
        int M = BSZ * n;
        layer1_kernel<<<M / 16, 256, 0, stream>>>(X, W1, b1, g1, be1, m1, v1, H1h, M);
        hipMemsetAsync(gmaxkey, 0, (size_t)BSZ * 256 * 4, stream);
        mfma_gemm_kernel<<<dim3(256 / 128, M / 128), 256, 0, stream>>>(
            H1h, W2h, 128, 256, b2, nullptr, nullptr, nullptr, nullptr, nullptr,
            H2h, gmaxkey, n, 0);
        decode_kernel<<<(BSZ * 256 + 255) / 256, 256, 0, stream>>>(gmaxkey, gmaxb, BSZ * 256);
        skinny_v2_kernel<<<(512 + 3) / 4, 256, 0, stream>>>(gmaxb, W3, 512, 0, b3,
                                                            gpart, 256, 512, 0);
        mfma_gemm_kernel<<<dim3(512 / 128, M / 128), 256, 0, stream>>>(
            H2h, W3h, 256, 512, nullptr, gpart, g2, be2, m2, v2, H3h, nullptr, n, 1);
        hipMemsetAsync(featkey, 0, (size_t)BSZ * 1024 * 4, stream);
        mfma_gemm_kernel<<<dim3(1024 / 128, M / 128), 256, 0, stream>>>(
            H3h, W4h, 512, 1024, b4, nullptr, nullptr, nullptr, nullptr, nullptr,
            nullptr, featkey, n, 0);
        decode_kernel<<<(BSZ * 1024 + 255) / 256, 256, 0, stream>>>(featkey, featout, BSZ * 1024);
    };

    enc(rebuild0, 2048, feat);

    // decoder (skinny M=16, fp32, coalesced)
    skinny_v2_kernel<<<2048 / 4, 256, 0, stream>>>(feat, D1W, 1024, 0, D1b, dh1, 1024, 2048, 1);
    skinny_v2_kernel<<<2048 / 4, 256, 0, stream>>>(dh1, D2W, 2048, 0, D2b, dh2, 2048, 2048, 1);
    skinny_v2_kernel<<<2048 / 4, 256, 0, stream>>>(dh2, D3W, 2048, 0, D3b, dh3, 2048, 2048, 1);
    skinny_v2_kernel<<<6144 / 4, 256, 0, stream>>>(dh3, D4W, 2048, 0, D4b, pred, 2048, 6144, 0);

    // l_recon
    knn(center, NG, 0, 64, pred, NBRK, idxa);
    gather_points_kernel<<<(BSZ * 2432 + 255) / 256, 256, 0, stream>>>(pred, 2048, idxa, 64 * NBRK,
                                                                       0, 2432, gatha, BSZ);
    chamfer_min_kernel<<<(BSZ * 2048 * 8 + 255) / 256, 256, 0, stream>>>(rebuild0, 2048,
                                                                         gatha, 2432, accum + 0);
    chamfer_min_kernel<<<(BSZ * 2432 * 8 + 255) / 256, 256, 0, stream>>>(gatha, 2432,
                                                                         rebuild0, 2048, accum + 1);
    // l_match
    knn(center, NG, 64, 32, pred, NBRK, idxb);
    gather_points_kernel<<<(BSZ * 1216 + 255) / 256, 256, 0, stream>>>(pred, 2048, idxb, 32 * NBRK,
                                                                       0, 1216, gathb, BSZ);
    chamfer_min_kernel<<<(BSZ * 1024 * 8 + 255) / 256, 256, 0, stream>>>(rebuild1, 1024,
                                                                         gathb, 1216, accum + 2);
    chamfer_min_kernel<<<(BSZ * 1216 * 8 + 255) / 256, 256, 0, stream>>>(gathb, 1216,
                                                                         rebuild1, 1024, accum + 3);
    // l_latent
    knn(center, NG, 96, 32, pred, 32, idxc);
    gather_points_kernel<<<(BSZ * 1024 + 255) / 256, 256, 0, stream>>>(pred, 2048, idxc, 32 * 32,
                                                                       0, 1024, gathc, BSZ);
    enc(gathc, 1024, featrec);
    latent_kernel<<<(BSZ * 1024 + 255) / 256, 256, 0, stream>>>(feat, featrec, BSZ * 1024,
                                                                accum + 4);
    // l_man: one self-KNN (k=32); manifold uses first 8 (stable top-k prefix)
    knn(pred, 2048, 0, 2048, pred, 32, knn32);
    normals_kernel<<<(BSZ * 2048 + 255) / 256, 256, 0, stream>>>(pred, knn32, nrmbuf);
    manifold_kernel<<<(BSZ * 2048 + 255) / 256, 256, 0, stream>>>(nrmbuf, knn32, 32, accum + 5);

    finalize_kernel<<<1, 1, 0, stream>>>(accum, (float*)d_out);
}

// Round 2
// 947.780 us; speedup vs baseline: 1.0405x; 1.0099x over previous
//
#include <hip/hip_runtime.h>
#include <math.h>

#define BSZ 16
#define NPTS 2048
#define NG 128
#define GS 32
#define NBRK 38

typedef _Float16 f16;
typedef _Float16 f16x8 __attribute__((ext_vector_type(8)));
typedef float f32x4 __attribute__((ext_vector_type(4)));
typedef float f32x2 __attribute__((ext_vector_type(2)));

// ---------- helpers ----------
__device__ __forceinline__ unsigned fkey(float x) {
    unsigned u = __float_as_uint(x);
    return (u >> 31) ? ~u : (u | 0x80000000u);
}
__device__ __forceinline__ float fkey_inv(unsigned k) {
    unsigned u = (k >> 31) ? (k ^ 0x80000000u) : ~k;
    return __uint_as_float(u);
}

// 64-lane min via DPP (no LDS/DS pipe): row_shr 1/2/4/8 prefix + row_bcast 15/31,
// then readlane 63 broadcasts the full-wave min. gfx9-lineage DPP (CDNA keeps it).
__device__ __forceinline__ unsigned wave_min_u32(unsigned v) {
    unsigned t;
    t = (unsigned)__builtin_amdgcn_update_dpp(-1, (int)v, 0x111, 0xF, 0xF, false);
    v = v < t ? v : t;
    t = (unsigned)__builtin_amdgcn_update_dpp(-1, (int)v, 0x112, 0xF, 0xF, false);
    v = v < t ? v : t;
    t = (unsigned)__builtin_amdgcn_update_dpp(-1, (int)v, 0x114, 0xF, 0xF, false);
    v = v < t ? v : t;
    t = (unsigned)__builtin_amdgcn_update_dpp(-1, (int)v, 0x118, 0xF, 0xF, false);
    v = v < t ? v : t;
    t = (unsigned)__builtin_amdgcn_update_dpp(-1, (int)v, 0x142, 0xA, 0xF, false);
    v = v < t ? v : t;
    t = (unsigned)__builtin_amdgcn_update_dpp(-1, (int)v, 0x143, 0xC, 0xF, false);
    v = v < t ? v : t;
    return (unsigned)__builtin_amdgcn_readlane((int)v, 63);
}

// 64-lane max of a u64 key via DPP: one chain handles (value, tiebreak) packed.
// old=0 is the identity for unsigned max; v_cmp_gt_u64 + 2 cndmask per step.
__device__ __forceinline__ unsigned long long wave_max_u64(unsigned long long v) {
#define DPPSTEP(ctrl, rmask)                                                                \
    {                                                                                       \
        unsigned tlo = (unsigned)__builtin_amdgcn_update_dpp(0, (int)(unsigned)v, ctrl,     \
                                                             rmask, 0xF, false);            \
        unsigned thi = (unsigned)__builtin_amdgcn_update_dpp(0, (int)(unsigned)(v >> 32),   \
                                                             ctrl, rmask, 0xF, false);      \
        unsigned long long t = ((unsigned long long)thi << 32) | tlo;                       \
        v = t > v ? t : v;                                                                  \
    }
    DPPSTEP(0x111, 0xF)
    DPPSTEP(0x112, 0xF)
    DPPSTEP(0x114, 0xF)
    DPPSTEP(0x118, 0xF)
    DPPSTEP(0x142, 0xA)
    DPPSTEP(0x143, 0xC)
#undef DPPSTEP
    unsigned rlo = (unsigned)__builtin_amdgcn_readlane((int)(unsigned)v, 63);
    unsigned rhi = (unsigned)__builtin_amdgcn_readlane((int)(unsigned)(v >> 32), 63);
    return ((unsigned long long)rhi << 32) | rlo;
}

// ---------- FPS v4: packed-f32 math + fused argmax, single u64 DPP reduce ----------
// One wave per batch, 32 points/lane in registers (as 16 f32x2 pairs -> v_pk_*).
// Per iter: packed distance update; argmax tracked inline via 4 independent
// (best, m) chains (cmp + cndmask with inline-const m); chains combined with
// exact (value desc, m asc) tie-break; cross-lane via ONE 6-step u64 DPP max on
// key = (float_bits(best) << 32) | ~j  -> (max value, min global index), matching
// the reference argmax first-occurrence semantics bit-exactly (same arithmetic).
// New center coords come from a uniform LDS broadcast read. No barriers in loop.
__global__ __launch_bounds__(64, 1) void fps_wave_kernel(const float* __restrict__ pts,
                                                         float* __restrict__ center) {
    int b = blockIdx.x;
    const float* P = pts + (size_t)b * NPTS * 3;
    int lane = threadIdx.x;          // 64 threads = exactly one wave
    __shared__ __align__(16) float Pl[NPTS * 3];
#pragma unroll
    for (int i = 0; i < 24; ++i) {   // 1536 float4 = 24 KB, coalesced
        int v4 = lane + i * 64;
        ((f32x4*)Pl)[v4] = ((const f32x4*)P)[v4];
    }
    __syncthreads();                 // single wave: cheap waitcnt+barrier
    f32x2 px2[16], py2[16], pz2[16], mind2[16];
#pragma unroll
    for (int m2 = 0; m2 < 16; ++m2) {
        int j0 = lane + (2 * m2) * 64, j1 = lane + (2 * m2 + 1) * 64;
        px2[m2] = (f32x2){Pl[j0 * 3 + 0], Pl[j1 * 3 + 0]};
        py2[m2] = (f32x2){Pl[j0 * 3 + 1], Pl[j1 * 3 + 1]};
        pz2[m2] = (f32x2){Pl[j0 * 3 + 2], Pl[j1 * 3 + 2]};
        mind2[m2] = (f32x2){1e10f, 1e10f};
    }
    float cx = Pl[0], cy = Pl[1], cz = Pl[2];   // far = 0
    float* C = center + (size_t)b * NG * 3;
#pragma unroll 1
    for (int g = 0; g < NG; ++g) {
        if (lane == 0) {
            C[g * 3 + 0] = cx; C[g * 3 + 1] = cy; C[g * 3 + 2] = cz;
        }
        if (g == NG - 1) break;      // last selection is unused
        f32x2 cxx = (f32x2){cx, cx}, cyy = (f32x2){cy, cy}, czz = (f32x2){cz, cz};
        float best[4] = {-1.f, -1.f, -1.f, -1.f};
        int bm[4] = {0, 0, 0, 0};
#pragma unroll
        for (int m2 = 0; m2 < 16; ++m2) {
            f32x2 dx = px2[m2] - cxx, dy = py2[m2] - cyy, dz = pz2[m2] - czz;
            f32x2 d = dx * dx + dy * dy + dz * dz;   // v_pk_mul + 2x v_pk_fma
            float md0 = fminf(mind2[m2][0], d[0]);
            float md1 = fminf(mind2[m2][1], d[1]);
            mind2[m2][0] = md0;
            mind2[m2][1] = md1;
            int c0 = (m2 & 1) * 2, c1 = c0 + 1;      // 4 independent dep chains
            if (md0 > best[c0]) { best[c0] = md0; bm[c0] = 2 * m2; }      // strict >:
            if (md1 > best[c1]) { best[c1] = md1; bm[c1] = 2 * m2 + 1; }  // keeps min m
        }
        // combine chains: value desc, tie -> smaller m (exact argmax order)
        float bv = best[0]; int bi = bm[0];
#pragma unroll
        for (int c = 1; c < 4; ++c) {
            bool t = (best[c] > bv) || (best[c] == bv && bm[c] < bi);
            bv = t ? best[c] : bv;
            bi = t ? bm[c] : bi;
        }
        unsigned j = (unsigned)(lane + (bi << 6));
        // bv >= 0 so float bits order as u32; ~j makes u64-max pick min index on ties
        unsigned long long key =
            ((unsigned long long)__float_as_uint(bv) << 32) | (unsigned)(~j);
        key = wave_max_u64(key);
        unsigned bj = ~(unsigned)key;
        cx = Pl[bj * 3 + 0]; cy = Pl[bj * 3 + 1]; cz = Pl[bj * 3 + 2];  // uniform bcast
    }
}

// ---------- KNN v7: 32-bit packed keys + DPP wave-min, zero DS ops ----------
// key = (quantized_dist << 11) | idx ; u32 order == (d, idx) lex order up to the
// 1/8192 distance quantum (idx breaks quantized ties; matches stable top_k
// except between points closer than 1.2e-4 in squared distance -- negligible).
// Per-lane top-4 key cache + watermark refill (rare); wave per query; no barriers.
__global__ void knn_kernel_v7(const float* __restrict__ Q, int q_bstride, int q_off, int nq,
                              const float* __restrict__ DB, int k,
                              int* __restrict__ out, int nbatch) {
    const unsigned KINF = 0xFFFFFFFFu;
    int wave = threadIdx.x >> 6, lane = threadIdx.x & 63;
    int qidx = blockIdx.x * 4 + wave;
    if (qidx >= nbatch * nq) return;     // wave-uniform
    int b = qidx / nq, qi = qidx % nq;
    const float* q = Q + ((size_t)b * q_bstride + q_off + qi) * 3;
    float qx = q[0], qy = q[1], qz = q[2];
    float qq = qx * qx + qy * qy + qz * qz;
    const float* db = DB + (size_t)b * NPTS * 3;

    unsigned key[32];
    unsigned c0 = KINF, c1 = KINF, c2 = KINF, c3 = KINF;
#pragma unroll
    for (int m = 0; m < 32; ++m) {
        int j = lane + (m << 6);
        float bx = db[j * 3 + 0], by = db[j * 3 + 1], bz = db[j * 3 + 2];
        float dv = qq + bx * bx + by * by + bz * bz - 2.0f * (qx * bx + qy * by + qz * bz);
        unsigned qd = (unsigned)fminf(fmaxf(dv, 0.f) * 8192.0f, 2097151.f);
        unsigned kk = (qd << 11) | (unsigned)j;
        key[m] = kk;
        if (kk < c3) {
            if (kk < c2) {
                c3 = c2;
                if (kk < c1) {
                    c2 = c1;
                    if (kk < c0) { c1 = c0; c0 = kk; } else c1 = kk;
                } else c2 = kk;
            } else c3 = kk;
        }
    }
    unsigned hw = c3;        // high-water: largest key ever cached (init: 4th best)
    int ncached = 4;
    int* o = out + (size_t)qidx * k;

    for (int r = 0; r < k; ++r) {
        bool need = (c0 == KINF) && (ncached < 32);
        if (__any(need)) {
            unsigned best = KINF;
#pragma unroll
            for (int m = 0; m < 32; ++m) {
                unsigned v = key[m];
                best = (v > hw && v < best) ? v : best;
            }
            if (need) {
                c0 = best;
                hw = best;
                ncached = (best == KINF) ? 32 : ncached + 1;
            }
        }
        unsigned g = wave_min_u32(c0);
        if (lane == 0) o[r] = (int)(g & 0x7FFu);
        if (((g & 0x7FFu) & 63u) == (unsigned)lane) {  // owner pops its c0 (== g)
            c0 = c1; c1 = c2; c2 = c3; c3 = KINF;
        }
    }
}

// ---------- gather points via index array ----------
__global__ void gather_points_kernel(const float* __restrict__ pts, int db_bstride,
                                     const int* __restrict__ idx, int idx_bstride, int idx_off,
                                     int m, float* __restrict__ out, int nbatch) {
    int t = blockIdx.x * blockDim.x + threadIdx.x;
    if (t >= nbatch * m) return;
    int b = t / m, j = t % m;
    int s = idx[(size_t)b * idx_bstride + idx_off + j];
    const float* p = pts + ((size_t)b * db_bstride + s) * 3;
    out[(size_t)t * 3 + 0] = p[0];
    out[(size_t)t * 3 + 1] = p[1];
    out[(size_t)t * 3 + 2] = p[2];
}

// ---------- fp32 -> fp16 weight conversion (strided slice) ----------
__global__ void cvt_w_kernel(const float* __restrict__ in, int ld, int off, int K,
                             f16* __restrict__ out, int total) {
    int t = blockIdx.x * blockDim.x + threadIdx.x;
    if (t >= total) return;
    int n = t / K, k = t % K;
    out[t] = (f16)in[(size_t)n * ld + off + k];
}

// ---------- layer1: H1 = relu(bn(x @ W1^T + b1)) in fp16, fused ----------
__global__ void layer1_kernel(const float* __restrict__ X, const float* __restrict__ W1,
                              const float* __restrict__ b1, const float* __restrict__ g1,
                              const float* __restrict__ be1, const float* __restrict__ m1,
                              const float* __restrict__ v1, f16* __restrict__ H1, int M) {
    __shared__ float w[384], bb[128], sg[128], sb[128], sm[128], sv[128];
    for (int i = threadIdx.x; i < 384; i += 256) w[i] = W1[i];
    if (threadIdx.x < 128) {
        int c = threadIdx.x;
        bb[c] = b1[c]; sg[c] = g1[c]; sb[c] = be1[c]; sm[c] = m1[c]; sv[c] = v1[c];
    }
    __syncthreads();
    int t = blockIdx.x * 256 + threadIdx.x;
    if (t >= M * 16) return;
    int row = t >> 4, cg = (t & 15) * 8;
    float x0 = X[(size_t)row * 3], x1 = X[(size_t)row * 3 + 1], x2 = X[(size_t)row * 3 + 2];
    f16x8 outv;
#pragma unroll
    for (int j = 0; j < 8; ++j) {
        int c = cg + j;
        float tv = x0 * w[c * 3] + x1 * w[c * 3 + 1] + x2 * w[c * 3 + 2] + bb[c];
        float vv = (tv - sm[c]) * rsqrtf(sv[c] + 1e-5f) * sg[c] + sb[c];
        outv[j] = (f16)fmaxf(vv, 0.f);
    }
    *(f16x8*)&H1[(size_t)row * 128 + cg] = outv;
}

// ---------- MFMA GEMM ----------
__global__ __launch_bounds__(256) void mfma_gemm_kernel(
        const f16* __restrict__ A, const f16* __restrict__ W, int K, int N,
        const float* __restrict__ bias, const float* __restrict__ bias2d,
        const float* __restrict__ bng, const float* __restrict__ bnb,
        const float* __restrict__ bnm, const float* __restrict__ bnv,
        f16* __restrict__ Cout, unsigned* __restrict__ maxkey,
        int rows_per_batch, int relu) {
    __shared__ f16 Als[128 * 40];
    __shared__ f16 Bls[128 * 40];
    int tid = threadIdx.x;
    int lane = tid & 63;
    int wave = tid >> 6;
    int wm = wave & 1, wn = wave >> 1;
    int c16 = lane & 15, quad = lane >> 4;
    int row0 = blockIdx.y * 128, col0 = blockIdx.x * 128;
    int sr = tid >> 2;
    int skc = (tid & 3) * 8;

    f32x4 acc[4][4];
#pragma unroll
    for (int i = 0; i < 4; ++i)
#pragma unroll
        for (int j = 0; j < 4; ++j) acc[i][j] = (f32x4){0.f, 0.f, 0.f, 0.f};

    for (int k0 = 0; k0 < K; k0 += 32) {
#pragma unroll
        for (int i = 0; i < 2; ++i) {
            int r2 = sr + i * 64;
            f16x8 av = *(const f16x8*)(A + (size_t)(row0 + r2) * K + k0 + skc);
            *(f16x8*)&Als[r2 * 40 + skc] = av;
            f16x8 bv = *(const f16x8*)(W + (size_t)(col0 + r2) * K + k0 + skc);
            *(f16x8*)&Bls[r2 * 40 + skc] = bv;
        }
        __syncthreads();
        f16x8 af[4], bf[4];
#pragma unroll
        for (int s = 0; s < 4; ++s) {
            af[s] = *(const f16x8*)&Als[(wm * 64 + s * 16 + c16) * 40 + quad * 8];
            bf[s] = *(const f16x8*)&Bls[(wn * 64 + s * 16 + c16) * 40 + quad * 8];
        }
#pragma unroll
        for (int ms = 0; ms < 4; ++ms)
#pragma unroll
            for (int ns = 0; ns < 4; ++ns)
                acc[ms][ns] = __builtin_amdgcn_mfma_f32_16x16x32_f16(af[ms], bf[ns],
                                                                     acc[ms][ns], 0, 0, 0);
        __syncthreads();
    }

    int b = row0 / rows_per_batch;
#pragma unroll
    for (int ns = 0; ns < 4; ++ns) {
        int col = col0 + wn * 64 + ns * 16 + c16;
        float bv = bias ? bias[col] : 0.f;
        float b2v = bias2d ? bias2d[(size_t)b * N + col] : 0.f;
        float mx = -3e38f;
#pragma unroll
        for (int ms = 0; ms < 4; ++ms) {
#pragma unroll
            for (int j = 0; j < 4; ++j) {
                float v = acc[ms][ns][j] + bv + b2v;
                if (bng) v = (v - bnm[col]) * rsqrtf(bnv[col] + 1e-5f) * bng[col] + bnb[col];
                if (relu) v = fmaxf(v, 0.f);
                if (Cout)
                    Cout[(size_t)(row0 + wm * 64 + ms * 16 + quad * 4 + j) * N + col] = (f16)v;
                mx = fmaxf(mx, v);
            }
        }
        if (maxkey) {
            mx = fmaxf(mx, __shfl_xor(mx, 16, 64));
            mx = fmaxf(mx, __shfl_xor(mx, 32, 64));
            if (quad == 0) atomicMax(&maxkey[(size_t)b * N + col], fkey(mx));
        }
    }
}

// ---------- skinny GEMM v2: wave per column, coalesced float4 ----------
__global__ void skinny_v2_kernel(const float* __restrict__ A, const float* __restrict__ W,
                                 int ldw, int woff, const float* __restrict__ bias,
                                 float* __restrict__ C, int K, int N, int relu) {
    int wave = threadIdx.x >> 6, lane = threadIdx.x & 63;
    int col = blockIdx.x * 4 + wave;
    if (col >= N) return;
    const float* w = W + (size_t)col * ldw + woff;
    float acc[16];
#pragma unroll
    for (int m = 0; m < 16; ++m) acc[m] = 0.f;
    for (int k0 = 0; k0 < K; k0 += 256) {
        f32x4 wv = *(const f32x4*)(w + k0 + lane * 4);
#pragma unroll
        for (int m = 0; m < 16; ++m) {
            f32x4 av = *(const f32x4*)(A + (size_t)m * K + k0 + lane * 4);
            acc[m] += av[0] * wv[0] + av[1] * wv[1] + av[2] * wv[2] + av[3] * wv[3];
        }
    }
#pragma unroll
    for (int m = 0; m < 16; ++m)
#pragma unroll
        for (int s = 1; s < 64; s <<= 1) acc[m] += __shfl_xor(acc[m], s, 64);
    if (lane == 0) {
        float bv = bias[col];
#pragma unroll
        for (int m = 0; m < 16; ++m) {
            float v = acc[m] + bv;
            if (relu) v = fmaxf(v, 0.f);
            C[(size_t)m * N + col] = v;
        }
    }
}

__global__ void decode_kernel(const unsigned* __restrict__ k, float* __restrict__ f, int n) {
    int t = blockIdx.x * blockDim.x + threadIdx.x;
    if (t < n) f[t] = fkey_inv(k[t]);
}

// ---------- chamfer v2: 8 lanes per A-point, j-strided, shfl-min ----------
__global__ void chamfer_min_kernel(const float* __restrict__ A, int na,
                                   const float* __restrict__ Bp, int nb,
                                   float* __restrict__ slot) {
    int t = blockIdx.x * 256 + threadIdx.x;
    int pt = t >> 3, sl = t & 7;
    float val = 0.f;
    if (pt < BSZ * na) {
        int b = pt / na;
        const float* a = A + (size_t)pt * 3;
        float ax = a[0], ay = a[1], az = a[2];
        float aa = ax * ax + ay * ay + az * az;
        const float* Bb = Bp + (size_t)b * nb * 3;
        float m = 3e38f;
        for (int j = sl; j < nb; j += 8) {
            float bx = Bb[j * 3 + 0], by = Bb[j * 3 + 1], bz = Bb[j * 3 + 2];
            float d = aa + bx * bx + by * by + bz * bz - 2.0f * (ax * bx + ay * by + az * bz);
            m = fminf(m, d);
        }
#pragma unroll
        for (int s = 1; s < 8; s <<= 1) m = fminf(m, __shfl_xor(m, s, 64));
        if (sl == 0) val = sqrtf(fmaxf(m, 1e-12f));
    }
    __shared__ float sdata[256];
    sdata[threadIdx.x] = val;
    __syncthreads();
    for (int s = 128; s > 0; s >>= 1) {
        if (threadIdx.x < s) sdata[threadIdx.x] += sdata[threadIdx.x + s];
        __syncthreads();
    }
    if (threadIdx.x == 0) atomicAdd(slot, sdata[0]);
}

// ---------- smooth-L1 latent loss sum ----------
__global__ void latent_kernel(const float* __restrict__ f1, const float* __restrict__ f2,
                              int n, float* __restrict__ slot) {
    int t = blockIdx.x * blockDim.x + threadIdx.x;
    float val = 0.f;
    if (t < n) {
        float d = f1[t] - f2[t];
        float ad = fabsf(d);
        val = (ad < 1.f) ? (0.5f * d * d) : (ad - 0.5f);
    }
    __shared__ float sdata[256];
    sdata[threadIdx.x] = val;
    __syncthreads();
    for (int s = 128; s > 0; s >>= 1) {
        if (threadIdx.x < s) sdata[threadIdx.x] += sdata[threadIdx.x + s];
        __syncthreads();
    }
    if (threadIdx.x == 0) atomicAdd(slot, sdata[0]);
}

// ---------- 3x3 symmetric smallest eigenvector (double, analytic) ----------
__device__ void smallest_evec(double cxx, double cxy, double cxz,
                              double cyy, double cyz, double czz, double ev[3]) {
    double p1 = cxy * cxy + cxz * cxz + cyz * cyz;
    double q = (cxx + cyy + czz) / 3.0;
    double p2 = (cxx - q) * (cxx - q) + (cyy - q) * (cyy - q) + (czz - q) * (czz - q) + 2.0 * p1;
    double lam = q;
    if (p2 > 0.0) {
        double p = sqrt(p2 / 6.0);
        double b00 = (cxx - q) / p, b11 = (cyy - q) / p, b22 = (czz - q) / p;
        double b01 = cxy / p, b02 = cxz / p, b12 = cyz / p;
        double detB = b00 * (b11 * b22 - b12 * b12) - b01 * (b01 * b22 - b12 * b02)
                    + b02 * (b01 * b12 - b11 * b02);
        double r = detB * 0.5;
        r = r < -1.0 ? -1.0 : (r > 1.0 ? 1.0 : r);
        double phi = acos(r) / 3.0;
        lam = q + 2.0 * p * cos(phi + 2.0943951023931953);
    }
    double r0x = cxx - lam, r0y = cxy, r0z = cxz;
    double r1x = cxy, r1y = cyy - lam, r1z = cyz;
    double r2x = cxz, r2y = cyz, r2z = czz - lam;
    double c0x = r0y * r1z - r0z * r1y, c0y = r0z * r1x - r0x * r1z, c0z = r0x * r1y - r0y * r1x;
    double c1x = r0y * r2z - r0z * r2y, c1y = r0z * r2x - r0x * r2z, c1z = r0x * r2y - r0y * r2x;
    double c2x = r1y * r2z - r1z * r2y, c2y = r1z * r2x - r1x * r2z, c2z = r1x * r2y - r1y * r2x;
    double n0 = c0x * c0x + c0y * c0y + c0z * c0z;
    double n1 = c1x * c1x + c1y * c1y + c1z * c1z;
    double n2 = c2x * c2x + c2y * c2y + c2z * c2z;
    double bx = c0x, by = c0y, bz = c0z, bn = n0;
    if (n1 > bn) { bx = c1x; by = c1y; bz = c1z; bn = n1; }
    if (n2 > bn) { bx = c2x; by = c2y; bz = c2z; bn = n2; }
    if (bn < 1e-280) { ev[0] = 1.0; ev[1] = 0.0; ev[2] = 0.0; return; }
    double inv = 1.0 / sqrt(bn);
    ev[0] = bx * inv; ev[1] = by * inv; ev[2] = bz * inv;
}

// ---------- normals ----------
__global__ void normals_kernel(const float* __restrict__ pred, const int* __restrict__ knn,
                               float* __restrict__ nrm) {
    int t = blockIdx.x * blockDim.x + threadIdx.x;
    if (t >= BSZ * NPTS) return;
    int b = t / NPTS, i = t % NPTS;
    const float* P = pred + (size_t)b * NPTS * 3;
    const int* id = knn + (size_t)t * 32;
    float px[32], py[32], pz[32];
    double sx = 0, sy = 0, sz = 0;
    for (int k = 0; k < 32; ++k) {
        int j = id[k];
        px[k] = P[j * 3 + 0]; py[k] = P[j * 3 + 1]; pz[k] = P[j * 3 + 2];
        sx += px[k]; sy += py[k]; sz += pz[k];
    }
    double mx = sx / 32.0, my = sy / 32.0, mz = sz / 32.0;
    double cxx = 0, cxy = 0, cxz = 0, cyy = 0, cyz = 0, czz = 0;
    for (int k = 0; k < 32; ++k) {
        double dx = px[k] - mx, dy = py[k] - my, dz = pz[k] - mz;
        cxx += dx * dx; cxy += dx * dy; cxz += dx * dz;
        cyy += dy * dy; cyz += dy * dz; czz += dz * dz;
    }
    cxx /= 32.0; cxy /= 32.0; cxz /= 32.0; cyy /= 32.0; cyz /= 32.0; czz /= 32.0;
    double ev[3];
    smallest_evec(cxx, cxy, cxz, cyy, cyz, czz, ev);
    float qx = P[i * 3 + 0], qy = P[i * 3 + 1], qz = P[i * 3 + 2];
    double proj = 0.0;
    for (int k = 0; k < 32; ++k)
        proj += (px[k] - qx) * ev[0] + (py[k] - qy) * ev[1] + (pz[k] - qz) * ev[2];
    double s = (proj >= 0.0) ? 1.0 : -1.0;
    nrm[(size_t)t * 3 + 0] = (float)(ev[0] * s);
    nrm[(size_t)t * 3 + 1] = (float)(ev[1] * s);
    nrm[(size_t)t * 3 + 2] = (float)(ev[2] * s);
}

// ---------- manifold loss: reads first 8 of the 32-NN list ----------
__global__ void manifold_kernel(const float* __restrict__ nrm, const int* __restrict__ knn,
                                int kstride, float* __restrict__ slot) {
    int t = blockIdx.x * blockDim.x + threadIdx.x;
    float val = 0.f;
    if (t < BSZ * NPTS) {
        int b = t / NPTS;
        const float* NB = nrm + (size_t)b * NPTS * 3;
        const int* id = knn + (size_t)t * kstride;
        int j0 = id[0];
        float ax = NB[j0 * 3 + 0], ay = NB[j0 * 3 + 1], az = NB[j0 * 3 + 2];
        float an = fmaxf(sqrtf(ax * ax + ay * ay + az * az), 1e-6f);
        float x[8]; float s = 0.f;
        for (int k = 0; k < 8; ++k) {
            int j = id[k];
            float bx = NB[j * 3 + 0], by = NB[j * 3 + 1], bz = NB[j * 3 + 2];
            float bn_ = fmaxf(sqrtf(bx * bx + by * by + bz * bz), 1e-6f);
            float c = (ax * bx + ay * by + az * bz) / (an * bn_);
            x[k] = 1.f - c; s += x[k];
        }
        float mean = s / 8.f;
        float var = 0.f;
        for (int k = 0; k < 8; ++k) { float d = x[k] - mean; var += d * d; }
        val = sqrtf(var / 7.f);
    }
    __shared__ float sdata[256];
    sdata[threadIdx.x] = val;
    __syncthreads();
    for (int s2 = 128; s2 > 0; s2 >>= 1) {
        if (threadIdx.x < s2) sdata[threadIdx.x] += sdata[threadIdx.x + s2];
        __syncthreads();
    }
    if (threadIdx.x == 0) atomicAdd(slot, sdata[0]);
}

__global__ void finalize_kernel(const float* __restrict__ acc, float* __restrict__ out) {
    float l_recon = 0.5f * (acc[0] / (16.f * 2048.f) + acc[1] / (16.f * 2432.f));
    float l_match = 0.5f * (acc[2] / (16.f * 1024.f) + acc[3] / (16.f * 1216.f));
    float l_latent = acc[4] / (16.f * 1024.f);
    float l_man = 0.1f * (acc[5] / (16.f * 2048.f));
    out[0] = l_recon + l_match + l_latent + l_man;
    out[1] = l_recon;
    out[2] = l_match;
    out[3] = l_latent;
    out[4] = l_man;
}

// ================= host =================
extern "C" void kernel_launch(void* const* d_in, const int* in_sizes, int n_in,
                              void* d_out, int out_size, void* d_ws, size_t ws_size,
                              hipStream_t stream) {
    (void)in_sizes; (void)n_in; (void)out_size; (void)ws_size;
    const float* pts = (const float*)d_in[0];
    const float* W1 = (const float*)d_in[1];
    const float* b1 = (const float*)d_in[2];
    const float* g1 = (const float*)d_in[3];
    const float* be1 = (const float*)d_in[4];
    const float* m1 = (const float*)d_in[5];
    const float* v1 = (const float*)d_in[6];
    const float* W2 = (const float*)d_in[7];
    const float* b2 = (const float*)d_in[8];
    const float* W3 = (const float*)d_in[9];
    const float* b3 = (const float*)d_in[10];
    const float* g2 = (const float*)d_in[11];
    const float* be2 = (const float*)d_in[12];
    const float* m2 = (const float*)d_in[13];
    const float* v2 = (const float*)d_in[14];
    const float* W4 = (const float*)d_in[15];
    const float* b4 = (const float*)d_in[16];
    const float* D1W = (const float*)d_in[17];
    const float* D1b = (const float*)d_in[18];
    const float* D2W = (const float*)d_in[19];
    const float* D2b = (const float*)d_in[20];
    const float* D3W = (const float*)d_in[21];
    const float* D3b = (const float*)d_in[22];
    const float* D4W = (const float*)d_in[23];
    const float* D4b = (const float*)d_in[24];

    char* ws = (char*)d_ws;
    size_t off = 0;
    auto alloc = [&](size_t bytes) -> void* {
        void* p = ws + off;
        off += (bytes + 255) & ~(size_t)255;
        return p;
    };
    float* center   = (float*)alloc((size_t)BSZ * NG * 3 * 4);
    int*   knnc     = (int*)  alloc((size_t)BSZ * NG * GS * 4);
    float* rebuild0 = (float*)alloc((size_t)BSZ * 2048 * 3 * 4);
    float* rebuild1 = (float*)alloc((size_t)BSZ * 1024 * 3 * 4);
    f16*   W2h      = (f16*)  alloc((size_t)256 * 128 * 2);
    f16*   W3h      = (f16*)  alloc((size_t)512 * 256 * 2);
    f16*   W4h      = (f16*)  alloc((size_t)1024 * 512 * 2);
    f16*   H1h      = (f16*)  alloc((size_t)BSZ * 2048 * 128 * 2);
    f16*   H2h      = (f16*)  alloc((size_t)BSZ * 2048 * 256 * 2);
    f16*   H3h      = (f16*)  alloc((size_t)BSZ * 2048 * 512 * 2);
    unsigned* gmaxkey = (unsigned*)alloc((size_t)BSZ * 256 * 4);
    float* gmaxb    = (float*)alloc((size_t)BSZ * 256 * 4);
    float* gpart    = (float*)alloc((size_t)BSZ * 512 * 4);
    unsigned* featkey = (unsigned*)alloc((size_t)BSZ * 1024 * 4);
    float* feat     = (float*)alloc((size_t)BSZ * 1024 * 4);
    float* featrec  = (float*)alloc((size_t)BSZ * 1024 * 4);
    float* dh1      = (float*)alloc((size_t)BSZ * 2048 * 4);
    float* dh2      = (float*)alloc((size_t)BSZ * 2048 * 4);
    float* dh3      = (float*)alloc((size_t)BSZ * 2048 * 4);
    float* pred     = (float*)alloc((size_t)BSZ * 6144 * 4);
    int*   idxa     = (int*)  alloc((size_t)BSZ * 64 * NBRK * 4);
    float* gatha    = (float*)alloc((size_t)BSZ * 64 * NBRK * 3 * 4);
    int*   idxb     = (int*)  alloc((size_t)BSZ * 32 * NBRK * 4);
    float* gathb    = (float*)alloc((size_t)BSZ * 32 * NBRK * 3 * 4);
    int*   idxc     = (int*)  alloc((size_t)BSZ * 32 * 32 * 4);
    float* gathc    = (float*)alloc((size_t)BSZ * 1024 * 3 * 4);
    int*   knn32    = (int*)  alloc((size_t)BSZ * 2048 * 32 * 4);
    float* nrmbuf   = (float*)alloc((size_t)BSZ * 2048 * 3 * 4);
    float* accum    = (float*)alloc(8 * 4);

    hipMemsetAsync(accum, 0, 8 * 4, stream);

    cvt_w_kernel<<<(256 * 128 + 255) / 256, 256, 0, stream>>>(W2, 128, 0, 128, W2h, 256 * 128);
    cvt_w_kernel<<<(512 * 256 + 255) / 256, 256, 0, stream>>>(W3, 512, 256, 256, W3h, 512 * 256);
    cvt_w_kernel<<<(1024 * 512 + 255) / 256, 256, 0, stream>>>(W4, 512, 0, 512, W4h, 1024 * 512);

    auto knn = [&](const float* Q, int q_bstride, int q_off, int nq,
                   const float* DB, int k, int* out) {
        int total = BSZ * nq;
        knn_kernel_v7<<<(total + 3) / 4, 256, 0, stream>>>(Q, q_bstride, q_off, nq,
                                                           DB, k, out, BSZ);
    };

    // FPS + grouping
    fps_wave_kernel<<<BSZ, 64, 0, stream>>>(pts, center);
    knn(center, NG, 0, NG, pts, GS, knnc);
    gather_points_kernel<<<(BSZ * 2048 + 255) / 256, 256, 0, stream>>>(pts, NPTS, knnc, NG * GS,
                                                                       0, 2048, rebuild0, BSZ);
    gather_points_kernel<<<(BSZ * 1024 + 255) / 256, 256, 0, stream>>>(pts, NPTS, knnc, NG * GS,
                                                                       2048, 1024, rebuild1, BSZ);

    auto enc = [&](const float* X, int n, float* featout) {
        int M = BSZ * n;
        layer1_kernel<<<M / 16, 256, 0, stream>>>(X, W1, b1, g1, be1, m1, v1, H1h, M);
        hipMemsetAsync(gmaxkey, 0, (size_t)BSZ * 256 * 4, stream);
        mfma_gemm_kernel<<<dim3(256 / 128, M / 128), 256, 0, stream>>>(
            H1h, W2h, 128, 256, b2, nullptr, nullptr, nullptr, nullptr, nullptr,
            H2h, gmaxkey, n, 0);
        decode_kernel<<<(BSZ * 256 + 255) / 256, 256, 0, stream>>>(gmaxkey, gmaxb, BSZ * 256);
        skinny_v2_kernel<<<(512 + 3) / 4, 256, 0, stream>>>(gmaxb, W3, 512, 0, b3,
                                                            gpart, 256, 512, 0);
        mfma_gemm_kernel<<<dim3(512 / 128, M / 128), 256, 0, stream>>>(
            H2h, W3h, 256, 512, nullptr, gpart, g2, be2, m2, v2, H3h, nullptr, n, 1);
        hipMemsetAsync(featkey, 0, (size_t)BSZ * 1024 * 4, stream);
        mfma_gemm_kernel<<<dim3(1024 / 128, M / 128), 256, 0, stream>>>(
            H3h, W4h, 512, 1024, b4, nullptr, nullptr, nullptr, nullptr, nullptr,
            nullptr, featkey, n, 0);
        decode_kernel<<<(BSZ * 1024 + 255) / 256, 256, 0, stream>>>(featkey, featout, BSZ * 1024);
    };

    enc(rebuild0, 2048, feat);

    // decoder (skinny M=16, fp32, coalesced)
    skinny_v2_kernel<<<2048 / 4, 256, 0, stream>>>(feat, D1W, 1024, 0, D1b, dh1, 1024, 2048, 1);
    skinny_v2_kernel<<<2048 / 4, 256, 0, stream>>>(dh1, D2W, 2048, 0, D2b, dh2, 2048, 2048, 1);
    skinny_v2_kernel<<<2048 / 4, 256, 0, stream>>>(dh2, D3W, 2048, 0, D3b, dh3, 2048, 2048, 1);
    skinny_v2_kernel<<<6144 / 4, 256, 0, stream>>>(dh3, D4W, 2048, 0, D4b, pred, 2048, 6144, 0);

    // l_recon
    knn(center, NG, 0, 64, pred, NBRK, idxa);
    gather_points_kernel<<<(BSZ * 2432 + 255) / 256, 256, 0, stream>>>(pred, 2048, idxa, 64 * NBRK,
                                                                       0, 2432, gatha, BSZ);
    chamfer_min_kernel<<<(BSZ * 2048 * 8 + 255) / 256, 256, 0, stream>>>(rebuild0, 2048,
                                                                         gatha, 2432, accum + 0);
    chamfer_min_kernel<<<(BSZ * 2432 * 8 + 255) / 256, 256, 0, stream>>>(gatha, 2432,
                                                                         rebuild0, 2048, accum + 1);
    // l_match
    knn(center, NG, 64, 32, pred, NBRK, idxb);
    gather_points_kernel<<<(BSZ * 1216 + 255) / 256, 256, 0, stream>>>(pred, 2048, idxb, 32 * NBRK,
                                                                       0, 1216, gathb, BSZ);
    chamfer_min_kernel<<<(BSZ * 1024 * 8 + 255) / 256, 256, 0, stream>>>(rebuild1, 1024,
                                                                         gathb, 1216, accum + 2);
    chamfer_min_kernel<<<(BSZ * 1216 * 8 + 255) / 256, 256, 0, stream>>>(gathb, 1216,
                                                                         rebuild1, 1024, accum + 3);
    // l_latent
    knn(center, NG, 96, 32, pred, 32, idxc);
    gather_points_kernel<<<(BSZ * 1024 + 255) / 256, 256, 0, stream>>>(pred, 2048, idxc, 32 * 32,
                                                                       0, 1024, gathc, BSZ);
    enc(gathc, 1024, featrec);
    latent_kernel<<<(BSZ * 1024 + 255) / 256, 256, 0, stream>>>(feat, featrec, BSZ * 1024,
                                                                accum + 4);
    // l_man: one self-KNN (k=32); manifold uses first 8 (stable top-k prefix)
    knn(pred, 2048, 0, 2048, pred, 32, knn32);
    normals_kernel<<<(BSZ * 2048 + 255) / 256, 256, 0, stream>>>(pred, knn32, nrmbuf);
    manifold_kernel<<<(BSZ * 2048 + 255) / 256, 256, 0, stream>>>(nrmbuf, knn32, 32, accum + 5);

    finalize_kernel<<<1, 1, 0, stream>>>(accum, (float*)d_out);
}

// Round 3
// 926.040 us; speedup vs baseline: 1.0649x; 1.0235x over previous
//
#include <hip/hip_runtime.h>
#include <math.h>

#define BSZ 16
#define NPTS 2048
#define NG 128
#define GS 32
#define NBRK 38

typedef _Float16 f16;
typedef _Float16 f16x8 __attribute__((ext_vector_type(8)));
typedef float f32x4 __attribute__((ext_vector_type(4)));

// ---------- helpers ----------
__device__ __forceinline__ unsigned fkey(float x) {
    unsigned u = __float_as_uint(x);
    return (u >> 31) ? ~u : (u | 0x80000000u);
}
__device__ __forceinline__ float fkey_inv(unsigned k) {
    unsigned u = (k >> 31) ? (k ^ 0x80000000u) : ~k;
    return __uint_as_float(u);
}

// 64-lane min via DPP (no LDS/DS pipe): row_shr 1/2/4/8 prefix + row_bcast 15/31,
// then readlane 63 broadcasts the full-wave min. gfx9-lineage DPP (CDNA keeps it).
__device__ __forceinline__ unsigned wave_min_u32(unsigned v) {
    unsigned t;
    t = (unsigned)__builtin_amdgcn_update_dpp(-1, (int)v, 0x111, 0xF, 0xF, false);
    v = v < t ? v : t;
    t = (unsigned)__builtin_amdgcn_update_dpp(-1, (int)v, 0x112, 0xF, 0xF, false);
    v = v < t ? v : t;
    t = (unsigned)__builtin_amdgcn_update_dpp(-1, (int)v, 0x114, 0xF, 0xF, false);
    v = v < t ? v : t;
    t = (unsigned)__builtin_amdgcn_update_dpp(-1, (int)v, 0x118, 0xF, 0xF, false);
    v = v < t ? v : t;
    t = (unsigned)__builtin_amdgcn_update_dpp(-1, (int)v, 0x142, 0xA, 0xF, false);
    v = v < t ? v : t;
    t = (unsigned)__builtin_amdgcn_update_dpp(-1, (int)v, 0x143, 0xC, 0xF, false);
    v = v < t ? v : t;
    return (unsigned)__builtin_amdgcn_readlane((int)v, 63);
}

// 64-lane max of a u64 key via DPP: one chain handles (value, tiebreak) packed.
// old=0 is the identity for unsigned max.
__device__ __forceinline__ unsigned long long wave_max_u64(unsigned long long v) {
#define DPPSTEP(ctrl, rmask)                                                                \
    {                                                                                       \
        unsigned tlo = (unsigned)__builtin_amdgcn_update_dpp(0, (int)(unsigned)v, ctrl,     \
                                                             rmask, 0xF, false);            \
        unsigned thi = (unsigned)__builtin_amdgcn_update_dpp(0, (int)(unsigned)(v >> 32),   \
                                                             ctrl, rmask, 0xF, false);      \
        unsigned long long t = ((unsigned long long)thi << 32) | tlo;                       \
        v = t > v ? t : v;                                                                  \
    }
    DPPSTEP(0x111, 0xF)
    DPPSTEP(0x112, 0xF)
    DPPSTEP(0x114, 0xF)
    DPPSTEP(0x118, 0xF)
    DPPSTEP(0x142, 0xA)
    DPPSTEP(0x143, 0xC)
#undef DPPSTEP
    unsigned rlo = (unsigned)__builtin_amdgcn_readlane((int)(unsigned)v, 63);
    unsigned rhi = (unsigned)__builtin_amdgcn_readlane((int)(unsigned)(v >> 32), 63);
    return ((unsigned long long)rhi << 32) | rlo;
}

// ---------- FPS v5: 4 waves, one barrier/iter, parity-buffered wave slots ----------
// 256 threads, 8 pts/lane (pass-1 issue cost 4x lower than the 1-wave v4).
// Per iter: per-lane fused argmax (2 strict-> chains, ascending m => min index),
// ONE u64 DPP max per wave on key=(bits(best)<<32)|~j, lanes 0-2 prefetch the
// wave-winner coords from LDS pre-barrier (latency hidden by inter-wave skew),
// {key,x,y,z} -> parity slot; ONE __syncthreads; all threads combine 4 slots
// (u64 max + cndmask coord select => next center, no further LDS read).
// Parity double-buffer makes the single barrier race-free: barrier g+1 separates
// readers of slot[g&1] (iter g) from its next writers (iter g+2).
// Tie-break matches jnp.argmax exactly: max dist, then min global index.
__global__ __launch_bounds__(256, 1) void fps_kernel_v5(const float* __restrict__ pts,
                                                        float* __restrict__ center) {
    int b = blockIdx.x;
    const float* P = pts + (size_t)b * NPTS * 3;
    int tid = threadIdx.x;
    int lane = tid & 63, wave = tid >> 6;
    __shared__ __align__(16) float Pl[NPTS * 3];
    __shared__ __align__(16) float slot[2][4][8];   // [parity][wave]{klo,khi,x,y,z,...}
#pragma unroll
    for (int i = 0; i < 6; ++i) {    // 1536 float4 = 24 KB, coalesced
        int v4 = tid + i * 256;
        ((f32x4*)Pl)[v4] = ((const f32x4*)P)[v4];
    }
    __syncthreads();
    float px[8], py[8], pz[8], mind[8];
#pragma unroll
    for (int m = 0; m < 8; ++m) {
        int j = tid + (m << 8);
        px[m] = Pl[j * 3 + 0];
        py[m] = Pl[j * 3 + 1];
        pz[m] = Pl[j * 3 + 2];
        mind[m] = 1e10f;
    }
    float cx = Pl[0], cy = Pl[1], cz = Pl[2];   // far = 0
    float* C = center + (size_t)b * NG * 3;
#pragma unroll 1
    for (int g = 0; g < NG; ++g) {
        if (tid == 0) {
            C[g * 3 + 0] = cx; C[g * 3 + 1] = cy; C[g * 3 + 2] = cz;
        }
        if (g == NG - 1) break;      // uniform: all threads exit together
        float best0 = -1.f, best1 = -1.f;
        int bm0 = 0, bm1 = 1;
#pragma unroll
        for (int m = 0; m < 8; m += 2) {   // 2 independent dep chains
            float dx0 = px[m] - cx, dy0 = py[m] - cy, dz0 = pz[m] - cz;
            float d0 = dx0 * dx0 + dy0 * dy0 + dz0 * dz0;
            float md0 = fminf(mind[m], d0);
            mind[m] = md0;
            if (md0 > best0) { best0 = md0; bm0 = m; }        // strict >: min m on tie
            float dx1 = px[m + 1] - cx, dy1 = py[m + 1] - cy, dz1 = pz[m + 1] - cz;
            float d1 = dx1 * dx1 + dy1 * dy1 + dz1 * dz1;
            float md1 = fminf(mind[m + 1], d1);
            mind[m + 1] = md1;
            if (md1 > best1) { best1 = md1; bm1 = m + 1; }
        }
        bool t = (best1 > best0) || (best1 == best0 && bm1 < bm0);
        float bv = t ? best1 : best0;
        int bi = t ? bm1 : bm0;
        unsigned j = (unsigned)(tid + (bi << 8));   // global point index
        // bv >= 0 so float bits order as u32; ~j => u64-max picks min index on ties
        unsigned long long key =
            ((unsigned long long)__float_as_uint(bv) << 32) | (unsigned)(~j);
        key = wave_max_u64(key);                    // broadcast to all lanes
        unsigned bj = ~(unsigned)key;
        int par = g & 1;
        if (lane < 3) slot[par][wave][2 + lane] = Pl[bj * 3 + lane];  // prefetch coords
        if (lane == 0) {
            slot[par][wave][0] = __uint_as_float((unsigned)key);
            slot[par][wave][1] = __uint_as_float((unsigned)(key >> 32));
        }
        __syncthreads();
        // combine 4 wave slots (uniform across all threads)
        unsigned long long kb = 0ull;
        float nx = 0.f, ny = 0.f, nz = 0.f;
#pragma unroll
        for (int w = 0; w < 4; ++w) {
            f32x4 v = *(const f32x4*)&slot[par][w][0];   // klo,khi,x,y
            float vz = slot[par][w][4];
            unsigned long long kk =
                ((unsigned long long)__float_as_uint(v[1]) << 32) | __float_as_uint(v[0]);
            bool tw = kk > kb;
            kb = tw ? kk : kb;
            nx = tw ? v[2] : nx;
            ny = tw ? v[3] : ny;
            nz = tw ? vz : nz;
        }
        cx = nx; cy = ny; cz = nz;
    }
}

// ---------- KNN v7: 32-bit packed keys + DPP wave-min, zero DS ops ----------
// key = (quantized_dist << 11) | idx ; u32 order == (d, idx) lex order up to the
// 1/8192 distance quantum (idx breaks quantized ties; matches stable top_k
// except between points closer than 1.2e-4 in squared distance -- negligible).
// Per-lane top-4 key cache + watermark refill (rare); wave per query; no barriers.
__global__ void knn_kernel_v7(const float* __restrict__ Q, int q_bstride, int q_off, int nq,
                              const float* __restrict__ DB, int k,
                              int* __restrict__ out, int nbatch) {
    const unsigned KINF = 0xFFFFFFFFu;
    int wave = threadIdx.x >> 6, lane = threadIdx.x & 63;
    int qidx = blockIdx.x * 4 + wave;
    if (qidx >= nbatch * nq) return;     // wave-uniform
    int b = qidx / nq, qi = qidx % nq;
    const float* q = Q + ((size_t)b * q_bstride + q_off + qi) * 3;
    float qx = q[0], qy = q[1], qz = q[2];
    float qq = qx * qx + qy * qy + qz * qz;
    const float* db = DB + (size_t)b * NPTS * 3;

    unsigned key[32];
    unsigned c0 = KINF, c1 = KINF, c2 = KINF, c3 = KINF;
#pragma unroll
    for (int m = 0; m < 32; ++m) {
        int j = lane + (m << 6);
        float bx = db[j * 3 + 0], by = db[j * 3 + 1], bz = db[j * 3 + 2];
        float dv = qq + bx * bx + by * by + bz * bz - 2.0f * (qx * bx + qy * by + qz * bz);
        unsigned qd = (unsigned)fminf(fmaxf(dv, 0.f) * 8192.0f, 2097151.f);
        unsigned kk = (qd << 11) | (unsigned)j;
        key[m] = kk;
        if (kk < c3) {
            if (kk < c2) {
                c3 = c2;
                if (kk < c1) {
                    c2 = c1;
                    if (kk < c0) { c1 = c0; c0 = kk; } else c1 = kk;
                } else c2 = kk;
            } else c3 = kk;
        }
    }
    unsigned hw = c3;        // high-water: largest key ever cached (init: 4th best)
    int ncached = 4;
    int* o = out + (size_t)qidx * k;

    for (int r = 0; r < k; ++r) {
        bool need = (c0 == KINF) && (ncached < 32);
        if (__any(need)) {
            unsigned best = KINF;
#pragma unroll
            for (int m = 0; m < 32; ++m) {
                unsigned v = key[m];
                best = (v > hw && v < best) ? v : best;
            }
            if (need) {
                c0 = best;
                hw = best;
                ncached = (best == KINF) ? 32 : ncached + 1;
            }
        }
        unsigned g = wave_min_u32(c0);
        if (lane == 0) o[r] = (int)(g & 0x7FFu);
        if (((g & 0x7FFu) & 63u) == (unsigned)lane) {  // owner pops its c0 (== g)
            c0 = c1; c1 = c2; c2 = c3; c3 = KINF;
        }
    }
}

// ---------- gather points via index array ----------
__global__ void gather_points_kernel(const float* __restrict__ pts, int db_bstride,
                                     const int* __restrict__ idx, int idx_bstride, int idx_off,
                                     int m, float* __restrict__ out, int nbatch) {
    int t = blockIdx.x * blockDim.x + threadIdx.x;
    if (t >= nbatch * m) return;
    int b = t / m, j = t % m;
    int s = idx[(size_t)b * idx_bstride + idx_off + j];
    const float* p = pts + ((size_t)b * db_bstride + s) * 3;
    out[(size_t)t * 3 + 0] = p[0];
    out[(size_t)t * 3 + 1] = p[1];
    out[(size_t)t * 3 + 2] = p[2];
}

// ---------- fp32 -> fp16 weight conversion (strided slice) ----------
__global__ void cvt_w_kernel(const float* __restrict__ in, int ld, int off, int K,
                             f16* __restrict__ out, int total) {
    int t = blockIdx.x * blockDim.x + threadIdx.x;
    if (t >= total) return;
    int n = t / K, k = t % K;
    out[t] = (f16)in[(size_t)n * ld + off + k];
}

// ---------- layer1: H1 = relu(bn(x @ W1^T + b1)) in fp16, fused ----------
__global__ void layer1_kernel(const float* __restrict__ X, const float* __restrict__ W1,
                              const float* __restrict__ b1, const float* __restrict__ g1,
                              const float* __restrict__ be1, const float* __restrict__ m1,
                              const float* __restrict__ v1, f16* __restrict__ H1, int M) {
    __shared__ float w[384], bb[128], sg[128], sb[128], sm[128], sv[128];
    for (int i = threadIdx.x; i < 384; i += 256) w[i] = W1[i];
    if (threadIdx.x < 128) {
        int c = threadIdx.x;
        bb[c] = b1[c]; sg[c] = g1[c]; sb[c] = be1[c]; sm[c] = m1[c]; sv[c] = v1[c];
    }
    __syncthreads();
    int t = blockIdx.x * 256 + threadIdx.x;
    if (t >= M * 16) return;
    int row = t >> 4, cg = (t & 15) * 8;
    float x0 = X[(size_t)row * 3], x1 = X[(size_t)row * 3 + 1], x2 = X[(size_t)row * 3 + 2];
    f16x8 outv;
#pragma unroll
    for (int j = 0; j < 8; ++j) {
        int c = cg + j;
        float tv = x0 * w[c * 3] + x1 * w[c * 3 + 1] + x2 * w[c * 3 + 2] + bb[c];
        float vv = (tv - sm[c]) * rsqrtf(sv[c] + 1e-5f) * sg[c] + sb[c];
        outv[j] = (f16)fmaxf(vv, 0.f);
    }
    *(f16x8*)&H1[(size_t)row * 128 + cg] = outv;
}

// ---------- MFMA GEMM ----------
__global__ __launch_bounds__(256) void mfma_gemm_kernel(
        const f16* __restrict__ A, const f16* __restrict__ W, int K, int N,
        const float* __restrict__ bias, const float* __restrict__ bias2d,
        const float* __restrict__ bng, const float* __restrict__ bnb,
        const float* __restrict__ bnm, const float* __restrict__ bnv,
        f16* __restrict__ Cout, unsigned* __restrict__ maxkey,
        int rows_per_batch, int relu) {
    __shared__ f16 Als[128 * 40];
    __shared__ f16 Bls[128 * 40];
    int tid = threadIdx.x;
    int lane = tid & 63;
    int wave = tid >> 6;
    int wm = wave & 1, wn = wave >> 1;
    int c16 = lane & 15, quad = lane >> 4;
    int row0 = blockIdx.y * 128, col0 = blockIdx.x * 128;
    int sr = tid >> 2;
    int skc = (tid & 3) * 8;

    f32x4 acc[4][4];
#pragma unroll
    for (int i = 0; i < 4; ++i)
#pragma unroll
        for (int j = 0; j < 4; ++j) acc[i][j] = (f32x4){0.f, 0.f, 0.f, 0.f};

    for (int k0 = 0; k0 < K; k0 += 32) {
#pragma unroll
        for (int i = 0; i < 2; ++i) {
            int r2 = sr + i * 64;
            f16x8 av = *(const f16x8*)(A + (size_t)(row0 + r2) * K + k0 + skc);
            *(f16x8*)&Als[r2 * 40 + skc] = av;
            f16x8 bv = *(const f16x8*)(W + (size_t)(col0 + r2) * K + k0 + skc);
            *(f16x8*)&Bls[r2 * 40 + skc] = bv;
        }
        __syncthreads();
        f16x8 af[4], bf[4];
#pragma unroll
        for (int s = 0; s < 4; ++s) {
            af[s] = *(const f16x8*)&Als[(wm * 64 + s * 16 + c16) * 40 + quad * 8];
            bf[s] = *(const f16x8*)&Bls[(wn * 64 + s * 16 + c16) * 40 + quad * 8];
        }
#pragma unroll
        for (int ms = 0; ms < 4; ++ms)
#pragma unroll
            for (int ns = 0; ns < 4; ++ns)
                acc[ms][ns] = __builtin_amdgcn_mfma_f32_16x16x32_f16(af[ms], bf[ns],
                                                                     acc[ms][ns], 0, 0, 0);
        __syncthreads();
    }

    int b = row0 / rows_per_batch;
#pragma unroll
    for (int ns = 0; ns < 4; ++ns) {
        int col = col0 + wn * 64 + ns * 16 + c16;
        float bv = bias ? bias[col] : 0.f;
        float b2v = bias2d ? bias2d[(size_t)b * N + col] : 0.f;
        float mx = -3e38f;
#pragma unroll
        for (int ms = 0; ms < 4; ++ms) {
#pragma unroll
            for (int j = 0; j < 4; ++j) {
                float v = acc[ms][ns][j] + bv + b2v;
                if (bng) v = (v - bnm[col]) * rsqrtf(bnv[col] + 1e-5f) * bng[col] + bnb[col];
                if (relu) v = fmaxf(v, 0.f);
                if (Cout)
                    Cout[(size_t)(row0 + wm * 64 + ms * 16 + quad * 4 + j) * N + col] = (f16)v;
                mx = fmaxf(mx, v);
            }
        }
        if (maxkey) {
            mx = fmaxf(mx, __shfl_xor(mx, 16, 64));
            mx = fmaxf(mx, __shfl_xor(mx, 32, 64));
            if (quad == 0) atomicMax(&maxkey[(size_t)b * N + col], fkey(mx));
        }
    }
}

// ---------- skinny GEMM v2: wave per column, coalesced float4 ----------
__global__ void skinny_v2_kernel(const float* __restrict__ A, const float* __restrict__ W,
                                 int ldw, int woff, const float* __restrict__ bias,
                                 float* __restrict__ C, int K, int N, int relu) {
    int wave = threadIdx.x >> 6, lane = threadIdx.x & 63;
    int col = blockIdx.x * 4 + wave;
    if (col >= N) return;
    const float* w = W + (size_t)col * ldw + woff;
    float acc[16];
#pragma unroll
    for (int m = 0; m < 16; ++m) acc[m] = 0.f;
    for (int k0 = 0; k0 < K; k0 += 256) {
        f32x4 wv = *(const f32x4*)(w + k0 + lane * 4);
#pragma unroll
        for (int m = 0; m < 16; ++m) {
            f32x4 av = *(const f32x4*)(A + (size_t)m * K + k0 + lane * 4);
            acc[m] += av[0] * wv[0] + av[1] * wv[1] + av[2] * wv[2] + av[3] * wv[3];
        }
    }
#pragma unroll
    for (int m = 0; m < 16; ++m)
#pragma unroll
        for (int s = 1; s < 64; s <<= 1) acc[m] += __shfl_xor(acc[m], s, 64);
    if (lane == 0) {
        float bv = bias[col];
#pragma unroll
        for (int m = 0; m < 16; ++m) {
            float v = acc[m] + bv;
            if (relu) v = fmaxf(v, 0.f);
            C[(size_t)m * N + col] = v;
        }
    }
}

__global__ void decode_kernel(const unsigned* __restrict__ k, float* __restrict__ f, int n) {
    int t = blockIdx.x * blockDim.x + threadIdx.x;
    if (t < n) f[t] = fkey_inv(k[t]);
}

// ---------- chamfer v2: 8 lanes per A-point, j-strided, shfl-min ----------
__global__ void chamfer_min_kernel(const float* __restrict__ A, int na,
                                   const float* __restrict__ Bp, int nb,
                                   float* __restrict__ slot) {
    int t = blockIdx.x * 256 + threadIdx.x;
    int pt = t >> 3, sl = t & 7;
    float val = 0.f;
    if (pt < BSZ * na) {
        int b = pt / na;
        const float* a = A + (size_t)pt * 3;
        float ax = a[0], ay = a[1], az = a[2];
        float aa = ax * ax + ay * ay + az * az;
        const float* Bb = Bp + (size_t)b * nb * 3;
        float m = 3e38f;
        for (int j = sl; j < nb; j += 8) {
            float bx = Bb[j * 3 + 0], by = Bb[j * 3 + 1], bz = Bb[j * 3 + 2];
            float d = aa + bx * bx + by * by + bz * bz - 2.0f * (ax * bx + ay * by + az * bz);
            m = fminf(m, d);
        }
#pragma unroll
        for (int s = 1; s < 8; s <<= 1) m = fminf(m, __shfl_xor(m, s, 64));
        if (sl == 0) val = sqrtf(fmaxf(m, 1e-12f));
    }
    __shared__ float sdata[256];
    sdata[threadIdx.x] = val;
    __syncthreads();
    for (int s = 128; s > 0; s >>= 1) {
        if (threadIdx.x < s) sdata[threadIdx.x] += sdata[threadIdx.x + s];
        __syncthreads();
    }
    if (threadIdx.x == 0) atomicAdd(slot, sdata[0]);
}

// ---------- smooth-L1 latent loss sum ----------
__global__ void latent_kernel(const float* __restrict__ f1, const float* __restrict__ f2,
                              int n, float* __restrict__ slot) {
    int t = blockIdx.x * blockDim.x + threadIdx.x;
    float val = 0.f;
    if (t < n) {
        float d = f1[t] - f2[t];
        float ad = fabsf(d);
        val = (ad < 1.f) ? (0.5f * d * d) : (ad - 0.5f);
    }
    __shared__ float sdata[256];
    sdata[threadIdx.x] = val;
    __syncthreads();
    for (int s = 128; s > 0; s >>= 1) {
        if (threadIdx.x < s) sdata[threadIdx.x] += sdata[threadIdx.x + s];
        __syncthreads();
    }
    if (threadIdx.x == 0) atomicAdd(slot, sdata[0]);
}

// ---------- 3x3 symmetric smallest eigenvector (double, analytic) ----------
__device__ void smallest_evec(double cxx, double cxy, double cxz,
                              double cyy, double cyz, double czz, double ev[3]) {
    double p1 = cxy * cxy + cxz * cxz + cyz * cyz;
    double q = (cxx + cyy + czz) / 3.0;
    double p2 = (cxx - q) * (cxx - q) + (cyy - q) * (cyy - q) + (czz - q) * (czz - q) + 2.0 * p1;
    double lam = q;
    if (p2 > 0.0) {
        double p = sqrt(p2 / 6.0);
        double b00 = (cxx - q) / p, b11 = (cyy - q) / p, b22 = (czz - q) / p;
        double b01 = cxy / p, b02 = cxz / p, b12 = cyz / p;
        double detB = b00 * (b11 * b22 - b12 * b12) - b01 * (b01 * b22 - b12 * b02)
                    + b02 * (b01 * b12 - b11 * b02);
        double r = detB * 0.5;
        r = r < -1.0 ? -1.0 : (r > 1.0 ? 1.0 : r);
        double phi = acos(r) / 3.0;
        lam = q + 2.0 * p * cos(phi + 2.0943951023931953);
    }
    double r0x = cxx - lam, r0y = cxy, r0z = cxz;
    double r1x = cxy, r1y = cyy - lam, r1z = cyz;
    double r2x = cxz, r2y = cyz, r2z = czz - lam;
    double c0x = r0y * r1z - r0z * r1y, c0y = r0z * r1x - r0x * r1z, c0z = r0x * r1y - r0y * r1x;
    double c1x = r0y * r2z - r0z * r2y, c1y = r0z * r2x - r0x * r2z, c1z = r0x * r2y - r0y * r2x;
    double c2x = r1y * r2z - r1z * r2y, c2y = r1z * r2x - r1x * r2z, c2z = r1x * r2y - r1y * r2x;
    double n0 = c0x * c0x + c0y * c0y + c0z * c0z;
    double n1 = c1x * c1x + c1y * c1y + c1z * c1z;
    double n2 = c2x * c2x + c2y * c2y + c2z * c2z;
    double bx = c0x, by = c0y, bz = c0z, bn = n0;
    if (n1 > bn) { bx = c1x; by = c1y; bz = c1z; bn = n1; }
    if (n2 > bn) { bx = c2x; by = c2y; bz = c2z; bn = n2; }
    if (bn < 1e-280) { ev[0] = 1.0; ev[1] = 0.0; ev[2] = 0.0; return; }
    double inv = 1.0 / sqrt(bn);
    ev[0] = bx * inv; ev[1] = by * inv; ev[2] = bz * inv;
}

// ---------- normals ----------
__global__ void normals_kernel(const float* __restrict__ pred, const int* __restrict__ knn,
                               float* __restrict__ nrm) {
    int t = blockIdx.x * blockDim.x + threadIdx.x;
    if (t >= BSZ * NPTS) return;
    int b = t / NPTS, i = t % NPTS;
    const float* P = pred + (size_t)b * NPTS * 3;
    const int* id = knn + (size_t)t * 32;
    float px[32], py[32], pz[32];
    double sx = 0, sy = 0, sz = 0;
    for (int k = 0; k < 32; ++k) {
        int j = id[k];
        px[k] = P[j * 3 + 0]; py[k] = P[j * 3 + 1]; pz[k] = P[j * 3 + 2];
        sx += px[k]; sy += py[k]; sz += pz[k];
    }
    double mx = sx / 32.0, my = sy / 32.0, mz = sz / 32.0;
    double cxx = 0, cxy = 0, cxz = 0, cyy = 0, cyz = 0, czz = 0;
    for (int k = 0; k < 32; ++k) {
        double dx = px[k] - mx, dy = py[k] - my, dz = pz[k] - mz;
        cxx += dx * dx; cxy += dx * dy; cxz += dx * dz;
        cyy += dy * dy; cyz += dy * dz; czz += dz * dz;
    }
    cxx /= 32.0; cxy /= 32.0; cxz /= 32.0; cyy /= 32.0; cyz /= 32.0; czz /= 32.0;
    double ev[3];
    smallest_evec(cxx, cxy, cxz, cyy, cyz, czz, ev);
    float qx = P[i * 3 + 0], qy = P[i * 3 + 1], qz = P[i * 3 + 2];
    double proj = 0.0;
    for (int k = 0; k < 32; ++k)
        proj += (px[k] - qx) * ev[0] + (py[k] - qy) * ev[1] + (pz[k] - qz) * ev[2];
    double s = (proj >= 0.0) ? 1.0 : -1.0;
    nrm[(size_t)t * 3 + 0] = (float)(ev[0] * s);
    nrm[(size_t)t * 3 + 1] = (float)(ev[1] * s);
    nrm[(size_t)t * 3 + 2] = (float)(ev[2] * s);
}

// ---------- manifold loss: reads first 8 of the 32-NN list ----------
__global__ void manifold_kernel(const float* __restrict__ nrm, const int* __restrict__ knn,
                                int kstride, float* __restrict__ slot) {
    int t = blockIdx.x * blockDim.x + threadIdx.x;
    float val = 0.f;
    if (t < BSZ * NPTS) {
        int b = t / NPTS;
        const float* NB = nrm + (size_t)b * NPTS * 3;
        const int* id = knn + (size_t)t * kstride;
        int j0 = id[0];
        float ax = NB[j0 * 3 + 0], ay = NB[j0 * 3 + 1], az = NB[j0 * 3 + 2];
        float an = fmaxf(sqrtf(ax * ax + ay * ay + az * az), 1e-6f);
        float x[8]; float s = 0.f;
        for (int k = 0; k < 8; ++k) {
            int j = id[k];
            float bx = NB[j * 3 + 0], by = NB[j * 3 + 1], bz = NB[j * 3 + 2];
            float bn_ = fmaxf(sqrtf(bx * bx + by * by + bz * bz), 1e-6f);
            float c = (ax * bx + ay * by + az * bz) / (an * bn_);
            x[k] = 1.f - c; s += x[k];
        }
        float mean = s / 8.f;
        float var = 0.f;
        for (int k = 0; k < 8; ++k) { float d = x[k] - mean; var += d * d; }
        val = sqrtf(var / 7.f);
    }
    __shared__ float sdata[256];
    sdata[threadIdx.x] = val;
    __syncthreads();
    for (int s2 = 128; s2 > 0; s2 >>= 1) {
        if (threadIdx.x < s2) sdata[threadIdx.x] += sdata[threadIdx.x + s2];
        __syncthreads();
    }
    if (threadIdx.x == 0) atomicAdd(slot, sdata[0]);
}

__global__ void finalize_kernel(const float* __restrict__ acc, float* __restrict__ out) {
    float l_recon = 0.5f * (acc[0] / (16.f * 2048.f) + acc[1] / (16.f * 2432.f));
    float l_match = 0.5f * (acc[2] / (16.f * 1024.f) + acc[3] / (16.f * 1216.f));
    float l_latent = acc[4] / (16.f * 1024.f);
    float l_man = 0.1f * (acc[5] / (16.f * 2048.f));
    out[0] = l_recon + l_match + l_latent + l_man;
    out[1] = l_recon;
    out[2] = l_match;
    out[3] = l_latent;
    out[4] = l_man;
}

// ================= host =================
extern "C" void kernel_launch(void* const* d_in, const int* in_sizes, int n_in,
                              void* d_out, int out_size, void* d_ws, size_t ws_size,
                              hipStream_t stream) {
    (void)in_sizes; (void)n_in; (void)out_size; (void)ws_size;
    const float* pts = (const float*)d_in[0];
    const float* W1 = (const float*)d_in[1];
    const float* b1 = (const float*)d_in[2];
    const float* g1 = (const float*)d_in[3];
    const float* be1 = (const float*)d_in[4];
    const float* m1 = (const float*)d_in[5];
    const float* v1 = (const float*)d_in[6];
    const float* W2 = (const float*)d_in[7];
    const float* b2 = (const float*)d_in[8];
    const float* W3 = (const float*)d_in[9];
    const float* b3 = (const float*)d_in[10];
    const float* g2 = (const float*)d_in[11];
    const float* be2 = (const float*)d_in[12];
    const float* m2 = (const float*)d_in[13];
    const float* v2 = (const float*)d_in[14];
    const float* W4 = (const float*)d_in[15];
    const float* b4 = (const float*)d_in[16];
    const float* D1W = (const float*)d_in[17];
    const float* D1b = (const float*)d_in[18];
    const float* D2W = (const float*)d_in[19];
    const float* D2b = (const float*)d_in[20];
    const float* D3W = (const float*)d_in[21];
    const float* D3b = (const float*)d_in[22];
    const float* D4W = (const float*)d_in[23];
    const float* D4b = (const float*)d_in[24];

    char* ws = (char*)d_ws;
    size_t off = 0;
    auto alloc = [&](size_t bytes) -> void* {
        void* p = ws + off;
        off += (bytes + 255) & ~(size_t)255;
        return p;
    };
    float* center   = (float*)alloc((size_t)BSZ * NG * 3 * 4);
    int*   knnc     = (int*)  alloc((size_t)BSZ * NG * GS * 4);
    float* rebuild0 = (float*)alloc((size_t)BSZ * 2048 * 3 * 4);
    float* rebuild1 = (float*)alloc((size_t)BSZ * 1024 * 3 * 4);
    f16*   W2h      = (f16*)  alloc((size_t)256 * 128 * 2);
    f16*   W3h      = (f16*)  alloc((size_t)512 * 256 * 2);
    f16*   W4h      = (f16*)  alloc((size_t)1024 * 512 * 2);
    f16*   H1h      = (f16*)  alloc((size_t)BSZ * 2048 * 128 * 2);
    f16*   H2h      = (f16*)  alloc((size_t)BSZ * 2048 * 256 * 2);
    f16*   H3h      = (f16*)  alloc((size_t)BSZ * 2048 * 512 * 2);
    unsigned* gmaxkey = (unsigned*)alloc((size_t)BSZ * 256 * 4);
    float* gmaxb    = (float*)alloc((size_t)BSZ * 256 * 4);
    float* gpart    = (float*)alloc((size_t)BSZ * 512 * 4);
    unsigned* featkey = (unsigned*)alloc((size_t)BSZ * 1024 * 4);
    float* feat     = (float*)alloc((size_t)BSZ * 1024 * 4);
    float* featrec  = (float*)alloc((size_t)BSZ * 1024 * 4);
    float* dh1      = (float*)alloc((size_t)BSZ * 2048 * 4);
    float* dh2      = (float*)alloc((size_t)BSZ * 2048 * 4);
    float* dh3      = (float*)alloc((size_t)BSZ * 2048 * 4);
    float* pred     = (float*)alloc((size_t)BSZ * 6144 * 4);
    int*   idxa     = (int*)  alloc((size_t)BSZ * 64 * NBRK * 4);
    float* gatha    = (float*)alloc((size_t)BSZ * 64 * NBRK * 3 * 4);
    int*   idxb     = (int*)  alloc((size_t)BSZ * 32 * NBRK * 4);
    float* gathb    = (float*)alloc((size_t)BSZ * 32 * NBRK * 3 * 4);
    int*   idxc     = (int*)  alloc((size_t)BSZ * 32 * 32 * 4);
    float* gathc    = (float*)alloc((size_t)BSZ * 1024 * 3 * 4);
    int*   knn32    = (int*)  alloc((size_t)BSZ * 2048 * 32 * 4);
    float* nrmbuf   = (float*)alloc((size_t)BSZ * 2048 * 3 * 4);
    float* accum    = (float*)alloc(8 * 4);

    hipMemsetAsync(accum, 0, 8 * 4, stream);

    cvt_w_kernel<<<(256 * 128 + 255) / 256, 256, 0, stream>>>(W2, 128, 0, 128, W2h, 256 * 128);
    cvt_w_kernel<<<(512 * 256 + 255) / 256, 256, 0, stream>>>(W3, 512, 256, 256, W3h, 512 * 256);
    cvt_w_kernel<<<(1024 * 512 + 255) / 256, 256, 0, stream>>>(W4, 512, 0, 512, W4h, 1024 * 512);

    auto knn = [&](const float* Q, int q_bstride, int q_off, int nq,
                   const float* DB, int k, int* out) {
        int total = BSZ * nq;
        knn_kernel_v7<<<(total + 3) / 4, 256, 0, stream>>>(Q, q_bstride, q_off, nq,
                                                           DB, k, out, BSZ);
    };

    // FPS + grouping
    fps_kernel_v5<<<BSZ, 256, 0, stream>>>(pts, center);
    knn(center, NG, 0, NG, pts, GS, knnc);
    gather_points_kernel<<<(BSZ * 2048 + 255) / 256, 256, 0, stream>>>(pts, NPTS, knnc, NG * GS,
                                                                       0, 2048, rebuild0, BSZ);
    gather_points_kernel<<<(BSZ * 1024 + 255) / 256, 256, 0, stream>>>(pts, NPTS, knnc, NG * GS,
                                                                       2048, 1024, rebuild1, BSZ);

    auto enc = [&](const float* X, int n, float* featout) {
        int M = BSZ * n;
        layer1_kernel<<<M / 16, 256, 0, stream>>>(X, W1, b1, g1, be1, m1, v1, H1h, M);
        hipMemsetAsync(gmaxkey, 0, (size_t)BSZ * 256 * 4, stream);
        mfma_gemm_kernel<<<dim3(256 / 128, M / 128), 256, 0, stream>>>(
            H1h, W2h, 128, 256, b2, nullptr, nullptr, nullptr, nullptr, nullptr,
            H2h, gmaxkey, n, 0);
        decode_kernel<<<(BSZ * 256 + 255) / 256, 256, 0, stream>>>(gmaxkey, gmaxb, BSZ * 256);
        skinny_v2_kernel<<<(512 + 3) / 4, 256, 0, stream>>>(gmaxb, W3, 512, 0, b3,
                                                            gpart, 256, 512, 0);
        mfma_gemm_kernel<<<dim3(512 / 128, M / 128), 256, 0, stream>>>(
            H2h, W3h, 256, 512, nullptr, gpart, g2, be2, m2, v2, H3h, nullptr, n, 1);
        hipMemsetAsync(featkey, 0, (size_t)BSZ * 1024 * 4, stream);
        mfma_gemm_kernel<<<dim3(1024 / 128, M / 128), 256, 0, stream>>>(
            H3h, W4h, 512, 1024, b4, nullptr, nullptr, nullptr, nullptr, nullptr,
            nullptr, featkey, n, 0);
        decode_kernel<<<(BSZ * 1024 + 255) / 256, 256, 0, stream>>>(featkey, featout, BSZ * 1024);
    };

    enc(rebuild0, 2048, feat);

    // decoder (skinny M=16, fp32, coalesced)
    skinny_v2_kernel<<<2048 / 4, 256, 0, stream>>>(feat, D1W, 1024, 0, D1b, dh1, 1024, 2048, 1);
    skinny_v2_kernel<<<2048 / 4, 256, 0, stream>>>(dh1, D2W, 2048, 0, D2b, dh2, 2048, 2048, 1);
    skinny_v2_kernel<<<2048 / 4, 256, 0, stream>>>(dh2, D3W, 2048, 0, D3b, dh3, 2048, 2048, 1);
    skinny_v2_kernel<<<6144 / 4, 256, 0, stream>>>(dh3, D4W, 2048, 0, D4b, pred, 2048, 6144, 0);

    // l_recon
    knn(center, NG, 0, 64, pred, NBRK, idxa);
    gather_points_kernel<<<(BSZ * 2432 + 255) / 256, 256, 0, stream>>>(pred, 2048, idxa, 64 * NBRK,
                                                                       0, 2432, gatha, BSZ);
    chamfer_min_kernel<<<(BSZ * 2048 * 8 + 255) / 256, 256, 0, stream>>>(rebuild0, 2048,
                                                                         gatha, 2432, accum + 0);
    chamfer_min_kernel<<<(BSZ * 2432 * 8 + 255) / 256, 256, 0, stream>>>(gatha, 2432,
                                                                         rebuild0, 2048, accum + 1);
    // l_match
    knn(center, NG, 64, 32, pred, NBRK, idxb);
    gather_points_kernel<<<(BSZ * 1216 + 255) / 256, 256, 0, stream>>>(pred, 2048, idxb, 32 * NBRK,
                                                                       0, 1216, gathb, BSZ);
    chamfer_min_kernel<<<(BSZ * 1024 * 8 + 255) / 256, 256, 0, stream>>>(rebuild1, 1024,
                                                                         gathb, 1216, accum + 2);
    chamfer_min_kernel<<<(BSZ * 1216 * 8 + 255) / 256, 256, 0, stream>>>(gathb, 1216,
                                                                         rebuild1, 1024, accum + 3);
    // l_latent
    knn(center, NG, 96, 32, pred, 32, idxc);
    gather_points_kernel<<<(BSZ * 1024 + 255) / 256, 256, 0, stream>>>(pred, 2048, idxc, 32 * 32,
                                                                       0, 1024, gathc, BSZ);
    enc(gathc, 1024, featrec);
    latent_kernel<<<(BSZ * 1024 + 255) / 256, 256, 0, stream>>>(feat, featrec, BSZ * 1024,
                                                                accum + 4);
    // l_man: one self-KNN (k=32); manifold uses first 8 (stable top-k prefix)
    knn(pred, 2048, 0, 2048, pred, 32, knn32);
    normals_kernel<<<(BSZ * 2048 + 255) / 256, 256, 0, stream>>>(pred, knn32, nrmbuf);
    manifold_kernel<<<(BSZ * 2048 + 255) / 256, 256, 0, stream>>>(nrmbuf, knn32, 32, accum + 5);

    finalize_kernel<<<1, 1, 0, stream>>>(accum, (float*)d_out);
}

// Round 4
// 889.667 us; speedup vs baseline: 1.1085x; 1.0409x over previous
//
#include <hip/hip_runtime.h>
#include <math.h>

#define BSZ 16
#define NPTS 2048
#define NG 128
#define GS 32
#define NBRK 38

typedef _Float16 f16;
typedef _Float16 f16x8 __attribute__((ext_vector_type(8)));
typedef float f32x4 __attribute__((ext_vector_type(4)));

// ---------- helpers ----------
__device__ __forceinline__ unsigned fkey(float x) {
    unsigned u = __float_as_uint(x);
    return (u >> 31) ? ~u : (u | 0x80000000u);
}
__device__ __forceinline__ float fkey_inv(unsigned k) {
    unsigned u = (k >> 31) ? (k ^ 0x80000000u) : ~k;
    return __uint_as_float(u);
}

// 64-lane min via DPP (no LDS/DS pipe): row_shr 1/2/4/8 prefix + row_bcast 15/31,
// then readlane 63 broadcasts the full-wave min. gfx9-lineage DPP (CDNA keeps it).
__device__ __forceinline__ unsigned wave_min_u32(unsigned v) {
    unsigned t;
    t = (unsigned)__builtin_amdgcn_update_dpp(-1, (int)v, 0x111, 0xF, 0xF, false);
    v = v < t ? v : t;
    t = (unsigned)__builtin_amdgcn_update_dpp(-1, (int)v, 0x112, 0xF, 0xF, false);
    v = v < t ? v : t;
    t = (unsigned)__builtin_amdgcn_update_dpp(-1, (int)v, 0x114, 0xF, 0xF, false);
    v = v < t ? v : t;
    t = (unsigned)__builtin_amdgcn_update_dpp(-1, (int)v, 0x118, 0xF, 0xF, false);
    v = v < t ? v : t;
    t = (unsigned)__builtin_amdgcn_update_dpp(-1, (int)v, 0x142, 0xA, 0xF, false);
    v = v < t ? v : t;
    t = (unsigned)__builtin_amdgcn_update_dpp(-1, (int)v, 0x143, 0xC, 0xF, false);
    v = v < t ? v : t;
    return (unsigned)__builtin_amdgcn_readlane((int)v, 63);
}

// 64-lane max of a u64 key via DPP: one chain handles (value, tiebreak) packed.
// old=0 is the identity for unsigned max.
__device__ __forceinline__ unsigned long long wave_max_u64(unsigned long long v) {
#define DPPSTEP(ctrl, rmask)                                                                \
    {                                                                                       \
        unsigned tlo = (unsigned)__builtin_amdgcn_update_dpp(0, (int)(unsigned)v, ctrl,     \
                                                             rmask, 0xF, false);            \
        unsigned thi = (unsigned)__builtin_amdgcn_update_dpp(0, (int)(unsigned)(v >> 32),   \
                                                             ctrl, rmask, 0xF, false);      \
        unsigned long long t = ((unsigned long long)thi << 32) | tlo;                       \
        v = t > v ? t : v;                                                                  \
    }
    DPPSTEP(0x111, 0xF)
    DPPSTEP(0x112, 0xF)
    DPPSTEP(0x114, 0xF)
    DPPSTEP(0x118, 0xF)
    DPPSTEP(0x142, 0xA)
    DPPSTEP(0x143, 0xC)
#undef DPPSTEP
    unsigned rlo = (unsigned)__builtin_amdgcn_readlane((int)(unsigned)v, 63);
    unsigned rhi = (unsigned)__builtin_amdgcn_readlane((int)(unsigned)(v >> 32), 63);
    return ((unsigned long long)rhi << 32) | rlo;
}

// ---------- FPS v5: 4 waves, one barrier/iter, parity-buffered wave slots ----------
// 256 threads, 8 pts/lane. Per iter: per-lane fused argmax (2 strict-> chains,
// ascending m => min index), ONE u64 DPP max per wave on key=(bits(best)<<32)|~j,
// lanes 0-2 prefetch wave-winner coords from LDS pre-barrier, {key,x,y,z} ->
// parity slot; ONE __syncthreads; all threads combine 4 slots. Parity double-
// buffer makes the single barrier race-free. Tie-break == jnp.argmax exactly.
__global__ __launch_bounds__(256, 1) void fps_kernel_v5(const float* __restrict__ pts,
                                                        float* __restrict__ center) {
    int b = blockIdx.x;
    const float* P = pts + (size_t)b * NPTS * 3;
    int tid = threadIdx.x;
    int lane = tid & 63, wave = tid >> 6;
    __shared__ __align__(16) float Pl[NPTS * 3];
    __shared__ __align__(16) float slot[2][4][8];   // [parity][wave]{klo,khi,x,y,z,...}
#pragma unroll
    for (int i = 0; i < 6; ++i) {    // 1536 float4 = 24 KB, coalesced
        int v4 = tid + i * 256;
        ((f32x4*)Pl)[v4] = ((const f32x4*)P)[v4];
    }
    __syncthreads();
    float px[8], py[8], pz[8], mind[8];
#pragma unroll
    for (int m = 0; m < 8; ++m) {
        int j = tid + (m << 8);
        px[m] = Pl[j * 3 + 0];
        py[m] = Pl[j * 3 + 1];
        pz[m] = Pl[j * 3 + 2];
        mind[m] = 1e10f;
    }
    float cx = Pl[0], cy = Pl[1], cz = Pl[2];   // far = 0
    float* C = center + (size_t)b * NG * 3;
#pragma unroll 1
    for (int g = 0; g < NG; ++g) {
        if (tid == 0) {
            C[g * 3 + 0] = cx; C[g * 3 + 1] = cy; C[g * 3 + 2] = cz;
        }
        if (g == NG - 1) break;      // uniform: all threads exit together
        float best0 = -1.f, best1 = -1.f;
        int bm0 = 0, bm1 = 1;
#pragma unroll
        for (int m = 0; m < 8; m += 2) {   // 2 independent dep chains
            float dx0 = px[m] - cx, dy0 = py[m] - cy, dz0 = pz[m] - cz;
            float d0 = dx0 * dx0 + dy0 * dy0 + dz0 * dz0;
            float md0 = fminf(mind[m], d0);
            mind[m] = md0;
            if (md0 > best0) { best0 = md0; bm0 = m; }        // strict >: min m on tie
            float dx1 = px[m + 1] - cx, dy1 = py[m + 1] - cy, dz1 = pz[m + 1] - cz;
            float d1 = dx1 * dx1 + dy1 * dy1 + dz1 * dz1;
            float md1 = fminf(mind[m + 1], d1);
            mind[m + 1] = md1;
            if (md1 > best1) { best1 = md1; bm1 = m + 1; }
        }
        bool t = (best1 > best0) || (best1 == best0 && bm1 < bm0);
        float bv = t ? best1 : best0;
        int bi = t ? bm1 : bm0;
        unsigned j = (unsigned)(tid + (bi << 8));   // global point index
        // bv >= 0 so float bits order as u32; ~j => u64-max picks min index on ties
        unsigned long long key =
            ((unsigned long long)__float_as_uint(bv) << 32) | (unsigned)(~j);
        key = wave_max_u64(key);                    // broadcast to all lanes
        unsigned bj = ~(unsigned)key;
        int par = g & 1;
        if (lane < 3) slot[par][wave][2 + lane] = Pl[bj * 3 + lane];  // prefetch coords
        if (lane == 0) {
            slot[par][wave][0] = __uint_as_float((unsigned)key);
            slot[par][wave][1] = __uint_as_float((unsigned)(key >> 32));
        }
        __syncthreads();
        // combine 4 wave slots (uniform across all threads)
        unsigned long long kb = 0ull;
        float nx = 0.f, ny = 0.f, nz = 0.f;
#pragma unroll
        for (int w = 0; w < 4; ++w) {
            f32x4 v = *(const f32x4*)&slot[par][w][0];   // klo,khi,x,y
            float vz = slot[par][w][4];
            unsigned long long kk =
                ((unsigned long long)__float_as_uint(v[1]) << 32) | __float_as_uint(v[0]);
            bool tw = kk > kb;
            kb = tw ? kk : kb;
            nx = tw ? v[2] : nx;
            ny = tw ? v[3] : ny;
            nz = tw ? vz : nz;
        }
        cx = nx; cy = ny; cz = nz;
    }
}

// ---------- KNN v7: 32-bit packed keys + DPP wave-min, zero DS ops ----------
// key = (quantized_dist << 11) | idx ; u32 order == (d, idx) lex order up to the
// 1/8192 distance quantum (idx breaks quantized ties; matches stable top_k
// except between points closer than 1.2e-4 in squared distance -- negligible).
// Per-lane top-4 key cache + watermark refill (rare); wave per query; no barriers.
__global__ void knn_kernel_v7(const float* __restrict__ Q, int q_bstride, int q_off, int nq,
                              const float* __restrict__ DB, int k,
                              int* __restrict__ out, int nbatch) {
    const unsigned KINF = 0xFFFFFFFFu;
    int wave = threadIdx.x >> 6, lane = threadIdx.x & 63;
    int qidx = blockIdx.x * 4 + wave;
    if (qidx >= nbatch * nq) return;     // wave-uniform
    int b = qidx / nq, qi = qidx % nq;
    const float* q = Q + ((size_t)b * q_bstride + q_off + qi) * 3;
    float qx = q[0], qy = q[1], qz = q[2];
    float qq = qx * qx + qy * qy + qz * qz;
    const float* db = DB + (size_t)b * NPTS * 3;

    unsigned key[32];
    unsigned c0 = KINF, c1 = KINF, c2 = KINF, c3 = KINF;
#pragma unroll
    for (int m = 0; m < 32; ++m) {
        int j = lane + (m << 6);
        float bx = db[j * 3 + 0], by = db[j * 3 + 1], bz = db[j * 3 + 2];
        float dv = qq + bx * bx + by * by + bz * bz - 2.0f * (qx * bx + qy * by + qz * bz);
        unsigned qd = (unsigned)fminf(fmaxf(dv, 0.f) * 8192.0f, 2097151.f);
        unsigned kk = (qd << 11) | (unsigned)j;
        key[m] = kk;
        if (kk < c3) {
            if (kk < c2) {
                c3 = c2;
                if (kk < c1) {
                    c2 = c1;
                    if (kk < c0) { c1 = c0; c0 = kk; } else c1 = kk;
                } else c2 = kk;
            } else c3 = kk;
        }
    }
    unsigned hw = c3;        // high-water: largest key ever cached (init: 4th best)
    int ncached = 4;
    int* o = out + (size_t)qidx * k;

    for (int r = 0; r < k; ++r) {
        bool need = (c0 == KINF) && (ncached < 32);
        if (__any(need)) {
            unsigned best = KINF;
#pragma unroll
            for (int m = 0; m < 32; ++m) {
                unsigned v = key[m];
                best = (v > hw && v < best) ? v : best;
            }
            if (need) {
                c0 = best;
                hw = best;
                ncached = (best == KINF) ? 32 : ncached + 1;
            }
        }
        unsigned g = wave_min_u32(c0);
        if (lane == 0) o[r] = (int)(g & 0x7FFu);
        if (((g & 0x7FFu) & 63u) == (unsigned)lane) {  // owner pops its c0 (== g)
            c0 = c1; c1 = c2; c2 = c3; c3 = KINF;
        }
    }
}

// ---------- gather points via index array ----------
__global__ void gather_points_kernel(const float* __restrict__ pts, int db_bstride,
                                     const int* __restrict__ idx, int idx_bstride, int idx_off,
                                     int m, float* __restrict__ out, int nbatch) {
    int t = blockIdx.x * blockDim.x + threadIdx.x;
    if (t >= nbatch * m) return;
    int b = t / m, j = t % m;
    int s = idx[(size_t)b * idx_bstride + idx_off + j];
    const float* p = pts + ((size_t)b * db_bstride + s) * 3;
    out[(size_t)t * 3 + 0] = p[0];
    out[(size_t)t * 3 + 1] = p[1];
    out[(size_t)t * 3 + 2] = p[2];
}

// ---------- fp32 -> fp16 weight conversion (strided slice) ----------
__global__ void cvt_w_kernel(const float* __restrict__ in, int ld, int off, int K,
                             f16* __restrict__ out, int total) {
    int t = blockIdx.x * blockDim.x + threadIdx.x;
    if (t >= total) return;
    int n = t / K, k = t % K;
    out[t] = (f16)in[(size_t)n * ld + off + k];
}

// ---------- layer1: H1 = relu(bn(x @ W1^T + b1)) in fp16, fused ----------
__global__ void layer1_kernel(const float* __restrict__ X, const float* __restrict__ W1,
                              const float* __restrict__ b1, const float* __restrict__ g1,
                              const float* __restrict__ be1, const float* __restrict__ m1,
                              const float* __restrict__ v1, f16* __restrict__ H1, int M) {
    __shared__ float w[384], bb[128], sg[128], sb[128], sm[128], sv[128];
    for (int i = threadIdx.x; i < 384; i += 256) w[i] = W1[i];
    if (threadIdx.x < 128) {
        int c = threadIdx.x;
        bb[c] = b1[c]; sg[c] = g1[c]; sb[c] = be1[c]; sm[c] = m1[c]; sv[c] = v1[c];
    }
    __syncthreads();
    int t = blockIdx.x * 256 + threadIdx.x;
    if (t >= M * 16) return;
    int row = t >> 4, cg = (t & 15) * 8;
    float x0 = X[(size_t)row * 3], x1 = X[(size_t)row * 3 + 1], x2 = X[(size_t)row * 3 + 2];
    f16x8 outv;
#pragma unroll
    for (int j = 0; j < 8; ++j) {
        int c = cg + j;
        float tv = x0 * w[c * 3] + x1 * w[c * 3 + 1] + x2 * w[c * 3 + 2] + bb[c];
        float vv = (tv - sm[c]) * rsqrtf(sv[c] + 1e-5f) * sg[c] + sb[c];
        outv[j] = (f16)fmaxf(vv, 0.f);
    }
    *(f16x8*)&H1[(size_t)row * 128 + cg] = outv;
}

// ---------- MFMA GEMM ----------
__global__ __launch_bounds__(256) void mfma_gemm_kernel(
        const f16* __restrict__ A, const f16* __restrict__ W, int K, int N,
        const float* __restrict__ bias, const float* __restrict__ bias2d,
        const float* __restrict__ bng, const float* __restrict__ bnb,
        const float* __restrict__ bnm, const float* __restrict__ bnv,
        f16* __restrict__ Cout, unsigned* __restrict__ maxkey,
        int rows_per_batch, int relu) {
    __shared__ f16 Als[128 * 40];
    __shared__ f16 Bls[128 * 40];
    int tid = threadIdx.x;
    int lane = tid & 63;
    int wave = tid >> 6;
    int wm = wave & 1, wn = wave >> 1;
    int c16 = lane & 15, quad = lane >> 4;
    int row0 = blockIdx.y * 128, col0 = blockIdx.x * 128;
    int sr = tid >> 2;
    int skc = (tid & 3) * 8;

    f32x4 acc[4][4];
#pragma unroll
    for (int i = 0; i < 4; ++i)
#pragma unroll
        for (int j = 0; j < 4; ++j) acc[i][j] = (f32x4){0.f, 0.f, 0.f, 0.f};

    for (int k0 = 0; k0 < K; k0 += 32) {
#pragma unroll
        for (int i = 0; i < 2; ++i) {
            int r2 = sr + i * 64;
            f16x8 av = *(const f16x8*)(A + (size_t)(row0 + r2) * K + k0 + skc);
            *(f16x8*)&Als[r2 * 40 + skc] = av;
            f16x8 bv = *(const f16x8*)(W + (size_t)(col0 + r2) * K + k0 + skc);
            *(f16x8*)&Bls[r2 * 40 + skc] = bv;
        }
        __syncthreads();
        f16x8 af[4], bf[4];
#pragma unroll
        for (int s = 0; s < 4; ++s) {
            af[s] = *(const f16x8*)&Als[(wm * 64 + s * 16 + c16) * 40 + quad * 8];
            bf[s] = *(const f16x8*)&Bls[(wn * 64 + s * 16 + c16) * 40 + quad * 8];
        }
#pragma unroll
        for (int ms = 0; ms < 4; ++ms)
#pragma unroll
            for (int ns = 0; ns < 4; ++ns)
                acc[ms][ns] = __builtin_amdgcn_mfma_f32_16x16x32_f16(af[ms], bf[ns],
                                                                     acc[ms][ns], 0, 0, 0);
        __syncthreads();
    }

    int b = row0 / rows_per_batch;
#pragma unroll
    for (int ns = 0; ns < 4; ++ns) {
        int col = col0 + wn * 64 + ns * 16 + c16;
        float bv = bias ? bias[col] : 0.f;
        float b2v = bias2d ? bias2d[(size_t)b * N + col] : 0.f;
        float mx = -3e38f;
#pragma unroll
        for (int ms = 0; ms < 4; ++ms) {
#pragma unroll
            for (int j = 0; j < 4; ++j) {
                float v = acc[ms][ns][j] + bv + b2v;
                if (bng) v = (v - bnm[col]) * rsqrtf(bnv[col] + 1e-5f) * bng[col] + bnb[col];
                if (relu) v = fmaxf(v, 0.f);
                if (Cout)
                    Cout[(size_t)(row0 + wm * 64 + ms * 16 + quad * 4 + j) * N + col] = (f16)v;
                mx = fmaxf(mx, v);
            }
        }
        if (maxkey) {
            mx = fmaxf(mx, __shfl_xor(mx, 16, 64));
            mx = fmaxf(mx, __shfl_xor(mx, 32, 64));
            if (quad == 0) atomicMax(&maxkey[(size_t)b * N + col], fkey(mx));
        }
    }
}

// ---------- skinny GEMM v2: wave per column, coalesced float4 ----------
__global__ void skinny_v2_kernel(const float* __restrict__ A, const float* __restrict__ W,
                                 int ldw, int woff, const float* __restrict__ bias,
                                 float* __restrict__ C, int K, int N, int relu) {
    int wave = threadIdx.x >> 6, lane = threadIdx.x & 63;
    int col = blockIdx.x * 4 + wave;
    if (col >= N) return;
    const float* w = W + (size_t)col * ldw + woff;
    float acc[16];
#pragma unroll
    for (int m = 0; m < 16; ++m) acc[m] = 0.f;
    for (int k0 = 0; k0 < K; k0 += 256) {
        f32x4 wv = *(const f32x4*)(w + k0 + lane * 4);
#pragma unroll
        for (int m = 0; m < 16; ++m) {
            f32x4 av = *(const f32x4*)(A + (size_t)m * K + k0 + lane * 4);
            acc[m] += av[0] * wv[0] + av[1] * wv[1] + av[2] * wv[2] + av[3] * wv[3];
        }
    }
#pragma unroll
    for (int m = 0; m < 16; ++m)
#pragma unroll
        for (int s = 1; s < 64; s <<= 1) acc[m] += __shfl_xor(acc[m], s, 64);
    if (lane == 0) {
        float bv = bias[col];
#pragma unroll
        for (int m = 0; m < 16; ++m) {
            float v = acc[m] + bv;
            if (relu) v = fmaxf(v, 0.f);
            C[(size_t)m * N + col] = v;
        }
    }
}

__global__ void decode_kernel(const unsigned* __restrict__ k, float* __restrict__ f, int n) {
    int t = blockIdx.x * blockDim.x + threadIdx.x;
    if (t < n) f[t] = fkey_inv(k[t]);
}

// ---------- chamfer v2: 8 lanes per A-point, j-strided, shfl-min ----------
__global__ void chamfer_min_kernel(const float* __restrict__ A, int na,
                                   const float* __restrict__ Bp, int nb,
                                   float* __restrict__ slot) {
    int t = blockIdx.x * 256 + threadIdx.x;
    int pt = t >> 3, sl = t & 7;
    float val = 0.f;
    if (pt < BSZ * na) {
        int b = pt / na;
        const float* a = A + (size_t)pt * 3;
        float ax = a[0], ay = a[1], az = a[2];
        float aa = ax * ax + ay * ay + az * az;
        const float* Bb = Bp + (size_t)b * nb * 3;
        float m = 3e38f;
        for (int j = sl; j < nb; j += 8) {
            float bx = Bb[j * 3 + 0], by = Bb[j * 3 + 1], bz = Bb[j * 3 + 2];
            float d = aa + bx * bx + by * by + bz * bz - 2.0f * (ax * bx + ay * by + az * bz);
            m = fminf(m, d);
        }
#pragma unroll
        for (int s = 1; s < 8; s <<= 1) m = fminf(m, __shfl_xor(m, s, 64));
        if (sl == 0) val = sqrtf(fmaxf(m, 1e-12f));
    }
    __shared__ float sdata[256];
    sdata[threadIdx.x] = val;
    __syncthreads();
    for (int s = 128; s > 0; s >>= 1) {
        if (threadIdx.x < s) sdata[threadIdx.x] += sdata[threadIdx.x + s];
        __syncthreads();
    }
    if (threadIdx.x == 0) atomicAdd(slot, sdata[0]);
}

// ---------- smooth-L1 latent loss sum ----------
__global__ void latent_kernel(const float* __restrict__ f1, const float* __restrict__ f2,
                              int n, float* __restrict__ slot) {
    int t = blockIdx.x * blockDim.x + threadIdx.x;
    float val = 0.f;
    if (t < n) {
        float d = f1[t] - f2[t];
        float ad = fabsf(d);
        val = (ad < 1.f) ? (0.5f * d * d) : (ad - 0.5f);
    }
    __shared__ float sdata[256];
    sdata[threadIdx.x] = val;
    __syncthreads();
    for (int s = 128; s > 0; s >>= 1) {
        if (threadIdx.x < s) sdata[threadIdx.x] += sdata[threadIdx.x + s];
        __syncthreads();
    }
    if (threadIdx.x == 0) atomicAdd(slot, sdata[0]);
}

// ---------- 3x3 symmetric smallest eigenvector (double, analytic) ----------
__device__ void smallest_evec(double cxx, double cxy, double cxz,
                              double cyy, double cyz, double czz, double ev[3]) {
    double p1 = cxy * cxy + cxz * cxz + cyz * cyz;
    double q = (cxx + cyy + czz) / 3.0;
    double p2 = (cxx - q) * (cxx - q) + (cyy - q) * (cyy - q) + (czz - q) * (czz - q) + 2.0 * p1;
    double lam = q;
    if (p2 > 0.0) {
        double p = sqrt(p2 / 6.0);
        double b00 = (cxx - q) / p, b11 = (cyy - q) / p, b22 = (czz - q) / p;
        double b01 = cxy / p, b02 = cxz / p, b12 = cyz / p;
        double detB = b00 * (b11 * b22 - b12 * b12) - b01 * (b01 * b22 - b12 * b02)
                    + b02 * (b01 * b12 - b11 * b02);
        double r = detB * 0.5;
        r = r < -1.0 ? -1.0 : (r > 1.0 ? 1.0 : r);
        double phi = acos(r) / 3.0;
        lam = q + 2.0 * p * cos(phi + 2.0943951023931953);
    }
    double r0x = cxx - lam, r0y = cxy, r0z = cxz;
    double r1x = cxy, r1y = cyy - lam, r1z = cyz;
    double r2x = cxz, r2y = cyz, r2z = czz - lam;
    double c0x = r0y * r1z - r0z * r1y, c0y = r0z * r1x - r0x * r1z, c0z = r0x * r1y - r0y * r1x;
    double c1x = r0y * r2z - r0z * r2y, c1y = r0z * r2x - r0x * r2z, c1z = r0x * r2y - r0y * r2x;
    double c2x = r1y * r2z - r1z * r2y, c2y = r1z * r2x - r1x * r2z, c2z = r1x * r2y - r1y * r2x;
    double n0 = c0x * c0x + c0y * c0y + c0z * c0z;
    double n1 = c1x * c1x + c1y * c1y + c1z * c1z;
    double n2 = c2x * c2x + c2y * c2y + c2z * c2z;
    double bx = c0x, by = c0y, bz = c0z, bn = n0;
    if (n1 > bn) { bx = c1x; by = c1y; bz = c1z; bn = n1; }
    if (n2 > bn) { bx = c2x; by = c2y; bz = c2z; bn = n2; }
    if (bn < 1e-280) { ev[0] = 1.0; ev[1] = 0.0; ev[2] = 0.0; return; }
    double inv = 1.0 / sqrt(bn);
    ev[0] = bx * inv; ev[1] = by * inv; ev[2] = bz * inv;
}

// ---------- normals v2: single-pass moments, zero per-thread arrays ----------
// cov = E[pp^T] - mean mean^T via 9 double accumulators (18 VGPRs) -- no px/py/pz
// arrays, no scratch spill (R3 counters: 27 MB scratch writes at VGPR=64).
// Sign projection needs no stored points: sum_k (p_k - q) . ev = (s - 32 q) . ev.
// Single-pass-double vs two-pass-double diff ~1e-13 rel: invisible at this
// problem's tolerance. Block=64 -> 512 workgroups covers all 256 CUs.
__global__ __launch_bounds__(64) void normals_kernel(const float* __restrict__ pred,
                                                     const int* __restrict__ knn,
                                                     float* __restrict__ nrm) {
    int t = blockIdx.x * 64 + threadIdx.x;
    if (t >= BSZ * NPTS) return;
    int b = t / NPTS, i = t % NPTS;
    const float* P = pred + (size_t)b * NPTS * 3;
    const int* id = knn + (size_t)t * 32;
    double sx = 0, sy = 0, sz = 0;
    double sxx = 0, sxy = 0, sxz = 0, syy = 0, syz = 0, szz = 0;
#pragma unroll
    for (int k0 = 0; k0 < 32; k0 += 4) {
        int4 jj = *(const int4*)&id[k0];   // id is 128B-aligned (t*32 ints)
#pragma unroll
        for (int u = 0; u < 4; ++u) {
            int j = (u == 0) ? jj.x : (u == 1) ? jj.y : (u == 2) ? jj.z : jj.w;
            double x = (double)P[j * 3 + 0];
            double y = (double)P[j * 3 + 1];
            double z = (double)P[j * 3 + 2];
            sx += x; sy += y; sz += z;
            sxx += x * x; sxy += x * y; sxz += x * z;
            syy += y * y; syz += y * z; szz += z * z;
        }
    }
    double mx = sx * (1.0 / 32.0), my = sy * (1.0 / 32.0), mz = sz * (1.0 / 32.0);
    double cxx = sxx * (1.0 / 32.0) - mx * mx;
    double cxy = sxy * (1.0 / 32.0) - mx * my;
    double cxz = sxz * (1.0 / 32.0) - mx * mz;
    double cyy = syy * (1.0 / 32.0) - my * my;
    double cyz = syz * (1.0 / 32.0) - my * mz;
    double czz = szz * (1.0 / 32.0) - mz * mz;
    double ev[3];
    smallest_evec(cxx, cxy, cxz, cyy, cyz, czz, ev);
    float qx = P[i * 3 + 0], qy = P[i * 3 + 1], qz = P[i * 3 + 2];
    double proj = (sx - 32.0 * (double)qx) * ev[0] + (sy - 32.0 * (double)qy) * ev[1]
                + (sz - 32.0 * (double)qz) * ev[2];
    double s = (proj >= 0.0) ? 1.0 : -1.0;
    nrm[(size_t)t * 3 + 0] = (float)(ev[0] * s);
    nrm[(size_t)t * 3 + 1] = (float)(ev[1] * s);
    nrm[(size_t)t * 3 + 2] = (float)(ev[2] * s);
}

// ---------- manifold loss: reads first 8 of the 32-NN list ----------
__global__ void manifold_kernel(const float* __restrict__ nrm, const int* __restrict__ knn,
                                int kstride, float* __restrict__ slot) {
    int t = blockIdx.x * blockDim.x + threadIdx.x;
    float val = 0.f;
    if (t < BSZ * NPTS) {
        int b = t / NPTS;
        const float* NB = nrm + (size_t)b * NPTS * 3;
        const int* id = knn + (size_t)t * kstride;
        int j0 = id[0];
        float ax = NB[j0 * 3 + 0], ay = NB[j0 * 3 + 1], az = NB[j0 * 3 + 2];
        float an = fmaxf(sqrtf(ax * ax + ay * ay + az * az), 1e-6f);
        float x[8]; float s = 0.f;
        for (int k = 0; k < 8; ++k) {
            int j = id[k];
            float bx = NB[j * 3 + 0], by = NB[j * 3 + 1], bz = NB[j * 3 + 2];
            float bn_ = fmaxf(sqrtf(bx * bx + by * by + bz * bz), 1e-6f);
            float c = (ax * bx + ay * by + az * bz) / (an * bn_);
            x[k] = 1.f - c; s += x[k];
        }
        float mean = s / 8.f;
        float var = 0.f;
        for (int k = 0; k < 8; ++k) { float d = x[k] - mean; var += d * d; }
        val = sqrtf(var / 7.f);
    }
    __shared__ float sdata[256];
    sdata[threadIdx.x] = val;
    __syncthreads();
    for (int s2 = 128; s2 > 0; s2 >>= 1) {
        if (threadIdx.x < s2) sdata[threadIdx.x] += sdata[threadIdx.x + s2];
        __syncthreads();
    }
    if (threadIdx.x == 0) atomicAdd(slot, sdata[0]);
}

__global__ void finalize_kernel(const float* __restrict__ acc, float* __restrict__ out) {
    float l_recon = 0.5f * (acc[0] / (16.f * 2048.f) + acc[1] / (16.f * 2432.f));
    float l_match = 0.5f * (acc[2] / (16.f * 1024.f) + acc[3] / (16.f * 1216.f));
    float l_latent = acc[4] / (16.f * 1024.f);
    float l_man = 0.1f * (acc[5] / (16.f * 2048.f));
    out[0] = l_recon + l_match + l_latent + l_man;
    out[1] = l_recon;
    out[2] = l_match;
    out[3] = l_latent;
    out[4] = l_man;
}

// ================= host =================
extern "C" void kernel_launch(void* const* d_in, const int* in_sizes, int n_in,
                              void* d_out, int out_size, void* d_ws, size_t ws_size,
                              hipStream_t stream) {
    (void)in_sizes; (void)n_in; (void)out_size; (void)ws_size;
    const float* pts = (const float*)d_in[0];
    const float* W1 = (const float*)d_in[1];
    const float* b1 = (const float*)d_in[2];
    const float* g1 = (const float*)d_in[3];
    const float* be1 = (const float*)d_in[4];
    const float* m1 = (const float*)d_in[5];
    const float* v1 = (const float*)d_in[6];
    const float* W2 = (const float*)d_in[7];
    const float* b2 = (const float*)d_in[8];
    const float* W3 = (const float*)d_in[9];
    const float* b3 = (const float*)d_in[10];
    const float* g2 = (const float*)d_in[11];
    const float* be2 = (const float*)d_in[12];
    const float* m2 = (const float*)d_in[13];
    const float* v2 = (const float*)d_in[14];
    const float* W4 = (const float*)d_in[15];
    const float* b4 = (const float*)d_in[16];
    const float* D1W = (const float*)d_in[17];
    const float* D1b = (const float*)d_in[18];
    const float* D2W = (const float*)d_in[19];
    const float* D2b = (const float*)d_in[20];
    const float* D3W = (const float*)d_in[21];
    const float* D3b = (const float*)d_in[22];
    const float* D4W = (const float*)d_in[23];
    const float* D4b = (const float*)d_in[24];

    char* ws = (char*)d_ws;
    size_t off = 0;
    auto alloc = [&](size_t bytes) -> void* {
        void* p = ws + off;
        off += (bytes + 255) & ~(size_t)255;
        return p;
    };
    float* center   = (float*)alloc((size_t)BSZ * NG * 3 * 4);
    int*   knnc     = (int*)  alloc((size_t)BSZ * NG * GS * 4);
    float* rebuild0 = (float*)alloc((size_t)BSZ * 2048 * 3 * 4);
    float* rebuild1 = (float*)alloc((size_t)BSZ * 1024 * 3 * 4);
    f16*   W2h      = (f16*)  alloc((size_t)256 * 128 * 2);
    f16*   W3h      = (f16*)  alloc((size_t)512 * 256 * 2);
    f16*   W4h      = (f16*)  alloc((size_t)1024 * 512 * 2);
    f16*   H1h      = (f16*)  alloc((size_t)BSZ * 2048 * 128 * 2);
    f16*   H2h      = (f16*)  alloc((size_t)BSZ * 2048 * 256 * 2);
    f16*   H3h      = (f16*)  alloc((size_t)BSZ * 2048 * 512 * 2);
    unsigned* gmaxkey = (unsigned*)alloc((size_t)BSZ * 256 * 4);
    float* gmaxb    = (float*)alloc((size_t)BSZ * 256 * 4);
    float* gpart    = (float*)alloc((size_t)BSZ * 512 * 4);
    unsigned* featkey = (unsigned*)alloc((size_t)BSZ * 1024 * 4);
    float* feat     = (float*)alloc((size_t)BSZ * 1024 * 4);
    float* featrec  = (float*)alloc((size_t)BSZ * 1024 * 4);
    float* dh1      = (float*)alloc((size_t)BSZ * 2048 * 4);
    float* dh2      = (float*)alloc((size_t)BSZ * 2048 * 4);
    float* dh3      = (float*)alloc((size_t)BSZ * 2048 * 4);
    float* pred     = (float*)alloc((size_t)BSZ * 6144 * 4);
    int*   idxa     = (int*)  alloc((size_t)BSZ * 64 * NBRK * 4);
    float* gatha    = (float*)alloc((size_t)BSZ * 64 * NBRK * 3 * 4);
    int*   idxb     = (int*)  alloc((size_t)BSZ * 32 * NBRK * 4);
    float* gathb    = (float*)alloc((size_t)BSZ * 32 * NBRK * 3 * 4);
    int*   idxc     = (int*)  alloc((size_t)BSZ * 32 * 32 * 4);
    float* gathc    = (float*)alloc((size_t)BSZ * 1024 * 3 * 4);
    int*   knn32    = (int*)  alloc((size_t)BSZ * 2048 * 32 * 4);
    float* nrmbuf   = (float*)alloc((size_t)BSZ * 2048 * 3 * 4);
    float* accum    = (float*)alloc(8 * 4);

    hipMemsetAsync(accum, 0, 8 * 4, stream);

    cvt_w_kernel<<<(256 * 128 + 255) / 256, 256, 0, stream>>>(W2, 128, 0, 128, W2h, 256 * 128);
    cvt_w_kernel<<<(512 * 256 + 255) / 256, 256, 0, stream>>>(W3, 512, 256, 256, W3h, 512 * 256);
    cvt_w_kernel<<<(1024 * 512 + 255) / 256, 256, 0, stream>>>(W4, 512, 0, 512, W4h, 1024 * 512);

    auto knn = [&](const float* Q, int q_bstride, int q_off, int nq,
                   const float* DB, int k, int* out) {
        int total = BSZ * nq;
        knn_kernel_v7<<<(total + 3) / 4, 256, 0, stream>>>(Q, q_bstride, q_off, nq,
                                                           DB, k, out, BSZ);
    };

    // FPS + grouping
    fps_kernel_v5<<<BSZ, 256, 0, stream>>>(pts, center);
    knn(center, NG, 0, NG, pts, GS, knnc);
    gather_points_kernel<<<(BSZ * 2048 + 255) / 256, 256, 0, stream>>>(pts, NPTS, knnc, NG * GS,
                                                                       0, 2048, rebuild0, BSZ);
    gather_points_kernel<<<(BSZ * 1024 + 255) / 256, 256, 0, stream>>>(pts, NPTS, knnc, NG * GS,
                                                                       2048, 1024, rebuild1, BSZ);

    auto enc = [&](const float* X, int n, float* featout) {
        int M = BSZ * n;
        layer1_kernel<<<M / 16, 256, 0, stream>>>(X, W1, b1, g1, be1, m1, v1, H1h, M);
        hipMemsetAsync(gmaxkey, 0, (size_t)BSZ * 256 * 4, stream);
        mfma_gemm_kernel<<<dim3(256 / 128, M / 128), 256, 0, stream>>>(
            H1h, W2h, 128, 256, b2, nullptr, nullptr, nullptr, nullptr, nullptr,
            H2h, gmaxkey, n, 0);
        decode_kernel<<<(BSZ * 256 + 255) / 256, 256, 0, stream>>>(gmaxkey, gmaxb, BSZ * 256);
        skinny_v2_kernel<<<(512 + 3) / 4, 256, 0, stream>>>(gmaxb, W3, 512, 0, b3,
                                                            gpart, 256, 512, 0);
        mfma_gemm_kernel<<<dim3(512 / 128, M / 128), 256, 0, stream>>>(
            H2h, W3h, 256, 512, nullptr, gpart, g2, be2, m2, v2, H3h, nullptr, n, 1);
        hipMemsetAsync(featkey, 0, (size_t)BSZ * 1024 * 4, stream);
        mfma_gemm_kernel<<<dim3(1024 / 128, M / 128), 256, 0, stream>>>(
            H3h, W4h, 512, 1024, b4, nullptr, nullptr, nullptr, nullptr, nullptr,
            nullptr, featkey, n, 0);
        decode_kernel<<<(BSZ * 1024 + 255) / 256, 256, 0, stream>>>(featkey, featout, BSZ * 1024);
    };

    enc(rebuild0, 2048, feat);

    // decoder (skinny M=16, fp32, coalesced)
    skinny_v2_kernel<<<2048 / 4, 256, 0, stream>>>(feat, D1W, 1024, 0, D1b, dh1, 1024, 2048, 1);
    skinny_v2_kernel<<<2048 / 4, 256, 0, stream>>>(dh1, D2W, 2048, 0, D2b, dh2, 2048, 2048, 1);
    skinny_v2_kernel<<<2048 / 4, 256, 0, stream>>>(dh2, D3W, 2048, 0, D3b, dh3, 2048, 2048, 1);
    skinny_v2_kernel<<<6144 / 4, 256, 0, stream>>>(dh3, D4W, 2048, 0, D4b, pred, 2048, 6144, 0);

    // l_recon
    knn(center, NG, 0, 64, pred, NBRK, idxa);
    gather_points_kernel<<<(BSZ * 2432 + 255) / 256, 256, 0, stream>>>(pred, 2048, idxa, 64 * NBRK,
                                                                       0, 2432, gatha, BSZ);
    chamfer_min_kernel<<<(BSZ * 2048 * 8 + 255) / 256, 256, 0, stream>>>(rebuild0, 2048,
                                                                         gatha, 2432, accum + 0);
    chamfer_min_kernel<<<(BSZ * 2432 * 8 + 255) / 256, 256, 0, stream>>>(gatha, 2432,
                                                                         rebuild0, 2048, accum + 1);
    // l_match
    knn(center, NG, 64, 32, pred, NBRK, idxb);
    gather_points_kernel<<<(BSZ * 1216 + 255) / 256, 256, 0, stream>>>(pred, 2048, idxb, 32 * NBRK,
                                                                       0, 1216, gathb, BSZ);
    chamfer_min_kernel<<<(BSZ * 1024 * 8 + 255) / 256, 256, 0, stream>>>(rebuild1, 1024,
                                                                         gathb, 1216, accum + 2);
    chamfer_min_kernel<<<(BSZ * 1216 * 8 + 255) / 256, 256, 0, stream>>>(gathb, 1216,
                                                                         rebuild1, 1024, accum + 3);
    // l_latent
    knn(center, NG, 96, 32, pred, 32, idxc);
    gather_points_kernel<<<(BSZ * 1024 + 255) / 256, 256, 0, stream>>>(pred, 2048, idxc, 32 * 32,
                                                                       0, 1024, gathc, BSZ);
    enc(gathc, 1024, featrec);
    latent_kernel<<<(BSZ * 1024 + 255) / 256, 256, 0, stream>>>(feat, featrec, BSZ * 1024,
                                                                accum + 4);
    // l_man: one self-KNN (k=32); manifold uses first 8 (stable top-k prefix)
    knn(pred, 2048, 0, 2048, pred, 32, knn32);
    normals_kernel<<<(BSZ * NPTS + 63) / 64, 64, 0, stream>>>(pred, knn32, nrmbuf);
    manifold_kernel<<<(BSZ * 2048 + 255) / 256, 256, 0, stream>>>(nrmbuf, knn32, 32, accum + 5);

    finalize_kernel<<<1, 1, 0, stream>>>(accum, (float*)d_out);
}

// Round 5
// 861.306 us; speedup vs baseline: 1.1450x; 1.0329x over previous
//
#include <hip/hip_runtime.h>
#include <math.h>

#define BSZ 16
#define NPTS 2048
#define NG 128
#define GS 32
#define NBRK 38

typedef _Float16 f16;
typedef _Float16 f16x8 __attribute__((ext_vector_type(8)));
typedef float f32x4 __attribute__((ext_vector_type(4)));

// ---------- helpers ----------
__device__ __forceinline__ unsigned fkey(float x) {
    unsigned u = __float_as_uint(x);
    return (u >> 31) ? ~u : (u | 0x80000000u);
}
__device__ __forceinline__ float fkey_inv(unsigned k) {
    unsigned u = (k >> 31) ? (k ^ 0x80000000u) : ~k;
    return __uint_as_float(u);
}

// 64-lane min via DPP (no LDS/DS pipe): row_shr 1/2/4/8 prefix + row_bcast 15/31,
// then readlane 63 broadcasts the full-wave min. gfx9-lineage DPP (CDNA keeps it).
__device__ __forceinline__ unsigned wave_min_u32(unsigned v) {
    unsigned t;
    t = (unsigned)__builtin_amdgcn_update_dpp(-1, (int)v, 0x111, 0xF, 0xF, false);
    v = v < t ? v : t;
    t = (unsigned)__builtin_amdgcn_update_dpp(-1, (int)v, 0x112, 0xF, 0xF, false);
    v = v < t ? v : t;
    t = (unsigned)__builtin_amdgcn_update_dpp(-1, (int)v, 0x114, 0xF, 0xF, false);
    v = v < t ? v : t;
    t = (unsigned)__builtin_amdgcn_update_dpp(-1, (int)v, 0x118, 0xF, 0xF, false);
    v = v < t ? v : t;
    t = (unsigned)__builtin_amdgcn_update_dpp(-1, (int)v, 0x142, 0xA, 0xF, false);
    v = v < t ? v : t;
    t = (unsigned)__builtin_amdgcn_update_dpp(-1, (int)v, 0x143, 0xC, 0xF, false);
    v = v < t ? v : t;
    return (unsigned)__builtin_amdgcn_readlane((int)v, 63);
}

// 64-lane max of a u64 key via DPP: one chain handles (value, tiebreak) packed.
// old=0 is the identity for unsigned max.
__device__ __forceinline__ unsigned long long wave_max_u64(unsigned long long v) {
#define DPPSTEP(ctrl, rmask)                                                                \
    {                                                                                       \
        unsigned tlo = (unsigned)__builtin_amdgcn_update_dpp(0, (int)(unsigned)v, ctrl,     \
                                                             rmask, 0xF, false);            \
        unsigned thi = (unsigned)__builtin_amdgcn_update_dpp(0, (int)(unsigned)(v >> 32),   \
                                                             ctrl, rmask, 0xF, false);      \
        unsigned long long t = ((unsigned long long)thi << 32) | tlo;                       \
        v = t > v ? t : v;                                                                  \
    }
    DPPSTEP(0x111, 0xF)
    DPPSTEP(0x112, 0xF)
    DPPSTEP(0x114, 0xF)
    DPPSTEP(0x118, 0xF)
    DPPSTEP(0x142, 0xA)
    DPPSTEP(0x143, 0xC)
#undef DPPSTEP
    unsigned rlo = (unsigned)__builtin_amdgcn_readlane((int)(unsigned)v, 63);
    unsigned rhi = (unsigned)__builtin_amdgcn_readlane((int)(unsigned)(v >> 32), 63);
    return ((unsigned long long)rhi << 32) | rlo;
}

// ---------- FPS v5: 4 waves, one barrier/iter, parity-buffered wave slots ----------
// 256 threads, 8 pts/lane. Per iter: per-lane fused argmax (2 strict-> chains,
// ascending m => min index), ONE u64 DPP max per wave on key=(bits(best)<<32)|~j,
// lanes 0-2 prefetch wave-winner coords from LDS pre-barrier, {key,x,y,z} ->
// parity slot; ONE __syncthreads; all threads combine 4 slots. Parity double-
// buffer makes the single barrier race-free. Tie-break == jnp.argmax exactly.
__global__ __launch_bounds__(256, 1) void fps_kernel_v5(const float* __restrict__ pts,
                                                        float* __restrict__ center) {
    int b = blockIdx.x;
    const float* P = pts + (size_t)b * NPTS * 3;
    int tid = threadIdx.x;
    int lane = tid & 63, wave = tid >> 6;
    __shared__ __align__(16) float Pl[NPTS * 3];
    __shared__ __align__(16) float slot[2][4][8];   // [parity][wave]{klo,khi,x,y,z,...}
#pragma unroll
    for (int i = 0; i < 6; ++i) {    // 1536 float4 = 24 KB, coalesced
        int v4 = tid + i * 256;
        ((f32x4*)Pl)[v4] = ((const f32x4*)P)[v4];
    }
    __syncthreads();
    float px[8], py[8], pz[8], mind[8];
#pragma unroll
    for (int m = 0; m < 8; ++m) {
        int j = tid + (m << 8);
        px[m] = Pl[j * 3 + 0];
        py[m] = Pl[j * 3 + 1];
        pz[m] = Pl[j * 3 + 2];
        mind[m] = 1e10f;
    }
    float cx = Pl[0], cy = Pl[1], cz = Pl[2];   // far = 0
    float* C = center + (size_t)b * NG * 3;
#pragma unroll 1
    for (int g = 0; g < NG; ++g) {
        if (tid == 0) {
            C[g * 3 + 0] = cx; C[g * 3 + 1] = cy; C[g * 3 + 2] = cz;
        }
        if (g == NG - 1) break;      // uniform: all threads exit together
        float best0 = -1.f, best1 = -1.f;
        int bm0 = 0, bm1 = 1;
#pragma unroll
        for (int m = 0; m < 8; m += 2) {   // 2 independent dep chains
            float dx0 = px[m] - cx, dy0 = py[m] - cy, dz0 = pz[m] - cz;
            float d0 = dx0 * dx0 + dy0 * dy0 + dz0 * dz0;
            float md0 = fminf(mind[m], d0);
            mind[m] = md0;
            if (md0 > best0) { best0 = md0; bm0 = m; }        // strict >: min m on tie
            float dx1 = px[m + 1] - cx, dy1 = py[m + 1] - cy, dz1 = pz[m + 1] - cz;
            float d1 = dx1 * dx1 + dy1 * dy1 + dz1 * dz1;
            float md1 = fminf(mind[m + 1], d1);
            mind[m + 1] = md1;
            if (md1 > best1) { best1 = md1; bm1 = m + 1; }
        }
        bool t = (best1 > best0) || (best1 == best0 && bm1 < bm0);
        float bv = t ? best1 : best0;
        int bi = t ? bm1 : bm0;
        unsigned j = (unsigned)(tid + (bi << 8));   // global point index
        // bv >= 0 so float bits order as u32; ~j => u64-max picks min index on ties
        unsigned long long key =
            ((unsigned long long)__float_as_uint(bv) << 32) | (unsigned)(~j);
        key = wave_max_u64(key);                    // broadcast to all lanes
        unsigned bj = ~(unsigned)key;
        int par = g & 1;
        if (lane < 3) slot[par][wave][2 + lane] = Pl[bj * 3 + lane];  // prefetch coords
        if (lane == 0) {
            slot[par][wave][0] = __uint_as_float((unsigned)key);
            slot[par][wave][1] = __uint_as_float((unsigned)(key >> 32));
        }
        __syncthreads();
        // combine 4 wave slots (uniform across all threads)
        unsigned long long kb = 0ull;
        float nx = 0.f, ny = 0.f, nz = 0.f;
#pragma unroll
        for (int w = 0; w < 4; ++w) {
            f32x4 v = *(const f32x4*)&slot[par][w][0];   // klo,khi,x,y
            float vz = slot[par][w][4];
            unsigned long long kk =
                ((unsigned long long)__float_as_uint(v[1]) << 32) | __float_as_uint(v[0]);
            bool tw = kk > kb;
            kb = tw ? kk : kb;
            nx = tw ? v[2] : nx;
            ny = tw ? v[3] : ny;
            nz = tw ? vz : nz;
        }
        cx = nx; cy = ny; cz = nz;
    }
}

// ---------- KNN v7: 32-bit packed keys + DPP wave-min, zero DS ops ----------
// key = (quantized_dist << 11) | idx ; u32 order == (d, idx) lex order up to the
// 1/8192 distance quantum (idx breaks quantized ties; matches stable top_k
// except between points closer than 1.2e-4 in squared distance -- negligible).
// Per-lane top-4 key cache + watermark refill (rare); wave per query; no barriers.
__global__ void knn_kernel_v7(const float* __restrict__ Q, int q_bstride, int q_off, int nq,
                              const float* __restrict__ DB, int k,
                              int* __restrict__ out, int nbatch) {
    const unsigned KINF = 0xFFFFFFFFu;
    int wave = threadIdx.x >> 6, lane = threadIdx.x & 63;
    int qidx = blockIdx.x * 4 + wave;
    if (qidx >= nbatch * nq) return;     // wave-uniform
    int b = qidx / nq, qi = qidx % nq;
    const float* q = Q + ((size_t)b * q_bstride + q_off + qi) * 3;
    float qx = q[0], qy = q[1], qz = q[2];
    float qq = qx * qx + qy * qy + qz * qz;
    const float* db = DB + (size_t)b * NPTS * 3;

    unsigned key[32];
    unsigned c0 = KINF, c1 = KINF, c2 = KINF, c3 = KINF;
#pragma unroll
    for (int m = 0; m < 32; ++m) {
        int j = lane + (m << 6);
        float bx = db[j * 3 + 0], by = db[j * 3 + 1], bz = db[j * 3 + 2];
        float dv = qq + bx * bx + by * by + bz * bz - 2.0f * (qx * bx + qy * by + qz * bz);
        unsigned qd = (unsigned)fminf(fmaxf(dv, 0.f) * 8192.0f, 2097151.f);
        unsigned kk = (qd << 11) | (unsigned)j;
        key[m] = kk;
        if (kk < c3) {
            if (kk < c2) {
                c3 = c2;
                if (kk < c1) {
                    c2 = c1;
                    if (kk < c0) { c1 = c0; c0 = kk; } else c1 = kk;
                } else c2 = kk;
            } else c3 = kk;
        }
    }
    unsigned hw = c3;        // high-water: largest key ever cached (init: 4th best)
    int ncached = 4;
    int* o = out + (size_t)qidx * k;

    for (int r = 0; r < k; ++r) {
        bool need = (c0 == KINF) && (ncached < 32);
        if (__any(need)) {
            unsigned best = KINF;
#pragma unroll
            for (int m = 0; m < 32; ++m) {
                unsigned v = key[m];
                best = (v > hw && v < best) ? v : best;
            }
            if (need) {
                c0 = best;
                hw = best;
                ncached = (best == KINF) ? 32 : ncached + 1;
            }
        }
        unsigned g = wave_min_u32(c0);
        if (lane == 0) o[r] = (int)(g & 0x7FFu);
        if (((g & 0x7FFu) & 63u) == (unsigned)lane) {  // owner pops its c0 (== g)
            c0 = c1; c1 = c2; c2 = c3; c3 = KINF;
        }
    }
}

// ---------- gather points via index array ----------
__global__ void gather_points_kernel(const float* __restrict__ pts, int db_bstride,
                                     const int* __restrict__ idx, int idx_bstride, int idx_off,
                                     int m, float* __restrict__ out, int nbatch) {
    int t = blockIdx.x * blockDim.x + threadIdx.x;
    if (t >= nbatch * m) return;
    int b = t / m, j = t % m;
    int s = idx[(size_t)b * idx_bstride + idx_off + j];
    const float* p = pts + ((size_t)b * db_bstride + s) * 3;
    out[(size_t)t * 3 + 0] = p[0];
    out[(size_t)t * 3 + 1] = p[1];
    out[(size_t)t * 3 + 2] = p[2];
}

// ---------- fp32 -> fp16 weight conversion (strided slice) ----------
__global__ void cvt_w_kernel(const float* __restrict__ in, int ld, int off, int K,
                             f16* __restrict__ out, int total) {
    int t = blockIdx.x * blockDim.x + threadIdx.x;
    if (t >= total) return;
    int n = t / K, k = t % K;
    out[t] = (f16)in[(size_t)n * ld + off + k];
}

// ---------- layer1: H1 = relu(bn(x @ W1^T + b1)) in fp16, fused ----------
__global__ void layer1_kernel(const float* __restrict__ X, const float* __restrict__ W1,
                              const float* __restrict__ b1, const float* __restrict__ g1,
                              const float* __restrict__ be1, const float* __restrict__ m1,
                              const float* __restrict__ v1, f16* __restrict__ H1, int M) {
    __shared__ float w[384], bb[128], sg[128], sb[128], sm[128], sv[128];
    for (int i = threadIdx.x; i < 384; i += 256) w[i] = W1[i];
    if (threadIdx.x < 128) {
        int c = threadIdx.x;
        bb[c] = b1[c]; sg[c] = g1[c]; sb[c] = be1[c]; sm[c] = m1[c]; sv[c] = v1[c];
    }
    __syncthreads();
    int t = blockIdx.x * 256 + threadIdx.x;
    if (t >= M * 16) return;
    int row = t >> 4, cg = (t & 15) * 8;
    float x0 = X[(size_t)row * 3], x1 = X[(size_t)row * 3 + 1], x2 = X[(size_t)row * 3 + 2];
    f16x8 outv;
#pragma unroll
    for (int j = 0; j < 8; ++j) {
        int c = cg + j;
        float tv = x0 * w[c * 3] + x1 * w[c * 3 + 1] + x2 * w[c * 3 + 2] + bb[c];
        float vv = (tv - sm[c]) * rsqrtf(sv[c] + 1e-5f) * sg[c] + sb[c];
        outv[j] = (f16)fmaxf(vv, 0.f);
    }
    *(f16x8*)&H1[(size_t)row * 128 + cg] = outv;
}

// ---------- MFMA GEMM v2: XCD-chunked block swizzle + register prefetch ----------
// R4 counters (K=512,N=1024 dispatch): FETCH 132.7 MB vs 34.5 MB unique input
// (A-panels re-fetched into up to 8 non-coherent XCD L2s) + MfmaUtil 15% with
// sync staging (global latency on critical path every k-iter).
// Fix 1: bijective chunked remap of the dispatch-linear block id -> each XCD
// owns a contiguous run of row-panels (T1; m204 formula, exact for any nwg).
// Fix 2: tile k+1's 4x16B global loads issued right after the first barrier,
// consumed at next iter's ds_write -> ~500-900cy HBM/L2 latency hides under
// ds_read+MFMA+barrier (T14-lite). Same barrier count, +16 VGPRs.
__global__ __launch_bounds__(256) void mfma_gemm_kernel(
        const f16* __restrict__ A, const f16* __restrict__ W, int K, int N,
        const float* __restrict__ bias, const float* __restrict__ bias2d,
        const float* __restrict__ bng, const float* __restrict__ bnb,
        const float* __restrict__ bnm, const float* __restrict__ bnv,
        f16* __restrict__ Cout, unsigned* __restrict__ maxkey,
        int rows_per_batch, int relu) {
    __shared__ f16 Als[128 * 40];
    __shared__ f16 Bls[128 * 40];
    int tid = threadIdx.x;
    int lane = tid & 63;
    int wave = tid >> 6;
    int wm = wave & 1, wn = wave >> 1;
    int c16 = lane & 15, quad = lane >> 4;
    // XCD-aware chunked swizzle (dispatch order is x-fastest; XCD = lin % 8)
    int gx = gridDim.x;
    int nwg = gx * gridDim.y;
    int lin = blockIdx.y * gx + blockIdx.x;
    int qc = nwg >> 3, rc = nwg & 7;
    int xcd = lin & 7, pos = lin >> 3;
    int nlin = (xcd < rc ? xcd * (qc + 1) : rc * (qc + 1) + (xcd - rc) * qc) + pos;
    int row0 = (nlin / gx) * 128, col0 = (nlin % gx) * 128;
    int sr = tid >> 2;
    int skc = (tid & 3) * 8;

    f32x4 acc[4][4];
#pragma unroll
    for (int i = 0; i < 4; ++i)
#pragma unroll
        for (int j = 0; j < 4; ++j) acc[i][j] = (f32x4){0.f, 0.f, 0.f, 0.f};

    const f16* Ab = A + (size_t)(row0 + sr) * K + skc;
    const f16* Ab2 = A + (size_t)(row0 + sr + 64) * K + skc;
    const f16* Wb = W + (size_t)(col0 + sr) * K + skc;
    const f16* Wb2 = W + (size_t)(col0 + sr + 64) * K + skc;

    f16x8 pa0 = *(const f16x8*)Ab;
    f16x8 pa1 = *(const f16x8*)Ab2;
    f16x8 pb0 = *(const f16x8*)Wb;
    f16x8 pb1 = *(const f16x8*)Wb2;

    for (int k0 = 0; k0 < K; k0 += 32) {
        *(f16x8*)&Als[sr * 40 + skc] = pa0;
        *(f16x8*)&Als[(sr + 64) * 40 + skc] = pa1;
        *(f16x8*)&Bls[sr * 40 + skc] = pb0;
        *(f16x8*)&Bls[(sr + 64) * 40 + skc] = pb1;
        __syncthreads();
        if (k0 + 32 < K) {            // issue next-tile loads; waitcnt lands at
            int kn = k0 + 32;         // next iter's ds_write, hidden under MFMA
            pa0 = *(const f16x8*)(Ab + kn);
            pa1 = *(const f16x8*)(Ab2 + kn);
            pb0 = *(const f16x8*)(Wb + kn);
            pb1 = *(const f16x8*)(Wb2 + kn);
        }
        f16x8 af[4], bf[4];
#pragma unroll
        for (int s = 0; s < 4; ++s) {
            af[s] = *(const f16x8*)&Als[(wm * 64 + s * 16 + c16) * 40 + quad * 8];
            bf[s] = *(const f16x8*)&Bls[(wn * 64 + s * 16 + c16) * 40 + quad * 8];
        }
#pragma unroll
        for (int ms = 0; ms < 4; ++ms)
#pragma unroll
            for (int ns = 0; ns < 4; ++ns)
                acc[ms][ns] = __builtin_amdgcn_mfma_f32_16x16x32_f16(af[ms], bf[ns],
                                                                     acc[ms][ns], 0, 0, 0);
        __syncthreads();
    }

    int b = row0 / rows_per_batch;
#pragma unroll
    for (int ns = 0; ns < 4; ++ns) {
        int col = col0 + wn * 64 + ns * 16 + c16;
        float bv = bias ? bias[col] : 0.f;
        float b2v = bias2d ? bias2d[(size_t)b * N + col] : 0.f;
        float mx = -3e38f;
#pragma unroll
        for (int ms = 0; ms < 4; ++ms) {
#pragma unroll
            for (int j = 0; j < 4; ++j) {
                float v = acc[ms][ns][j] + bv + b2v;
                if (bng) v = (v - bnm[col]) * rsqrtf(bnv[col] + 1e-5f) * bng[col] + bnb[col];
                if (relu) v = fmaxf(v, 0.f);
                if (Cout)
                    Cout[(size_t)(row0 + wm * 64 + ms * 16 + quad * 4 + j) * N + col] = (f16)v;
                mx = fmaxf(mx, v);
            }
        }
        if (maxkey) {
            mx = fmaxf(mx, __shfl_xor(mx, 16, 64));
            mx = fmaxf(mx, __shfl_xor(mx, 32, 64));
            if (quad == 0) atomicMax(&maxkey[(size_t)b * N + col], fkey(mx));
        }
    }
}

// ---------- skinny GEMM v2: wave per column, coalesced float4 ----------
__global__ void skinny_v2_kernel(const float* __restrict__ A, const float* __restrict__ W,
                                 int ldw, int woff, const float* __restrict__ bias,
                                 float* __restrict__ C, int K, int N, int relu) {
    int wave = threadIdx.x >> 6, lane = threadIdx.x & 63;
    int col = blockIdx.x * 4 + wave;
    if (col >= N) return;
    const float* w = W + (size_t)col * ldw + woff;
    float acc[16];
#pragma unroll
    for (int m = 0; m < 16; ++m) acc[m] = 0.f;
    for (int k0 = 0; k0 < K; k0 += 256) {
        f32x4 wv = *(const f32x4*)(w + k0 + lane * 4);
#pragma unroll
        for (int m = 0; m < 16; ++m) {
            f32x4 av = *(const f32x4*)(A + (size_t)m * K + k0 + lane * 4);
            acc[m] += av[0] * wv[0] + av[1] * wv[1] + av[2] * wv[2] + av[3] * wv[3];
        }
    }
#pragma unroll
    for (int m = 0; m < 16; ++m)
#pragma unroll
        for (int s = 1; s < 64; s <<= 1) acc[m] += __shfl_xor(acc[m], s, 64);
    if (lane == 0) {
        float bv = bias[col];
#pragma unroll
        for (int m = 0; m < 16; ++m) {
            float v = acc[m] + bv;
            if (relu) v = fmaxf(v, 0.f);
            C[(size_t)m * N + col] = v;
        }
    }
}

__global__ void decode_kernel(const unsigned* __restrict__ k, float* __restrict__ f, int n) {
    int t = blockIdx.x * blockDim.x + threadIdx.x;
    if (t < n) f[t] = fkey_inv(k[t]);
}

// ---------- chamfer v2: 8 lanes per A-point, j-strided, shfl-min ----------
__global__ void chamfer_min_kernel(const float* __restrict__ A, int na,
                                   const float* __restrict__ Bp, int nb,
                                   float* __restrict__ slot) {
    int t = blockIdx.x * 256 + threadIdx.x;
    int pt = t >> 3, sl = t & 7;
    float val = 0.f;
    if (pt < BSZ * na) {
        int b = pt / na;
        const float* a = A + (size_t)pt * 3;
        float ax = a[0], ay = a[1], az = a[2];
        float aa = ax * ax + ay * ay + az * az;
        const float* Bb = Bp + (size_t)b * nb * 3;
        float m = 3e38f;
        for (int j = sl; j < nb; j += 8) {
            float bx = Bb[j * 3 + 0], by = Bb[j * 3 + 1], bz = Bb[j * 3 + 2];
            float d = aa + bx * bx + by * by + bz * bz - 2.0f * (ax * bx + ay * by + az * bz);
            m = fminf(m, d);
        }
#pragma unroll
        for (int s = 1; s < 8; s <<= 1) m = fminf(m, __shfl_xor(m, s, 64));
        if (sl == 0) val = sqrtf(fmaxf(m, 1e-12f));
    }
    __shared__ float sdata[256];
    sdata[threadIdx.x] = val;
    __syncthreads();
    for (int s = 128; s > 0; s >>= 1) {
        if (threadIdx.x < s) sdata[threadIdx.x] += sdata[threadIdx.x + s];
        __syncthreads();
    }
    if (threadIdx.x == 0) atomicAdd(slot, sdata[0]);
}

// ---------- smooth-L1 latent loss sum ----------
__global__ void latent_kernel(const float* __restrict__ f1, const float* __restrict__ f2,
                              int n, float* __restrict__ slot) {
    int t = blockIdx.x * blockDim.x + threadIdx.x;
    float val = 0.f;
    if (t < n) {
        float d = f1[t] - f2[t];
        float ad = fabsf(d);
        val = (ad < 1.f) ? (0.5f * d * d) : (ad - 0.5f);
    }
    __shared__ float sdata[256];
    sdata[threadIdx.x] = val;
    __syncthreads();
    for (int s = 128; s > 0; s >>= 1) {
        if (threadIdx.x < s) sdata[threadIdx.x] += sdata[threadIdx.x + s];
        __syncthreads();
    }
    if (threadIdx.x == 0) atomicAdd(slot, sdata[0]);
}

// ---------- 3x3 symmetric smallest eigenvector (double, analytic) ----------
__device__ void smallest_evec(double cxx, double cxy, double cxz,
                              double cyy, double cyz, double czz, double ev[3]) {
    double p1 = cxy * cxy + cxz * cxz + cyz * cyz;
    double q = (cxx + cyy + czz) / 3.0;
    double p2 = (cxx - q) * (cxx - q) + (cyy - q) * (cyy - q) + (czz - q) * (czz - q) + 2.0 * p1;
    double lam = q;
    if (p2 > 0.0) {
        double p = sqrt(p2 / 6.0);
        double b00 = (cxx - q) / p, b11 = (cyy - q) / p, b22 = (czz - q) / p;
        double b01 = cxy / p, b02 = cxz / p, b12 = cyz / p;
        double detB = b00 * (b11 * b22 - b12 * b12) - b01 * (b01 * b22 - b12 * b02)
                    + b02 * (b01 * b12 - b11 * b02);
        double r = detB * 0.5;
        r = r < -1.0 ? -1.0 : (r > 1.0 ? 1.0 : r);
        double phi = acos(r) / 3.0;
        lam = q + 2.0 * p * cos(phi + 2.0943951023931953);
    }
    double r0x = cxx - lam, r0y = cxy, r0z = cxz;
    double r1x = cxy, r1y = cyy - lam, r1z = cyz;
    double r2x = cxz, r2y = cyz, r2z = czz - lam;
    double c0x = r0y * r1z - r0z * r1y, c0y = r0z * r1x - r0x * r1z, c0z = r0x * r1y - r0y * r1x;
    double c1x = r0y * r2z - r0z * r2y, c1y = r0z * r2x - r0x * r2z, c1z = r0x * r2y - r0y * r2x;
    double c2x = r1y * r2z - r1z * r2y, c2y = r1z * r2x - r1x * r2z, c2z = r1x * r2y - r1y * r2x;
    double n0 = c0x * c0x + c0y * c0y + c0z * c0z;
    double n1 = c1x * c1x + c1y * c1y + c1z * c1z;
    double n2 = c2x * c2x + c2y * c2y + c2z * c2z;
    double bx = c0x, by = c0y, bz = c0z, bn = n0;
    if (n1 > bn) { bx = c1x; by = c1y; bz = c1z; bn = n1; }
    if (n2 > bn) { bx = c2x; by = c2y; bz = c2z; bn = n2; }
    if (bn < 1e-280) { ev[0] = 1.0; ev[1] = 0.0; ev[2] = 0.0; return; }
    double inv = 1.0 / sqrt(bn);
    ev[0] = bx * inv; ev[1] = by * inv; ev[2] = bz * inv;
}

// ---------- normals v2: single-pass moments, zero per-thread arrays ----------
// cov = E[pp^T] - mean mean^T via 9 double accumulators -- no scratch spill.
// Sign projection: sum_k (p_k - q) . ev = (s - 32 q) . ev.
__global__ __launch_bounds__(64) void normals_kernel(const float* __restrict__ pred,
                                                     const int* __restrict__ knn,
                                                     float* __restrict__ nrm) {
    int t = blockIdx.x * 64 + threadIdx.x;
    if (t >= BSZ * NPTS) return;
    int b = t / NPTS, i = t % NPTS;
    const float* P = pred + (size_t)b * NPTS * 3;
    const int* id = knn + (size_t)t * 32;
    double sx = 0, sy = 0, sz = 0;
    double sxx = 0, sxy = 0, sxz = 0, syy = 0, syz = 0, szz = 0;
#pragma unroll
    for (int k0 = 0; k0 < 32; k0 += 4) {
        int4 jj = *(const int4*)&id[k0];   // id is 128B-aligned (t*32 ints)
#pragma unroll
        for (int u = 0; u < 4; ++u) {
            int j = (u == 0) ? jj.x : (u == 1) ? jj.y : (u == 2) ? jj.z : jj.w;
            double x = (double)P[j * 3 + 0];
            double y = (double)P[j * 3 + 1];
            double z = (double)P[j * 3 + 2];
            sx += x; sy += y; sz += z;
            sxx += x * x; sxy += x * y; sxz += x * z;
            syy += y * y; syz += y * z; szz += z * z;
        }
    }
    double mx = sx * (1.0 / 32.0), my = sy * (1.0 / 32.0), mz = sz * (1.0 / 32.0);
    double cxx = sxx * (1.0 / 32.0) - mx * mx;
    double cxy = sxy * (1.0 / 32.0) - mx * my;
    double cxz = sxz * (1.0 / 32.0) - mx * mz;
    double cyy = syy * (1.0 / 32.0) - my * my;
    double cyz = syz * (1.0 / 32.0) - my * mz;
    double czz = szz * (1.0 / 32.0) - mz * mz;
    double ev[3];
    smallest_evec(cxx, cxy, cxz, cyy, cyz, czz, ev);
    float qx = P[i * 3 + 0], qy = P[i * 3 + 1], qz = P[i * 3 + 2];
    double proj = (sx - 32.0 * (double)qx) * ev[0] + (sy - 32.0 * (double)qy) * ev[1]
                + (sz - 32.0 * (double)qz) * ev[2];
    double s = (proj >= 0.0) ? 1.0 : -1.0;
    nrm[(size_t)t * 3 + 0] = (float)(ev[0] * s);
    nrm[(size_t)t * 3 + 1] = (float)(ev[1] * s);
    nrm[(size_t)t * 3 + 2] = (float)(ev[2] * s);
}

// ---------- manifold loss: reads first 8 of the 32-NN list ----------
__global__ void manifold_kernel(const float* __restrict__ nrm, const int* __restrict__ knn,
                                int kstride, float* __restrict__ slot) {
    int t = blockIdx.x * blockDim.x + threadIdx.x;
    float val = 0.f;
    if (t < BSZ * NPTS) {
        int b = t / NPTS;
        const float* NB = nrm + (size_t)b * NPTS * 3;
        const int* id = knn + (size_t)t * kstride;
        int j0 = id[0];
        float ax = NB[j0 * 3 + 0], ay = NB[j0 * 3 + 1], az = NB[j0 * 3 + 2];
        float an = fmaxf(sqrtf(ax * ax + ay * ay + az * az), 1e-6f);
        float x[8]; float s = 0.f;
        for (int k = 0; k < 8; ++k) {
            int j = id[k];
            float bx = NB[j * 3 + 0], by = NB[j * 3 + 1], bz = NB[j * 3 + 2];
            float bn_ = fmaxf(sqrtf(bx * bx + by * by + bz * bz), 1e-6f);
            float c = (ax * bx + ay * by + az * bz) / (an * bn_);
            x[k] = 1.f - c; s += x[k];
        }
        float mean = s / 8.f;
        float var = 0.f;
        for (int k = 0; k < 8; ++k) { float d = x[k] - mean; var += d * d; }
        val = sqrtf(var / 7.f);
    }
    __shared__ float sdata[256];
    sdata[threadIdx.x] = val;
    __syncthreads();
    for (int s2 = 128; s2 > 0; s2 >>= 1) {
        if (threadIdx.x < s2) sdata[threadIdx.x] += sdata[threadIdx.x + s2];
        __syncthreads();
    }
    if (threadIdx.x == 0) atomicAdd(slot, sdata[0]);
}

__global__ void finalize_kernel(const float* __restrict__ acc, float* __restrict__ out) {
    float l_recon = 0.5f * (acc[0] / (16.f * 2048.f) + acc[1] / (16.f * 2432.f));
    float l_match = 0.5f * (acc[2] / (16.f * 1024.f) + acc[3] / (16.f * 1216.f));
    float l_latent = acc[4] / (16.f * 1024.f);
    float l_man = 0.1f * (acc[5] / (16.f * 2048.f));
    out[0] = l_recon + l_match + l_latent + l_man;
    out[1] = l_recon;
    out[2] = l_match;
    out[3] = l_latent;
    out[4] = l_man;
}

// ================= host =================
extern "C" void kernel_launch(void* const* d_in, const int* in_sizes, int n_in,
                              void* d_out, int out_size, void* d_ws, size_t ws_size,
                              hipStream_t stream) {
    (void)in_sizes; (void)n_in; (void)out_size; (void)ws_size;
    const float* pts = (const float*)d_in[0];
    const float* W1 = (const float*)d_in[1];
    const float* b1 = (const float*)d_in[2];
    const float* g1 = (const float*)d_in[3];
    const float* be1 = (const float*)d_in[4];
    const float* m1 = (const float*)d_in[5];
    const float* v1 = (const float*)d_in[6];
    const float* W2 = (const float*)d_in[7];
    const float* b2 = (const float*)d_in[8];
    const float* W3 = (const float*)d_in[9];
    const float* b3 = (const float*)d_in[10];
    const float* g2 = (const float*)d_in[11];
    const float* be2 = (const float*)d_in[12];
    const float* m2 = (const float*)d_in[13];
    const float* v2 = (const float*)d_in[14];
    const float* W4 = (const float*)d_in[15];
    const float* b4 = (const float*)d_in[16];
    const float* D1W = (const float*)d_in[17];
    const float* D1b = (const float*)d_in[18];
    const float* D2W = (const float*)d_in[19];
    const float* D2b = (const float*)d_in[20];
    const float* D3W = (const float*)d_in[21];
    const float* D3b = (const float*)d_in[22];
    const float* D4W = (const float*)d_in[23];
    const float* D4b = (const float*)d_in[24];

    char* ws = (char*)d_ws;
    size_t off = 0;
    auto alloc = [&](size_t bytes) -> void* {
        void* p = ws + off;
        off += (bytes + 255) & ~(size_t)255;
        return p;
    };
    float* center   = (float*)alloc((size_t)BSZ * NG * 3 * 4);
    int*   knnc     = (int*)  alloc((size_t)BSZ * NG * GS * 4);
    float* rebuild0 = (float*)alloc((size_t)BSZ * 2048 * 3 * 4);
    float* rebuild1 = (float*)alloc((size_t)BSZ * 1024 * 3 * 4);
    f16*   W2h      = (f16*)  alloc((size_t)256 * 128 * 2);
    f16*   W3h      = (f16*)  alloc((size_t)512 * 256 * 2);
    f16*   W4h      = (f16*)  alloc((size_t)1024 * 512 * 2);
    f16*   H1h      = (f16*)  alloc((size_t)BSZ * 2048 * 128 * 2);
    f16*   H2h      = (f16*)  alloc((size_t)BSZ * 2048 * 256 * 2);
    f16*   H3h      = (f16*)  alloc((size_t)BSZ * 2048 * 512 * 2);
    unsigned* gmaxkey = (unsigned*)alloc((size_t)BSZ * 256 * 4);
    float* gmaxb    = (float*)alloc((size_t)BSZ * 256 * 4);
    float* gpart    = (float*)alloc((size_t)BSZ * 512 * 4);
    unsigned* featkey = (unsigned*)alloc((size_t)BSZ * 1024 * 4);
    float* feat     = (float*)alloc((size_t)BSZ * 1024 * 4);
    float* featrec  = (float*)alloc((size_t)BSZ * 1024 * 4);
    float* dh1      = (float*)alloc((size_t)BSZ * 2048 * 4);
    float* dh2      = (float*)alloc((size_t)BSZ * 2048 * 4);
    float* dh3      = (float*)alloc((size_t)BSZ * 2048 * 4);
    float* pred     = (float*)alloc((size_t)BSZ * 6144 * 4);
    int*   idxa     = (int*)  alloc((size_t)BSZ * 64 * NBRK * 4);
    float* gatha    = (float*)alloc((size_t)BSZ * 64 * NBRK * 3 * 4);
    int*   idxb     = (int*)  alloc((size_t)BSZ * 32 * NBRK * 4);
    float* gathb    = (float*)alloc((size_t)BSZ * 32 * NBRK * 3 * 4);
    int*   idxc     = (int*)  alloc((size_t)BSZ * 32 * 32 * 4);
    float* gathc    = (float*)alloc((size_t)BSZ * 1024 * 3 * 4);
    int*   knn32    = (int*)  alloc((size_t)BSZ * 2048 * 32 * 4);
    float* nrmbuf   = (float*)alloc((size_t)BSZ * 2048 * 3 * 4);
    float* accum    = (float*)alloc(8 * 4);

    hipMemsetAsync(accum, 0, 8 * 4, stream);

    cvt_w_kernel<<<(256 * 128 + 255) / 256, 256, 0, stream>>>(W2, 128, 0, 128, W2h, 256 * 128);
    cvt_w_kernel<<<(512 * 256 + 255) / 256, 256, 0, stream>>>(W3, 512, 256, 256, W3h, 512 * 256);
    cvt_w_kernel<<<(1024 * 512 + 255) / 256, 256, 0, stream>>>(W4, 512, 0, 512, W4h, 1024 * 512);

    auto knn = [&](const float* Q, int q_bstride, int q_off, int nq,
                   const float* DB, int k, int* out) {
        int total = BSZ * nq;
        knn_kernel_v7<<<(total + 3) / 4, 256, 0, stream>>>(Q, q_bstride, q_off, nq,
                                                           DB, k, out, BSZ);
    };

    // FPS + grouping
    fps_kernel_v5<<<BSZ, 256, 0, stream>>>(pts, center);
    knn(center, NG, 0, NG, pts, GS, knnc);
    gather_points_kernel<<<(BSZ * 2048 + 255) / 256, 256, 0, stream>>>(pts, NPTS, knnc, NG * GS,
                                                                       0, 2048, rebuild0, BSZ);
    gather_points_kernel<<<(BSZ * 1024 + 255) / 256, 256, 0, stream>>>(pts, NPTS, knnc, NG * GS,
                                                                       2048, 1024, rebuild1, BSZ);

    auto enc = [&](const float* X, int n, float* featout) {
        int M = BSZ * n;
        layer1_kernel<<<M / 16, 256, 0, stream>>>(X, W1, b1, g1, be1, m1, v1, H1h, M);
        hipMemsetAsync(gmaxkey, 0, (size_t)BSZ * 256 * 4, stream);
        mfma_gemm_kernel<<<dim3(256 / 128, M / 128), 256, 0, stream>>>(
            H1h, W2h, 128, 256, b2, nullptr, nullptr, nullptr, nullptr, nullptr,
            H2h, gmaxkey, n, 0);
        decode_kernel<<<(BSZ * 256 + 255) / 256, 256, 0, stream>>>(gmaxkey, gmaxb, BSZ * 256);
        skinny_v2_kernel<<<(512 + 3) / 4, 256, 0, stream>>>(gmaxb, W3, 512, 0, b3,
                                                            gpart, 256, 512, 0);
        mfma_gemm_kernel<<<dim3(512 / 128, M / 128), 256, 0, stream>>>(
            H2h, W3h, 256, 512, nullptr, gpart, g2, be2, m2, v2, H3h, nullptr, n, 1);
        hipMemsetAsync(featkey, 0, (size_t)BSZ * 1024 * 4, stream);
        mfma_gemm_kernel<<<dim3(1024 / 128, M / 128), 256, 0, stream>>>(
            H3h, W4h, 512, 1024, b4, nullptr, nullptr, nullptr, nullptr, nullptr,
            nullptr, featkey, n, 0);
        decode_kernel<<<(BSZ * 1024 + 255) / 256, 256, 0, stream>>>(featkey, featout, BSZ * 1024);
    };

    enc(rebuild0, 2048, feat);

    // decoder (skinny M=16, fp32, coalesced)
    skinny_v2_kernel<<<2048 / 4, 256, 0, stream>>>(feat, D1W, 1024, 0, D1b, dh1, 1024, 2048, 1);
    skinny_v2_kernel<<<2048 / 4, 256, 0, stream>>>(dh1, D2W, 2048, 0, D2b, dh2, 2048, 2048, 1);
    skinny_v2_kernel<<<2048 / 4, 256, 0, stream>>>(dh2, D3W, 2048, 0, D3b, dh3, 2048, 2048, 1);
    skinny_v2_kernel<<<6144 / 4, 256, 0, stream>>>(dh3, D4W, 2048, 0, D4b, pred, 2048, 6144, 0);

    // l_recon
    knn(center, NG, 0, 64, pred, NBRK, idxa);
    gather_points_kernel<<<(BSZ * 2432 + 255) / 256, 256, 0, stream>>>(pred, 2048, idxa, 64 * NBRK,
                                                                       0, 2432, gatha, BSZ);
    chamfer_min_kernel<<<(BSZ * 2048 * 8 + 255) / 256, 256, 0, stream>>>(rebuild0, 2048,
                                                                         gatha, 2432, accum + 0);
    chamfer_min_kernel<<<(BSZ * 2432 * 8 + 255) / 256, 256, 0, stream>>>(gatha, 2432,
                                                                         rebuild0, 2048, accum + 1);
    // l_match
    knn(center, NG, 64, 32, pred, NBRK, idxb);
    gather_points_kernel<<<(BSZ * 1216 + 255) / 256, 256, 0, stream>>>(pred, 2048, idxb, 32 * NBRK,
                                                                       0, 1216, gathb, BSZ);
    chamfer_min_kernel<<<(BSZ * 1024 * 8 + 255) / 256, 256, 0, stream>>>(rebuild1, 1024,
                                                                         gathb, 1216, accum + 2);
    chamfer_min_kernel<<<(BSZ * 1216 * 8 + 255) / 256, 256, 0, stream>>>(gathb, 1216,
                                                                         rebuild1, 1024, accum + 3);
    // l_latent
    knn(center, NG, 96, 32, pred, 32, idxc);
    gather_points_kernel<<<(BSZ * 1024 + 255) / 256, 256, 0, stream>>>(pred, 2048, idxc, 32 * 32,
                                                                       0, 1024, gathc, BSZ);
    enc(gathc, 1024, featrec);
    latent_kernel<<<(BSZ * 1024 + 255) / 256, 256, 0, stream>>>(feat, featrec, BSZ * 1024,
                                                                accum + 4);
    // l_man: one self-KNN (k=32); manifold uses first 8 (stable top-k prefix)
    knn(pred, 2048, 0, 2048, pred, 32, knn32);
    normals_kernel<<<(BSZ * NPTS + 63) / 64, 64, 0, stream>>>(pred, knn32, nrmbuf);
    manifold_kernel<<<(BSZ * 2048 + 255) / 256, 256, 0, stream>>>(nrmbuf, knn32, 32, accum + 5);

    finalize_kernel<<<1, 1, 0, stream>>>(accum, (float*)d_out);
}

// Round 6
// 752.402 us; speedup vs baseline: 1.3107x; 1.1447x over previous
//
#include <hip/hip_runtime.h>
#include <math.h>

#define BSZ 16
#define NPTS 2048
#define NG 128
#define GS 32
#define NBRK 38

typedef _Float16 f16;
typedef _Float16 f16x8 __attribute__((ext_vector_type(8)));
typedef float f32x4 __attribute__((ext_vector_type(4)));

// ---------- helpers ----------
__device__ __forceinline__ unsigned fkey(float x) {
    unsigned u = __float_as_uint(x);
    return (u >> 31) ? ~u : (u | 0x80000000u);
}
__device__ __forceinline__ float fkey_inv(unsigned k) {
    unsigned u = (k >> 31) ? (k ^ 0x80000000u) : ~k;
    return __uint_as_float(u);
}

// 64-lane min via DPP (no LDS/DS pipe).
__device__ __forceinline__ unsigned wave_min_u32(unsigned v) {
    unsigned t;
    t = (unsigned)__builtin_amdgcn_update_dpp(-1, (int)v, 0x111, 0xF, 0xF, false);
    v = v < t ? v : t;
    t = (unsigned)__builtin_amdgcn_update_dpp(-1, (int)v, 0x112, 0xF, 0xF, false);
    v = v < t ? v : t;
    t = (unsigned)__builtin_amdgcn_update_dpp(-1, (int)v, 0x114, 0xF, 0xF, false);
    v = v < t ? v : t;
    t = (unsigned)__builtin_amdgcn_update_dpp(-1, (int)v, 0x118, 0xF, 0xF, false);
    v = v < t ? v : t;
    t = (unsigned)__builtin_amdgcn_update_dpp(-1, (int)v, 0x142, 0xA, 0xF, false);
    v = v < t ? v : t;
    t = (unsigned)__builtin_amdgcn_update_dpp(-1, (int)v, 0x143, 0xC, 0xF, false);
    v = v < t ? v : t;
    return (unsigned)__builtin_amdgcn_readlane((int)v, 63);
}

// 64-lane max of a u64 key via DPP (old=0 is identity for unsigned max).
__device__ __forceinline__ unsigned long long wave_max_u64(unsigned long long v) {
#define DPPSTEP(ctrl, rmask)                                                                \
    {                                                                                       \
        unsigned tlo = (unsigned)__builtin_amdgcn_update_dpp(0, (int)(unsigned)v, ctrl,     \
                                                             rmask, 0xF, false);            \
        unsigned thi = (unsigned)__builtin_amdgcn_update_dpp(0, (int)(unsigned)(v >> 32),   \
                                                             ctrl, rmask, 0xF, false);      \
        unsigned long long t = ((unsigned long long)thi << 32) | tlo;                       \
        v = t > v ? t : v;                                                                  \
    }
    DPPSTEP(0x111, 0xF)
    DPPSTEP(0x112, 0xF)
    DPPSTEP(0x114, 0xF)
    DPPSTEP(0x118, 0xF)
    DPPSTEP(0x142, 0xA)
    DPPSTEP(0x143, 0xC)
#undef DPPSTEP
    unsigned rlo = (unsigned)__builtin_amdgcn_readlane((int)(unsigned)v, 63);
    unsigned rhi = (unsigned)__builtin_amdgcn_readlane((int)(unsigned)(v >> 32), 63);
    return ((unsigned long long)rhi << 32) | rlo;
}

// ---------- FPS v5 (unchanged from R5): 4 waves, one barrier/iter ----------
__global__ __launch_bounds__(256, 1) void fps_kernel_v5(const float* __restrict__ pts,
                                                        float* __restrict__ center) {
    int b = blockIdx.x;
    const float* P = pts + (size_t)b * NPTS * 3;
    int tid = threadIdx.x;
    int lane = tid & 63, wave = tid >> 6;
    __shared__ __align__(16) float Pl[NPTS * 3];
    __shared__ __align__(16) float slot[2][4][8];   // [parity][wave]{klo,khi,x,y,z,...}
#pragma unroll
    for (int i = 0; i < 6; ++i) {    // 1536 float4 = 24 KB, coalesced
        int v4 = tid + i * 256;
        ((f32x4*)Pl)[v4] = ((const f32x4*)P)[v4];
    }
    __syncthreads();
    float px[8], py[8], pz[8], mind[8];
#pragma unroll
    for (int m = 0; m < 8; ++m) {
        int j = tid + (m << 8);
        px[m] = Pl[j * 3 + 0];
        py[m] = Pl[j * 3 + 1];
        pz[m] = Pl[j * 3 + 2];
        mind[m] = 1e10f;
    }
    float cx = Pl[0], cy = Pl[1], cz = Pl[2];   // far = 0
    float* C = center + (size_t)b * NG * 3;
#pragma unroll 1
    for (int g = 0; g < NG; ++g) {
        if (tid == 0) {
            C[g * 3 + 0] = cx; C[g * 3 + 1] = cy; C[g * 3 + 2] = cz;
        }
        if (g == NG - 1) break;      // uniform: all threads exit together
        float best0 = -1.f, best1 = -1.f;
        int bm0 = 0, bm1 = 1;
#pragma unroll
        for (int m = 0; m < 8; m += 2) {   // 2 independent dep chains
            float dx0 = px[m] - cx, dy0 = py[m] - cy, dz0 = pz[m] - cz;
            float d0 = dx0 * dx0 + dy0 * dy0 + dz0 * dz0;
            float md0 = fminf(mind[m], d0);
            mind[m] = md0;
            if (md0 > best0) { best0 = md0; bm0 = m; }        // strict >: min m on tie
            float dx1 = px[m + 1] - cx, dy1 = py[m + 1] - cy, dz1 = pz[m + 1] - cz;
            float d1 = dx1 * dx1 + dy1 * dy1 + dz1 * dz1;
            float md1 = fminf(mind[m + 1], d1);
            mind[m + 1] = md1;
            if (md1 > best1) { best1 = md1; bm1 = m + 1; }
        }
        bool t = (best1 > best0) || (best1 == best0 && bm1 < bm0);
        float bv = t ? best1 : best0;
        int bi = t ? bm1 : bm0;
        unsigned j = (unsigned)(tid + (bi << 8));   // global point index
        unsigned long long key =
            ((unsigned long long)__float_as_uint(bv) << 32) | (unsigned)(~j);
        key = wave_max_u64(key);                    // broadcast to all lanes
        unsigned bj = ~(unsigned)key;
        int par = g & 1;
        if (lane < 3) slot[par][wave][2 + lane] = Pl[bj * 3 + lane];  // prefetch coords
        if (lane == 0) {
            slot[par][wave][0] = __uint_as_float((unsigned)key);
            slot[par][wave][1] = __uint_as_float((unsigned)(key >> 32));
        }
        __syncthreads();
        unsigned long long kb = 0ull;
        float nx = 0.f, ny = 0.f, nz = 0.f;
#pragma unroll
        for (int w = 0; w < 4; ++w) {
            f32x4 v = *(const f32x4*)&slot[par][w][0];   // klo,khi,x,y
            float vz = slot[par][w][4];
            unsigned long long kk =
                ((unsigned long long)__float_as_uint(v[1]) << 32) | __float_as_uint(v[0]);
            bool tw = kk > kb;
            kb = tw ? kk : kb;
            nx = tw ? v[2] : nx;
            ny = tw ? v[3] : ny;
            nz = tw ? vz : nz;
        }
        cx = nx; cy = ny; cz = nz;
    }
}

// ---------- KNN body (v7, unchanged logic): per-wave query, zero DS ops ----------
__device__ __forceinline__ void knn_query(const float* __restrict__ q,
                                          const float* __restrict__ db,
                                          int k, int* __restrict__ o, int lane) {
    const unsigned KINF = 0xFFFFFFFFu;
    float qx = q[0], qy = q[1], qz = q[2];
    float qq = qx * qx + qy * qy + qz * qz;
    unsigned key[32];
    unsigned c0 = KINF, c1 = KINF, c2 = KINF, c3 = KINF;
#pragma unroll
    for (int m = 0; m < 32; ++m) {
        int j = lane + (m << 6);
        float bx = db[j * 3 + 0], by = db[j * 3 + 1], bz = db[j * 3 + 2];
        float dv = qq + bx * bx + by * by + bz * bz - 2.0f * (qx * bx + qy * by + qz * bz);
        unsigned qd = (unsigned)fminf(fmaxf(dv, 0.f) * 8192.0f, 2097151.f);
        unsigned kk = (qd << 11) | (unsigned)j;
        key[m] = kk;
        if (kk < c3) {
            if (kk < c2) {
                c3 = c2;
                if (kk < c1) {
                    c2 = c1;
                    if (kk < c0) { c1 = c0; c0 = kk; } else c1 = kk;
                } else c2 = kk;
            } else c3 = kk;
        }
    }
    unsigned hw = c3;
    int ncached = 4;
    for (int r = 0; r < k; ++r) {
        bool need = (c0 == KINF) && (ncached < 32);
        if (__any(need)) {
            unsigned best = KINF;
#pragma unroll
            for (int m = 0; m < 32; ++m) {
                unsigned v = key[m];
                best = (v > hw && v < best) ? v : best;
            }
            if (need) {
                c0 = best;
                hw = best;
                ncached = (best == KINF) ? 32 : ncached + 1;
            }
        }
        unsigned g = wave_min_u32(c0);
        if (lane == 0) o[r] = (int)(g & 0x7FFu);
        if (((g & 0x7FFu) & 63u) == (unsigned)lane) {
            c0 = c1; c1 = c2; c2 = c3; c3 = KINF;
        }
    }
}

// group KNN: center queries vs pts
__global__ void knn_kernel_v7(const float* __restrict__ Q, int q_bstride, int q_off, int nq,
                              const float* __restrict__ DB, int k,
                              int* __restrict__ out, int nbatch) {
    int wave = threadIdx.x >> 6, lane = threadIdx.x & 63;
    int qidx = blockIdx.x * 4 + wave;
    if (qidx >= nbatch * nq) return;     // wave-uniform
    int b = qidx / nq, qi = qidx % nq;
    knn_query(Q + ((size_t)b * q_bstride + q_off + qi) * 3,
              DB + (size_t)b * NPTS * 3, k, out + (size_t)qidx * k, lane);
}

// ---------- fused post-decoder KNN: 3 center-vs-pred jobs + self-KNN ----------
// blocks [0,512): BSZ*128 center queries -> idxa(k=38)/idxb(38)/idxc(32)
// blocks [512,8704): BSZ*2048 pred self-queries -> knn32(k=32)
// branch is block-uniform; k is wave-uniform. Saves 3 dispatches.
__global__ void knn_post_kernel(const float* __restrict__ center,
                                const float* __restrict__ pred,
                                int* __restrict__ idxa, int* __restrict__ idxb,
                                int* __restrict__ idxc, int* __restrict__ knn32) {
    int wave = threadIdx.x >> 6, lane = threadIdx.x & 63;
    if (blockIdx.x < 512) {
        int qidx = blockIdx.x * 4 + wave;        // 2048 = BSZ*128 exact
        int b = qidx >> 7, qi = qidx & 127;
        const float* q = center + ((size_t)b * NG + qi) * 3;
        const float* db = pred + (size_t)b * NPTS * 3;
        int k; int* o;
        if (qi < 64) { k = NBRK; o = idxa + ((size_t)b * 64 + qi) * NBRK; }
        else if (qi < 96) { k = NBRK; o = idxb + ((size_t)b * 32 + qi - 64) * NBRK; }
        else { k = GS; o = idxc + ((size_t)b * 32 + qi - 96) * GS; }
        knn_query(q, db, k, o, lane);
    } else {
        int qidx = (blockIdx.x - 512) * 4 + wave;   // 32768 = BSZ*2048 exact
        int b = qidx >> 11, qi = qidx & 2047;
        const float* db = pred + (size_t)b * NPTS * 3;
        knn_query(db + (size_t)qi * 3, db, GS, knn32 + (size_t)qidx * GS, lane);
    }
}

// ---------- fused gathers ----------
// rebuild0 (BSZ*2048) + rebuild1 (BSZ*1024) from pts via knnc
__global__ void gather_rebuild_kernel(const float* __restrict__ pts,
                                      const int* __restrict__ knnc,
                                      float* __restrict__ rebuild0,
                                      float* __restrict__ rebuild1) {
    int t = blockIdx.x * 256 + threadIdx.x;
    int s, tt; float* out;
    if (t < BSZ * 2048) {
        tt = t;
        int b = tt >> 11, j = tt & 2047;
        s = knnc[(size_t)b * (NG * GS) + j];
        out = rebuild0;
    } else {
        tt = t - BSZ * 2048;
        int b = tt >> 10, j = tt & 1023;
        s = knnc[(size_t)b * (NG * GS) + 2048 + j];
        out = rebuild1;
    }
    int b2 = (out == rebuild0) ? (tt >> 11) : (tt >> 10);
    const float* p = pts + ((size_t)b2 * NPTS + s) * 3;
    out[(size_t)tt * 3 + 0] = p[0];
    out[(size_t)tt * 3 + 1] = p[1];
    out[(size_t)tt * 3 + 2] = p[2];
}

// gatha (BSZ*2432) + gathb (BSZ*1216) + gathc (BSZ*1024) from pred
__global__ void gather_abc_kernel(const float* __restrict__ pred,
                                  const int* __restrict__ idxa,
                                  const int* __restrict__ idxb,
                                  const int* __restrict__ idxc,
                                  float* __restrict__ gatha,
                                  float* __restrict__ gathb,
                                  float* __restrict__ gathc) {
    const int NA = BSZ * 2432, NB_ = BSZ * 1216, NC = BSZ * 1024;
    int t = blockIdx.x * 256 + threadIdx.x;
    const int* idx; int m, tt; float* out;
    if (t < NA) { tt = t; idx = idxa; m = 2432; out = gatha; }
    else if (t < NA + NB_) { tt = t - NA; idx = idxb; m = 1216; out = gathb; }
    else if (t < NA + NB_ + NC) { tt = t - NA - NB_; idx = idxc; m = 1024; out = gathc; }
    else return;
    int b = tt / m, j = tt - b * m;
    int s = idx[(size_t)b * m + j];       // idx batch stride == m for all three
    const float* p = pred + ((size_t)b * NPTS + s) * 3;
    out[(size_t)tt * 3 + 0] = p[0];
    out[(size_t)tt * 3 + 1] = p[1];
    out[(size_t)tt * 3 + 2] = p[2];
}

// ---------- fused fp32 -> fp16 weight conversion (3 matrices, 1 dispatch) ----------
__global__ void cvt_all_kernel(const float* __restrict__ W2, const float* __restrict__ W3,
                               const float* __restrict__ W4, f16* __restrict__ W2h,
                               f16* __restrict__ W3h, f16* __restrict__ W4h) {
    int t = blockIdx.x * 256 + threadIdx.x;
    if (t < 32768) {                       // W2h: 256x128, ld 128, off 0
        int n = t >> 7, k = t & 127;
        W2h[t] = (f16)W2[(size_t)n * 128 + k];
    } else if (t < 163840) {               // W3h: 512x256, ld 512, off 256
        int u = t - 32768;
        int n = u >> 8, k = u & 255;
        W3h[u] = (f16)W3[(size_t)n * 512 + 256 + k];
    } else if (t < 688128) {               // W4h: 1024x512, ld 512, off 0
        int u = t - 163840;
        int n = u >> 9, k = u & 511;
        W4h[u] = (f16)W4[(size_t)n * 512 + k];
    }
}

// ---------- layer1: H1 = relu(bn(x @ W1^T + b1)) in fp16, fused ----------
__global__ void layer1_kernel(const float* __restrict__ X, const float* __restrict__ W1,
                              const float* __restrict__ b1, const float* __restrict__ g1,
                              const float* __restrict__ be1, const float* __restrict__ m1,
                              const float* __restrict__ v1, f16* __restrict__ H1, int M) {
    __shared__ float w[384], bb[128], sg[128], sb[128], sm[128], sv[128];
    for (int i = threadIdx.x; i < 384; i += 256) w[i] = W1[i];
    if (threadIdx.x < 128) {
        int c = threadIdx.x;
        bb[c] = b1[c]; sg[c] = g1[c]; sb[c] = be1[c]; sm[c] = m1[c]; sv[c] = v1[c];
    }
    __syncthreads();
    int t = blockIdx.x * 256 + threadIdx.x;
    if (t >= M * 16) return;
    int row = t >> 4, cg = (t & 15) * 8;
    float x0 = X[(size_t)row * 3], x1 = X[(size_t)row * 3 + 1], x2 = X[(size_t)row * 3 + 2];
    f16x8 outv;
#pragma unroll
    for (int j = 0; j < 8; ++j) {
        int c = cg + j;
        float tv = x0 * w[c * 3] + x1 * w[c * 3 + 1] + x2 * w[c * 3 + 2] + bb[c];
        float vv = (tv - sm[c]) * rsqrtf(sv[c] + 1e-5f) * sg[c] + sb[c];
        outv[j] = (f16)fmaxf(vv, 0.f);
    }
    *(f16x8*)&H1[(size_t)row * 128 + cg] = outv;
}

// ---------- MFMA GEMM v2 (unchanged from R5): XCD swizzle + reg prefetch ----------
__global__ __launch_bounds__(256) void mfma_gemm_kernel(
        const f16* __restrict__ A, const f16* __restrict__ W, int K, int N,
        const float* __restrict__ bias, const float* __restrict__ bias2d,
        const float* __restrict__ bng, const float* __restrict__ bnb,
        const float* __restrict__ bnm, const float* __restrict__ bnv,
        f16* __restrict__ Cout, unsigned* __restrict__ maxkey,
        int rows_per_batch, int relu) {
    __shared__ f16 Als[128 * 40];
    __shared__ f16 Bls[128 * 40];
    int tid = threadIdx.x;
    int lane = tid & 63;
    int wave = tid >> 6;
    int wm = wave & 1, wn = wave >> 1;
    int c16 = lane & 15, quad = lane >> 4;
    int gx = gridDim.x;
    int nwg = gx * gridDim.y;
    int lin = blockIdx.y * gx + blockIdx.x;
    int qc = nwg >> 3, rc = nwg & 7;
    int xcd = lin & 7, pos = lin >> 3;
    int nlin = (xcd < rc ? xcd * (qc + 1) : rc * (qc + 1) + (xcd - rc) * qc) + pos;
    int row0 = (nlin / gx) * 128, col0 = (nlin % gx) * 128;
    int sr = tid >> 2;
    int skc = (tid & 3) * 8;

    f32x4 acc[4][4];
#pragma unroll
    for (int i = 0; i < 4; ++i)
#pragma unroll
        for (int j = 0; j < 4; ++j) acc[i][j] = (f32x4){0.f, 0.f, 0.f, 0.f};

    const f16* Ab = A + (size_t)(row0 + sr) * K + skc;
    const f16* Ab2 = A + (size_t)(row0 + sr + 64) * K + skc;
    const f16* Wb = W + (size_t)(col0 + sr) * K + skc;
    const f16* Wb2 = W + (size_t)(col0 + sr + 64) * K + skc;

    f16x8 pa0 = *(const f16x8*)Ab;
    f16x8 pa1 = *(const f16x8*)Ab2;
    f16x8 pb0 = *(const f16x8*)Wb;
    f16x8 pb1 = *(const f16x8*)Wb2;

    for (int k0 = 0; k0 < K; k0 += 32) {
        *(f16x8*)&Als[sr * 40 + skc] = pa0;
        *(f16x8*)&Als[(sr + 64) * 40 + skc] = pa1;
        *(f16x8*)&Bls[sr * 40 + skc] = pb0;
        *(f16x8*)&Bls[(sr + 64) * 40 + skc] = pb1;
        __syncthreads();
        if (k0 + 32 < K) {
            int kn = k0 + 32;
            pa0 = *(const f16x8*)(Ab + kn);
            pa1 = *(const f16x8*)(Ab2 + kn);
            pb0 = *(const f16x8*)(Wb + kn);
            pb1 = *(const f16x8*)(Wb2 + kn);
        }
        f16x8 af[4], bf[4];
#pragma unroll
        for (int s = 0; s < 4; ++s) {
            af[s] = *(const f16x8*)&Als[(wm * 64 + s * 16 + c16) * 40 + quad * 8];
            bf[s] = *(const f16x8*)&Bls[(wn * 64 + s * 16 + c16) * 40 + quad * 8];
        }
#pragma unroll
        for (int ms = 0; ms < 4; ++ms)
#pragma unroll
            for (int ns = 0; ns < 4; ++ns)
                acc[ms][ns] = __builtin_amdgcn_mfma_f32_16x16x32_f16(af[ms], bf[ns],
                                                                     acc[ms][ns], 0, 0, 0);
        __syncthreads();
    }

    int b = row0 / rows_per_batch;
#pragma unroll
    for (int ns = 0; ns < 4; ++ns) {
        int col = col0 + wn * 64 + ns * 16 + c16;
        float bv = bias ? bias[col] : 0.f;
        float b2v = bias2d ? bias2d[(size_t)b * N + col] : 0.f;
        float mx = -3e38f;
#pragma unroll
        for (int ms = 0; ms < 4; ++ms) {
#pragma unroll
            for (int j = 0; j < 4; ++j) {
                float v = acc[ms][ns][j] + bv + b2v;
                if (bng) v = (v - bnm[col]) * rsqrtf(bnv[col] + 1e-5f) * bng[col] + bnb[col];
                if (relu) v = fmaxf(v, 0.f);
                if (Cout)
                    Cout[(size_t)(row0 + wm * 64 + ms * 16 + quad * 4 + j) * N + col] = (f16)v;
                mx = fmaxf(mx, v);
            }
        }
        if (maxkey) {
            mx = fmaxf(mx, __shfl_xor(mx, 16, 64));
            mx = fmaxf(mx, __shfl_xor(mx, 32, 64));
            if (quad == 0) atomicMax(&maxkey[(size_t)b * N + col], fkey(mx));
        }
    }
}

// ---------- skinny GEMM v3: wave/column, optional inline fkey decode of A ----------
__global__ void skinny_v2_kernel(const float* __restrict__ A, const float* __restrict__ W,
                                 int ldw, int woff, const float* __restrict__ bias,
                                 float* __restrict__ C, int K, int N, int relu, int akey) {
    int wave = threadIdx.x >> 6, lane = threadIdx.x & 63;
    int col = blockIdx.x * 4 + wave;
    if (col >= N) return;
    const float* w = W + (size_t)col * ldw + woff;
    float acc[16];
#pragma unroll
    for (int m = 0; m < 16; ++m) acc[m] = 0.f;
    for (int k0 = 0; k0 < K; k0 += 256) {
        f32x4 wv = *(const f32x4*)(w + k0 + lane * 4);
#pragma unroll
        for (int m = 0; m < 16; ++m) {
            f32x4 av = *(const f32x4*)(A + (size_t)m * K + k0 + lane * 4);
            if (akey) {
#pragma unroll
                for (int u = 0; u < 4; ++u) av[u] = fkey_inv(__float_as_uint(av[u]));
            }
            acc[m] += av[0] * wv[0] + av[1] * wv[1] + av[2] * wv[2] + av[3] * wv[3];
        }
    }
#pragma unroll
    for (int m = 0; m < 16; ++m)
#pragma unroll
        for (int s = 1; s < 64; s <<= 1) acc[m] += __shfl_xor(acc[m], s, 64);
    if (lane == 0) {
        float bv = bias[col];
#pragma unroll
        for (int m = 0; m < 16; ++m) {
            float v = acc[m] + bv;
            if (relu) v = fmaxf(v, 0.f);
            C[(size_t)m * N + col] = v;
        }
    }
}

// ---------- fused chamfer x4: block-range job table, one dispatch ----------
__global__ void chamfer4_kernel(const float* __restrict__ rebuild0,
                                const float* __restrict__ gatha,
                                const float* __restrict__ rebuild1,
                                const float* __restrict__ gathb,
                                float* __restrict__ accum) {
    int blk = blockIdx.x;
    const float *A, *Bp; int na, nb, base; float* slot;
    if (blk < 1024)      { A = rebuild0; na = 2048; Bp = gatha;    nb = 2432; slot = accum + 0; base = 0; }
    else if (blk < 2240) { A = gatha;    na = 2432; Bp = rebuild0; nb = 2048; slot = accum + 1; base = 1024; }
    else if (blk < 2752) { A = rebuild1; na = 1024; Bp = gathb;    nb = 1216; slot = accum + 2; base = 2240; }
    else                 { A = gathb;    na = 1216; Bp = rebuild1; nb = 1024; slot = accum + 3; base = 2752; }
    int t = (blk - base) * 256 + threadIdx.x;
    int pt = t >> 3, sl = t & 7;
    float val = 0.f;
    if (pt < BSZ * na) {
        int b = pt / na;
        const float* a = A + (size_t)pt * 3;
        float ax = a[0], ay = a[1], az = a[2];
        float aa = ax * ax + ay * ay + az * az;
        const float* Bb = Bp + (size_t)b * nb * 3;
        float m = 3e38f;
        for (int j = sl; j < nb; j += 8) {
            float bx = Bb[j * 3 + 0], by = Bb[j * 3 + 1], bz = Bb[j * 3 + 2];
            float d = aa + bx * bx + by * by + bz * bz - 2.0f * (ax * bx + ay * by + az * bz);
            m = fminf(m, d);
        }
#pragma unroll
        for (int s = 1; s < 8; s <<= 1) m = fminf(m, __shfl_xor(m, s, 64));
        if (sl == 0) val = sqrtf(fmaxf(m, 1e-12f));
    }
    __shared__ float sdata[256];
    sdata[threadIdx.x] = val;
    __syncthreads();
    for (int s = 128; s > 0; s >>= 1) {
        if (threadIdx.x < s) sdata[threadIdx.x] += sdata[threadIdx.x + s];
        __syncthreads();
    }
    if (threadIdx.x == 0) atomicAdd(slot, sdata[0]);
}

// ---------- smooth-L1 latent loss: inline fkey decode of both operands ----------
__global__ void latent_kernel(const unsigned* __restrict__ k1,
                              const unsigned* __restrict__ k2,
                              int n, float* __restrict__ slot) {
    int t = blockIdx.x * blockDim.x + threadIdx.x;
    float val = 0.f;
    if (t < n) {
        float d = fkey_inv(k1[t]) - fkey_inv(k2[t]);
        float ad = fabsf(d);
        val = (ad < 1.f) ? (0.5f * d * d) : (ad - 0.5f);
    }
    __shared__ float sdata[256];
    sdata[threadIdx.x] = val;
    __syncthreads();
    for (int s = 128; s > 0; s >>= 1) {
        if (threadIdx.x < s) sdata[threadIdx.x] += sdata[threadIdx.x + s];
        __syncthreads();
    }
    if (threadIdx.x == 0) atomicAdd(slot, sdata[0]);
}

// ---------- 3x3 symmetric smallest eigenvector (double, analytic) ----------
__device__ void smallest_evec(double cxx, double cxy, double cxz,
                              double cyy, double cyz, double czz, double ev[3]) {
    double p1 = cxy * cxy + cxz * cxz + cyz * cyz;
    double q = (cxx + cyy + czz) / 3.0;
    double p2 = (cxx - q) * (cxx - q) + (cyy - q) * (cyy - q) + (czz - q) * (czz - q) + 2.0 * p1;
    double lam = q;
    if (p2 > 0.0) {
        double p = sqrt(p2 / 6.0);
        double b00 = (cxx - q) / p, b11 = (cyy - q) / p, b22 = (czz - q) / p;
        double b01 = cxy / p, b02 = cxz / p, b12 = cyz / p;
        double detB = b00 * (b11 * b22 - b12 * b12) - b01 * (b01 * b22 - b12 * b02)
                    + b02 * (b01 * b12 - b11 * b02);
        double r = detB * 0.5;
        r = r < -1.0 ? -1.0 : (r > 1.0 ? 1.0 : r);
        double phi = acos(r) / 3.0;
        lam = q + 2.0 * p * cos(phi + 2.0943951023931953);
    }
    double r0x = cxx - lam, r0y = cxy, r0z = cxz;
    double r1x = cxy, r1y = cyy - lam, r1z = cyz;
    double r2x = cxz, r2y = cyz, r2z = czz - lam;
    double c0x = r0y * r1z - r0z * r1y, c0y = r0z * r1x - r0x * r1z, c0z = r0x * r1y - r0y * r1x;
    double c1x = r0y * r2z - r0z * r2y, c1y = r0z * r2x - r0x * r2z, c1z = r0x * r2y - r0y * r2x;
    double c2x = r1y * r2z - r1z * r2y, c2y = r1z * r2x - r1x * r2z, c2z = r1x * r2y - r1y * r2x;
    double n0 = c0x * c0x + c0y * c0y + c0z * c0z;
    double n1 = c1x * c1x + c1y * c1y + c1z * c1z;
    double n2 = c2x * c2x + c2y * c2y + c2z * c2z;
    double bx = c0x, by = c0y, bz = c0z, bn = n0;
    if (n1 > bn) { bx = c1x; by = c1y; bz = c1z; bn = n1; }
    if (n2 > bn) { bx = c2x; by = c2y; bz = c2z; bn = n2; }
    if (bn < 1e-280) { ev[0] = 1.0; ev[1] = 0.0; ev[2] = 0.0; return; }
    double inv = 1.0 / sqrt(bn);
    ev[0] = bx * inv; ev[1] = by * inv; ev[2] = bz * inv;
}

// ---------- normals v2 (unchanged from R4 fix): single-pass moments ----------
__global__ __launch_bounds__(64) void normals_kernel(const float* __restrict__ pred,
                                                     const int* __restrict__ knn,
                                                     float* __restrict__ nrm) {
    int t = blockIdx.x * 64 + threadIdx.x;
    if (t >= BSZ * NPTS) return;
    int b = t / NPTS, i = t % NPTS;
    const float* P = pred + (size_t)b * NPTS * 3;
    const int* id = knn + (size_t)t * 32;
    double sx = 0, sy = 0, sz = 0;
    double sxx = 0, sxy = 0, sxz = 0, syy = 0, syz = 0, szz = 0;
#pragma unroll
    for (int k0 = 0; k0 < 32; k0 += 4) {
        int4 jj = *(const int4*)&id[k0];
#pragma unroll
        for (int u = 0; u < 4; ++u) {
            int j = (u == 0) ? jj.x : (u == 1) ? jj.y : (u == 2) ? jj.z : jj.w;
            double x = (double)P[j * 3 + 0];
            double y = (double)P[j * 3 + 1];
            double z = (double)P[j * 3 + 2];
            sx += x; sy += y; sz += z;
            sxx += x * x; sxy += x * y; sxz += x * z;
            syy += y * y; syz += y * z; szz += z * z;
        }
    }
    double mx = sx * (1.0 / 32.0), my = sy * (1.0 / 32.0), mz = sz * (1.0 / 32.0);
    double cxx = sxx * (1.0 / 32.0) - mx * mx;
    double cxy = sxy * (1.0 / 32.0) - mx * my;
    double cxz = sxz * (1.0 / 32.0) - mx * mz;
    double cyy = syy * (1.0 / 32.0) - my * my;
    double cyz = syz * (1.0 / 32.0) - my * mz;
    double czz = szz * (1.0 / 32.0) - mz * mz;
    double ev[3];
    smallest_evec(cxx, cxy, cxz, cyy, cyz, czz, ev);
    float qx = P[i * 3 + 0], qy = P[i * 3 + 1], qz = P[i * 3 + 2];
    double proj = (sx - 32.0 * (double)qx) * ev[0] + (sy - 32.0 * (double)qy) * ev[1]
                + (sz - 32.0 * (double)qz) * ev[2];
    double s = (proj >= 0.0) ? 1.0 : -1.0;
    nrm[(size_t)t * 3 + 0] = (float)(ev[0] * s);
    nrm[(size_t)t * 3 + 1] = (float)(ev[1] * s);
    nrm[(size_t)t * 3 + 2] = (float)(ev[2] * s);
}

// ---------- manifold loss: reads first 8 of the 32-NN list ----------
__global__ void manifold_kernel(const float* __restrict__ nrm, const int* __restrict__ knn,
                                int kstride, float* __restrict__ slot) {
    int t = blockIdx.x * blockDim.x + threadIdx.x;
    float val = 0.f;
    if (t < BSZ * NPTS) {
        int b = t / NPTS;
        const float* NB = nrm + (size_t)b * NPTS * 3;
        const int* id = knn + (size_t)t * kstride;
        int j0 = id[0];
        float ax = NB[j0 * 3 + 0], ay = NB[j0 * 3 + 1], az = NB[j0 * 3 + 2];
        float an = fmaxf(sqrtf(ax * ax + ay * ay + az * az), 1e-6f);
        float x[8]; float s = 0.f;
        for (int k = 0; k < 8; ++k) {
            int j = id[k];
            float bx = NB[j * 3 + 0], by = NB[j * 3 + 1], bz = NB[j * 3 + 2];
            float bn_ = fmaxf(sqrtf(bx * bx + by * by + bz * bz), 1e-6f);
            float c = (ax * bx + ay * by + az * bz) / (an * bn_);
            x[k] = 1.f - c; s += x[k];
        }
        float mean = s / 8.f;
        float var = 0.f;
        for (int k = 0; k < 8; ++k) { float d = x[k] - mean; var += d * d; }
        val = sqrtf(var / 7.f);
    }
    __shared__ float sdata[256];
    sdata[threadIdx.x] = val;
    __syncthreads();
    for (int s2 = 128; s2 > 0; s2 >>= 1) {
        if (threadIdx.x < s2) sdata[threadIdx.x] += sdata[threadIdx.x + s2];
        __syncthreads();
    }
    if (threadIdx.x == 0) atomicAdd(slot, sdata[0]);
}

__global__ void finalize_kernel(const float* __restrict__ acc, float* __restrict__ out) {
    float l_recon = 0.5f * (acc[0] / (16.f * 2048.f) + acc[1] / (16.f * 2432.f));
    float l_match = 0.5f * (acc[2] / (16.f * 1024.f) + acc[3] / (16.f * 1216.f));
    float l_latent = acc[4] / (16.f * 1024.f);
    float l_man = 0.1f * (acc[5] / (16.f * 2048.f));
    out[0] = l_recon + l_match + l_latent + l_man;
    out[1] = l_recon;
    out[2] = l_match;
    out[3] = l_latent;
    out[4] = l_man;
}

// ================= host =================
extern "C" void kernel_launch(void* const* d_in, const int* in_sizes, int n_in,
                              void* d_out, int out_size, void* d_ws, size_t ws_size,
                              hipStream_t stream) {
    (void)in_sizes; (void)n_in; (void)out_size; (void)ws_size;
    const float* pts = (const float*)d_in[0];
    const float* W1 = (const float*)d_in[1];
    const float* b1 = (const float*)d_in[2];
    const float* g1 = (const float*)d_in[3];
    const float* be1 = (const float*)d_in[4];
    const float* m1 = (const float*)d_in[5];
    const float* v1 = (const float*)d_in[6];
    const float* W2 = (const float*)d_in[7];
    const float* b2 = (const float*)d_in[8];
    const float* W3 = (const float*)d_in[9];
    const float* b3 = (const float*)d_in[10];
    const float* g2 = (const float*)d_in[11];
    const float* be2 = (const float*)d_in[12];
    const float* m2 = (const float*)d_in[13];
    const float* v2 = (const float*)d_in[14];
    const float* W4 = (const float*)d_in[15];
    const float* b4 = (const float*)d_in[16];
    const float* D1W = (const float*)d_in[17];
    const float* D1b = (const float*)d_in[18];
    const float* D2W = (const float*)d_in[19];
    const float* D2b = (const float*)d_in[20];
    const float* D3W = (const float*)d_in[21];
    const float* D3b = (const float*)d_in[22];
    const float* D4W = (const float*)d_in[23];
    const float* D4b = (const float*)d_in[24];

    char* ws = (char*)d_ws;
    size_t off = 0;
    auto alloc = [&](size_t bytes) -> void* {
        void* p = ws + off;
        off += (bytes + 255) & ~(size_t)255;
        return p;
    };
    float* center   = (float*)alloc((size_t)BSZ * NG * 3 * 4);
    int*   knnc     = (int*)  alloc((size_t)BSZ * NG * GS * 4);
    float* rebuild0 = (float*)alloc((size_t)BSZ * 2048 * 3 * 4);
    float* rebuild1 = (float*)alloc((size_t)BSZ * 1024 * 3 * 4);
    f16*   W2h      = (f16*)  alloc((size_t)256 * 128 * 2);
    f16*   W3h      = (f16*)  alloc((size_t)512 * 256 * 2);
    f16*   W4h      = (f16*)  alloc((size_t)1024 * 512 * 2);
    f16*   H1h      = (f16*)  alloc((size_t)BSZ * 2048 * 128 * 2);
    f16*   H2h      = (f16*)  alloc((size_t)BSZ * 2048 * 256 * 2);
    f16*   H3h      = (f16*)  alloc((size_t)BSZ * 2048 * 512 * 2);
    // contiguous key region + accum: ONE memset covers all
    // layout: gmaxkey1[BSZ*256] gmaxkey2[BSZ*256] featkey1[BSZ*1024]
    //         featkey2[BSZ*1024] accum[8]
    unsigned* keybase = (unsigned*)alloc(((size_t)BSZ * 2560 + 64) * 4);
    unsigned* gmaxkey1 = keybase;
    unsigned* gmaxkey2 = keybase + (size_t)BSZ * 256;
    unsigned* featkey1 = keybase + (size_t)BSZ * 512;
    unsigned* featkey2 = keybase + (size_t)BSZ * 512 + (size_t)BSZ * 1024;
    float* accum = (float*)(keybase + (size_t)BSZ * 2560);
    float* gpart    = (float*)alloc((size_t)BSZ * 512 * 4);
    float* dh1      = (float*)alloc((size_t)BSZ * 2048 * 4);
    float* dh2      = (float*)alloc((size_t)BSZ * 2048 * 4);
    float* dh3      = (float*)alloc((size_t)BSZ * 2048 * 4);
    float* pred     = (float*)alloc((size_t)BSZ * 6144 * 4);
    int*   idxa     = (int*)  alloc((size_t)BSZ * 64 * NBRK * 4);
    float* gatha    = (float*)alloc((size_t)BSZ * 64 * NBRK * 3 * 4);
    int*   idxb     = (int*)  alloc((size_t)BSZ * 32 * NBRK * 4);
    float* gathb    = (float*)alloc((size_t)BSZ * 32 * NBRK * 3 * 4);
    int*   idxc     = (int*)  alloc((size_t)BSZ * 32 * 32 * 4);
    float* gathc    = (float*)alloc((size_t)BSZ * 1024 * 3 * 4);
    int*   knn32    = (int*)  alloc((size_t)BSZ * 2048 * 32 * 4);
    float* nrmbuf   = (float*)alloc((size_t)BSZ * 2048 * 3 * 4);

    // ONE memset: all atomicMax key buffers + accum slots (idempotent per launch)
    hipMemsetAsync(keybase, 0, ((size_t)BSZ * 2560 + 8) * 4, stream);

    cvt_all_kernel<<<2688, 256, 0, stream>>>(W2, W3, W4, W2h, W3h, W4h);

    // FPS + grouping
    fps_kernel_v5<<<BSZ, 256, 0, stream>>>(pts, center);
    knn_kernel_v7<<<(BSZ * NG + 3) / 4, 256, 0, stream>>>(center, NG, 0, NG, pts, GS,
                                                          knnc, BSZ);
    gather_rebuild_kernel<<<(BSZ * 3072) / 256, 256, 0, stream>>>(pts, knnc,
                                                                  rebuild0, rebuild1);

    // encoder: 5 dispatches (layer1, gemm1+maxkey, skinny(inline-decode), gemm2, gemm3)
    auto enc = [&](const float* X, int n, unsigned* gkey, unsigned* fkeyout) {
        int M = BSZ * n;
        layer1_kernel<<<M / 16, 256, 0, stream>>>(X, W1, b1, g1, be1, m1, v1, H1h, M);
        mfma_gemm_kernel<<<dim3(256 / 128, M / 128), 256, 0, stream>>>(
            H1h, W2h, 128, 256, b2, nullptr, nullptr, nullptr, nullptr, nullptr,
            H2h, gkey, n, 0);
        skinny_v2_kernel<<<(512 + 3) / 4, 256, 0, stream>>>(
            (const float*)gkey, W3, 512, 0, b3, gpart, 256, 512, 0, 1);
        mfma_gemm_kernel<<<dim3(512 / 128, M / 128), 256, 0, stream>>>(
            H2h, W3h, 256, 512, nullptr, gpart, g2, be2, m2, v2, H3h, nullptr, n, 1);
        mfma_gemm_kernel<<<dim3(1024 / 128, M / 128), 256, 0, stream>>>(
            H3h, W4h, 512, 1024, b4, nullptr, nullptr, nullptr, nullptr, nullptr,
            nullptr, fkeyout, n, 0);
    };

    enc(rebuild0, 2048, gmaxkey1, featkey1);

    // decoder (skinny M=16, fp32; D1 decodes featkey1 inline)
    skinny_v2_kernel<<<2048 / 4, 256, 0, stream>>>((const float*)featkey1, D1W, 1024, 0,
                                                   D1b, dh1, 1024, 2048, 1, 1);
    skinny_v2_kernel<<<2048 / 4, 256, 0, stream>>>(dh1, D2W, 2048, 0, D2b, dh2,
                                                   2048, 2048, 1, 0);
    skinny_v2_kernel<<<2048 / 4, 256, 0, stream>>>(dh2, D3W, 2048, 0, D3b, dh3,
                                                   2048, 2048, 1, 0);
    skinny_v2_kernel<<<6144 / 4, 256, 0, stream>>>(dh3, D4W, 2048, 0, D4b, pred,
                                                   2048, 6144, 0, 0);

    // all pred-database KNNs in one dispatch: idxa/idxb/idxc + self knn32
    knn_post_kernel<<<512 + (BSZ * NPTS) / 4, 256, 0, stream>>>(center, pred, idxa,
                                                                idxb, idxc, knn32);
    gather_abc_kernel<<<(BSZ * 4672) / 256, 256, 0, stream>>>(pred, idxa, idxb, idxc,
                                                              gatha, gathb, gathc);
    chamfer4_kernel<<<3360, 256, 0, stream>>>(rebuild0, gatha, rebuild1, gathb, accum);
    normals_kernel<<<(BSZ * NPTS) / 64, 64, 0, stream>>>(pred, knn32, nrmbuf);

    enc(gathc, 1024, gmaxkey2, featkey2);
    latent_kernel<<<(BSZ * 1024 + 255) / 256, 256, 0, stream>>>(featkey1, featkey2,
                                                                BSZ * 1024, accum + 4);
    manifold_kernel<<<(BSZ * 2048 + 255) / 256, 256, 0, stream>>>(nrmbuf, knn32, 32,
                                                                  accum + 5);

    finalize_kernel<<<1, 1, 0, stream>>>(accum, (float*)d_out);
}

// Round 7
// 665.139 us; speedup vs baseline: 1.4827x; 1.1312x over previous
//
#include <hip/hip_runtime.h>
#include <math.h>

#define BSZ 16
#define NPTS 2048
#define NG 128
#define GS 32
#define NBRK 38

typedef _Float16 f16;
typedef _Float16 f16x8 __attribute__((ext_vector_type(8)));
typedef float f32x4 __attribute__((ext_vector_type(4)));

// ---------- helpers ----------
__device__ __forceinline__ unsigned fkey(float x) {
    unsigned u = __float_as_uint(x);
    return (u >> 31) ? ~u : (u | 0x80000000u);
}
__device__ __forceinline__ float fkey_inv(unsigned k) {
    unsigned u = (k >> 31) ? (k ^ 0x80000000u) : ~k;
    return __uint_as_float(u);
}

// 64-lane min via DPP (no LDS/DS pipe).
__device__ __forceinline__ unsigned wave_min_u32(unsigned v) {
    unsigned t;
    t = (unsigned)__builtin_amdgcn_update_dpp(-1, (int)v, 0x111, 0xF, 0xF, false);
    v = v < t ? v : t;
    t = (unsigned)__builtin_amdgcn_update_dpp(-1, (int)v, 0x112, 0xF, 0xF, false);
    v = v < t ? v : t;
    t = (unsigned)__builtin_amdgcn_update_dpp(-1, (int)v, 0x114, 0xF, 0xF, false);
    v = v < t ? v : t;
    t = (unsigned)__builtin_amdgcn_update_dpp(-1, (int)v, 0x118, 0xF, 0xF, false);
    v = v < t ? v : t;
    t = (unsigned)__builtin_amdgcn_update_dpp(-1, (int)v, 0x142, 0xA, 0xF, false);
    v = v < t ? v : t;
    t = (unsigned)__builtin_amdgcn_update_dpp(-1, (int)v, 0x143, 0xC, 0xF, false);
    v = v < t ? v : t;
    return (unsigned)__builtin_amdgcn_readlane((int)v, 63);
}

// 64-lane max of a u64 key via DPP (old=0 is identity for unsigned max).
__device__ __forceinline__ unsigned long long wave_max_u64(unsigned long long v) {
#define DPPSTEP(ctrl, rmask)                                                                \
    {                                                                                       \
        unsigned tlo = (unsigned)__builtin_amdgcn_update_dpp(0, (int)(unsigned)v, ctrl,     \
                                                             rmask, 0xF, false);            \
        unsigned thi = (unsigned)__builtin_amdgcn_update_dpp(0, (int)(unsigned)(v >> 32),   \
                                                             ctrl, rmask, 0xF, false);      \
        unsigned long long t = ((unsigned long long)thi << 32) | tlo;                       \
        v = t > v ? t : v;                                                                  \
    }
    DPPSTEP(0x111, 0xF)
    DPPSTEP(0x112, 0xF)
    DPPSTEP(0x114, 0xF)
    DPPSTEP(0x118, 0xF)
    DPPSTEP(0x142, 0xA)
    DPPSTEP(0x143, 0xC)
#undef DPPSTEP
    unsigned rlo = (unsigned)__builtin_amdgcn_readlane((int)(unsigned)v, 63);
    unsigned rhi = (unsigned)__builtin_amdgcn_readlane((int)(unsigned)(v >> 32), 63);
    return ((unsigned long long)rhi << 32) | rlo;
}

// ---------- FPS v5 (unchanged): 4 waves, one barrier/iter ----------
__global__ __launch_bounds__(256, 1) void fps_kernel_v5(const float* __restrict__ pts,
                                                        float* __restrict__ center) {
    int b = blockIdx.x;
    const float* P = pts + (size_t)b * NPTS * 3;
    int tid = threadIdx.x;
    int lane = tid & 63, wave = tid >> 6;
    __shared__ __align__(16) float Pl[NPTS * 3];
    __shared__ __align__(16) float slot[2][4][8];   // [parity][wave]{klo,khi,x,y,z,...}
#pragma unroll
    for (int i = 0; i < 6; ++i) {    // 1536 float4 = 24 KB, coalesced
        int v4 = tid + i * 256;
        ((f32x4*)Pl)[v4] = ((const f32x4*)P)[v4];
    }
    __syncthreads();
    float px[8], py[8], pz[8], mind[8];
#pragma unroll
    for (int m = 0; m < 8; ++m) {
        int j = tid + (m << 8);
        px[m] = Pl[j * 3 + 0];
        py[m] = Pl[j * 3 + 1];
        pz[m] = Pl[j * 3 + 2];
        mind[m] = 1e10f;
    }
    float cx = Pl[0], cy = Pl[1], cz = Pl[2];   // far = 0
    float* C = center + (size_t)b * NG * 3;
#pragma unroll 1
    for (int g = 0; g < NG; ++g) {
        if (tid == 0) {
            C[g * 3 + 0] = cx; C[g * 3 + 1] = cy; C[g * 3 + 2] = cz;
        }
        if (g == NG - 1) break;      // uniform: all threads exit together
        float best0 = -1.f, best1 = -1.f;
        int bm0 = 0, bm1 = 1;
#pragma unroll
        for (int m = 0; m < 8; m += 2) {   // 2 independent dep chains
            float dx0 = px[m] - cx, dy0 = py[m] - cy, dz0 = pz[m] - cz;
            float d0 = dx0 * dx0 + dy0 * dy0 + dz0 * dz0;
            float md0 = fminf(mind[m], d0);
            mind[m] = md0;
            if (md0 > best0) { best0 = md0; bm0 = m; }        // strict >: min m on tie
            float dx1 = px[m + 1] - cx, dy1 = py[m + 1] - cy, dz1 = pz[m + 1] - cz;
            float d1 = dx1 * dx1 + dy1 * dy1 + dz1 * dz1;
            float md1 = fminf(mind[m + 1], d1);
            mind[m + 1] = md1;
            if (md1 > best1) { best1 = md1; bm1 = m + 1; }
        }
        bool t = (best1 > best0) || (best1 == best0 && bm1 < bm0);
        float bv = t ? best1 : best0;
        int bi = t ? bm1 : bm0;
        unsigned j = (unsigned)(tid + (bi << 8));   // global point index
        unsigned long long key =
            ((unsigned long long)__float_as_uint(bv) << 32) | (unsigned)(~j);
        key = wave_max_u64(key);                    // broadcast to all lanes
        unsigned bj = ~(unsigned)key;
        int par = g & 1;
        if (lane < 3) slot[par][wave][2 + lane] = Pl[bj * 3 + lane];  // prefetch coords
        if (lane == 0) {
            slot[par][wave][0] = __uint_as_float((unsigned)key);
            slot[par][wave][1] = __uint_as_float((unsigned)(key >> 32));
        }
        __syncthreads();
        unsigned long long kb = 0ull;
        float nx = 0.f, ny = 0.f, nz = 0.f;
#pragma unroll
        for (int w = 0; w < 4; ++w) {
            f32x4 v = *(const f32x4*)&slot[par][w][0];   // klo,khi,x,y
            float vz = slot[par][w][4];
            unsigned long long kk =
                ((unsigned long long)__float_as_uint(v[1]) << 32) | __float_as_uint(v[0]);
            bool tw = kk > kb;
            kb = tw ? kk : kb;
            nx = tw ? v[2] : nx;
            ny = tw ? v[3] : ny;
            nz = tw ? vz : nz;
        }
        cx = nx; cy = ny; cz = nz;
    }
}

// ---------- KNN body (v7, unchanged logic): per-wave query, zero DS ops ----------
__device__ __forceinline__ void knn_query(const float* __restrict__ q,
                                          const float* __restrict__ db,
                                          int k, int* __restrict__ o, int lane) {
    const unsigned KINF = 0xFFFFFFFFu;
    float qx = q[0], qy = q[1], qz = q[2];
    float qq = qx * qx + qy * qy + qz * qz;
    unsigned key[32];
    unsigned c0 = KINF, c1 = KINF, c2 = KINF, c3 = KINF;
#pragma unroll
    for (int m = 0; m < 32; ++m) {
        int j = lane + (m << 6);
        float bx = db[j * 3 + 0], by = db[j * 3 + 1], bz = db[j * 3 + 2];
        float dv = qq + bx * bx + by * by + bz * bz - 2.0f * (qx * bx + qy * by + qz * bz);
        unsigned qd = (unsigned)fminf(fmaxf(dv, 0.f) * 8192.0f, 2097151.f);
        unsigned kk = (qd << 11) | (unsigned)j;
        key[m] = kk;
        if (kk < c3) {
            if (kk < c2) {
                c3 = c2;
                if (kk < c1) {
                    c2 = c1;
                    if (kk < c0) { c1 = c0; c0 = kk; } else c1 = kk;
                } else c2 = kk;
            } else c3 = kk;
        }
    }
    unsigned hw = c3;
    int ncached = 4;
    for (int r = 0; r < k; ++r) {
        bool need = (c0 == KINF) && (ncached < 32);
        if (__any(need)) {
            unsigned best = KINF;
#pragma unroll
            for (int m = 0; m < 32; ++m) {
                unsigned v = key[m];
                best = (v > hw && v < best) ? v : best;
            }
            if (need) {
                c0 = best;
                hw = best;
                ncached = (best == KINF) ? 32 : ncached + 1;
            }
        }
        unsigned g = wave_min_u32(c0);
        if (lane == 0) o[r] = (int)(g & 0x7FFu);
        if (((g & 0x7FFu) & 63u) == (unsigned)lane) {
            c0 = c1; c1 = c2; c2 = c3; c3 = KINF;
        }
    }
}

// group KNN: center queries vs pts
__global__ void knn_kernel_v7(const float* __restrict__ Q, int q_bstride, int q_off, int nq,
                              const float* __restrict__ DB, int k,
                              int* __restrict__ out, int nbatch) {
    int wave = threadIdx.x >> 6, lane = threadIdx.x & 63;
    int qidx = blockIdx.x * 4 + wave;
    if (qidx >= nbatch * nq) return;     // wave-uniform
    int b = qidx / nq, qi = qidx % nq;
    knn_query(Q + ((size_t)b * q_bstride + q_off + qi) * 3,
              DB + (size_t)b * NPTS * 3, k, out + (size_t)qidx * k, lane);
}

// ---------- fused post-decoder KNN: 3 center-vs-pred jobs + self-KNN ----------
__global__ void knn_post_kernel(const float* __restrict__ center,
                                const float* __restrict__ pred,
                                int* __restrict__ idxa, int* __restrict__ idxb,
                                int* __restrict__ idxc, int* __restrict__ knn32) {
    int wave = threadIdx.x >> 6, lane = threadIdx.x & 63;
    if (blockIdx.x < 512) {
        int qidx = blockIdx.x * 4 + wave;        // 2048 = BSZ*128 exact
        int b = qidx >> 7, qi = qidx & 127;
        const float* q = center + ((size_t)b * NG + qi) * 3;
        const float* db = pred + (size_t)b * NPTS * 3;
        int k; int* o;
        if (qi < 64) { k = NBRK; o = idxa + ((size_t)b * 64 + qi) * NBRK; }
        else if (qi < 96) { k = NBRK; o = idxb + ((size_t)b * 32 + qi - 64) * NBRK; }
        else { k = GS; o = idxc + ((size_t)b * 32 + qi - 96) * GS; }
        knn_query(q, db, k, o, lane);
    } else {
        int qidx = (blockIdx.x - 512) * 4 + wave;   // 32768 = BSZ*2048 exact
        int b = qidx >> 11, qi = qidx & 2047;
        const float* db = pred + (size_t)b * NPTS * 3;
        knn_query(db + (size_t)qi * 3, db, GS, knn32 + (size_t)qidx * GS, lane);
    }
}

// ---------- fused gathers (now also emit packed float4 {x,y,z,|p|^2}) ----------
// rebuild0 (x3 + packed4) + rebuild1 (x3 + packed4) from pts via knnc
__global__ void gather_rebuild_kernel(const float* __restrict__ pts,
                                      const int* __restrict__ knnc,
                                      float* __restrict__ rebuild0,
                                      float* __restrict__ rebuild1,
                                      f32x4* __restrict__ r0p4,
                                      f32x4* __restrict__ r1p4) {
    int t = blockIdx.x * 256 + threadIdx.x;
    if (t < BSZ * 2048) {
        int b = t >> 11, j = t & 2047;
        int s = knnc[(size_t)b * (NG * GS) + j];
        const float* p = pts + ((size_t)b * NPTS + s) * 3;
        float x = p[0], y = p[1], z = p[2];
        rebuild0[(size_t)t * 3 + 0] = x;
        rebuild0[(size_t)t * 3 + 1] = y;
        rebuild0[(size_t)t * 3 + 2] = z;
        r0p4[t] = (f32x4){x, y, z, x * x + y * y + z * z};
    } else {
        int tt = t - BSZ * 2048;
        int b = tt >> 10, j = tt & 1023;
        int s = knnc[(size_t)b * (NG * GS) + 2048 + j];
        const float* p = pts + ((size_t)b * NPTS + s) * 3;
        float x = p[0], y = p[1], z = p[2];
        rebuild1[(size_t)tt * 3 + 0] = x;
        rebuild1[(size_t)tt * 3 + 1] = y;
        rebuild1[(size_t)tt * 3 + 2] = z;
        r1p4[tt] = (f32x4){x, y, z, x * x + y * y + z * z};
    }
}

// gatha->gap4 (BSZ*2432), gathb->gbp4 (BSZ*1216) packed; gathc (x3, encoder input)
__global__ void gather_abc_kernel(const float* __restrict__ pred,
                                  const int* __restrict__ idxa,
                                  const int* __restrict__ idxb,
                                  const int* __restrict__ idxc,
                                  f32x4* __restrict__ gap4,
                                  f32x4* __restrict__ gbp4,
                                  float* __restrict__ gathc) {
    const int NA = BSZ * 2432, NB_ = BSZ * 1216, NC = BSZ * 1024;
    int t = blockIdx.x * 256 + threadIdx.x;
    if (t < NA) {
        int b = t / 2432, j = t - b * 2432;
        int s = idxa[(size_t)b * 2432 + j];
        const float* p = pred + ((size_t)b * NPTS + s) * 3;
        float x = p[0], y = p[1], z = p[2];
        gap4[t] = (f32x4){x, y, z, x * x + y * y + z * z};
    } else if (t < NA + NB_) {
        int tt = t - NA;
        int b = tt / 1216, j = tt - b * 1216;
        int s = idxb[(size_t)b * 1216 + j];
        const float* p = pred + ((size_t)b * NPTS + s) * 3;
        float x = p[0], y = p[1], z = p[2];
        gbp4[tt] = (f32x4){x, y, z, x * x + y * y + z * z};
    } else if (t < NA + NB_ + NC) {
        int tt = t - NA - NB_;
        int b = tt >> 10, j = tt & 1023;
        int s = idxc[(size_t)b * 1024 + j];
        const float* p = pred + ((size_t)b * NPTS + s) * 3;
        gathc[(size_t)tt * 3 + 0] = p[0];
        gathc[(size_t)tt * 3 + 1] = p[1];
        gathc[(size_t)tt * 3 + 2] = p[2];
    }
}

// ---------- fused fp32 -> fp16 weight conversion (3 matrices, 1 dispatch) ----------
__global__ void cvt_all_kernel(const float* __restrict__ W2, const float* __restrict__ W3,
                               const float* __restrict__ W4, f16* __restrict__ W2h,
                               f16* __restrict__ W3h, f16* __restrict__ W4h) {
    int t = blockIdx.x * 256 + threadIdx.x;
    if (t < 32768) {                       // W2h: 256x128, ld 128, off 0
        int n = t >> 7, k = t & 127;
        W2h[t] = (f16)W2[(size_t)n * 128 + k];
    } else if (t < 163840) {               // W3h: 512x256, ld 512, off 256
        int u = t - 32768;
        int n = u >> 8, k = u & 255;
        W3h[u] = (f16)W3[(size_t)n * 512 + 256 + k];
    } else if (t < 688128) {               // W4h: 1024x512, ld 512, off 0
        int u = t - 163840;
        int n = u >> 9, k = u & 511;
        W4h[u] = (f16)W4[(size_t)n * 512 + k];
    }
}

// ---------- layer1: H1 = relu(bn(x @ W1^T + b1)) in fp16, fused ----------
__global__ void layer1_kernel(const float* __restrict__ X, const float* __restrict__ W1,
                              const float* __restrict__ b1, const float* __restrict__ g1,
                              const float* __restrict__ be1, const float* __restrict__ m1,
                              const float* __restrict__ v1, f16* __restrict__ H1, int M) {
    __shared__ float w[384], bb[128], sg[128], sb[128], sm[128], sv[128];
    for (int i = threadIdx.x; i < 384; i += 256) w[i] = W1[i];
    if (threadIdx.x < 128) {
        int c = threadIdx.x;
        bb[c] = b1[c]; sg[c] = g1[c]; sb[c] = be1[c]; sm[c] = m1[c]; sv[c] = v1[c];
    }
    __syncthreads();
    int t = blockIdx.x * 256 + threadIdx.x;
    if (t >= M * 16) return;
    int row = t >> 4, cg = (t & 15) * 8;
    float x0 = X[(size_t)row * 3], x1 = X[(size_t)row * 3 + 1], x2 = X[(size_t)row * 3 + 2];
    f16x8 outv;
#pragma unroll
    for (int j = 0; j < 8; ++j) {
        int c = cg + j;
        float tv = x0 * w[c * 3] + x1 * w[c * 3 + 1] + x2 * w[c * 3 + 2] + bb[c];
        float vv = (tv - sm[c]) * rsqrtf(sv[c] + 1e-5f) * sg[c] + sb[c];
        outv[j] = (f16)fmaxf(vv, 0.f);
    }
    *(f16x8*)&H1[(size_t)row * 128 + cg] = outv;
}

// ---------- MFMA GEMM v2 (unchanged): XCD swizzle + reg prefetch ----------
__global__ __launch_bounds__(256) void mfma_gemm_kernel(
        const f16* __restrict__ A, const f16* __restrict__ W, int K, int N,
        const float* __restrict__ bias, const float* __restrict__ bias2d,
        const float* __restrict__ bng, const float* __restrict__ bnb,
        const float* __restrict__ bnm, const float* __restrict__ bnv,
        f16* __restrict__ Cout, unsigned* __restrict__ maxkey,
        int rows_per_batch, int relu) {
    __shared__ f16 Als[128 * 40];
    __shared__ f16 Bls[128 * 40];
    int tid = threadIdx.x;
    int lane = tid & 63;
    int wave = tid >> 6;
    int wm = wave & 1, wn = wave >> 1;
    int c16 = lane & 15, quad = lane >> 4;
    int gx = gridDim.x;
    int nwg = gx * gridDim.y;
    int lin = blockIdx.y * gx + blockIdx.x;
    int qc = nwg >> 3, rc = nwg & 7;
    int xcd = lin & 7, pos = lin >> 3;
    int nlin = (xcd < rc ? xcd * (qc + 1) : rc * (qc + 1) + (xcd - rc) * qc) + pos;
    int row0 = (nlin / gx) * 128, col0 = (nlin % gx) * 128;
    int sr = tid >> 2;
    int skc = (tid & 3) * 8;

    f32x4 acc[4][4];
#pragma unroll
    for (int i = 0; i < 4; ++i)
#pragma unroll
        for (int j = 0; j < 4; ++j) acc[i][j] = (f32x4){0.f, 0.f, 0.f, 0.f};

    const f16* Ab = A + (size_t)(row0 + sr) * K + skc;
    const f16* Ab2 = A + (size_t)(row0 + sr + 64) * K + skc;
    const f16* Wb = W + (size_t)(col0 + sr) * K + skc;
    const f16* Wb2 = W + (size_t)(col0 + sr + 64) * K + skc;

    f16x8 pa0 = *(const f16x8*)Ab;
    f16x8 pa1 = *(const f16x8*)Ab2;
    f16x8 pb0 = *(const f16x8*)Wb;
    f16x8 pb1 = *(const f16x8*)Wb2;

    for (int k0 = 0; k0 < K; k0 += 32) {
        *(f16x8*)&Als[sr * 40 + skc] = pa0;
        *(f16x8*)&Als[(sr + 64) * 40 + skc] = pa1;
        *(f16x8*)&Bls[sr * 40 + skc] = pb0;
        *(f16x8*)&Bls[(sr + 64) * 40 + skc] = pb1;
        __syncthreads();
        if (k0 + 32 < K) {
            int kn = k0 + 32;
            pa0 = *(const f16x8*)(Ab + kn);
            pa1 = *(const f16x8*)(Ab2 + kn);
            pb0 = *(const f16x8*)(Wb + kn);
            pb1 = *(const f16x8*)(Wb2 + kn);
        }
        f16x8 af[4], bf[4];
#pragma unroll
        for (int s = 0; s < 4; ++s) {
            af[s] = *(const f16x8*)&Als[(wm * 64 + s * 16 + c16) * 40 + quad * 8];
            bf[s] = *(const f16x8*)&Bls[(wn * 64 + s * 16 + c16) * 40 + quad * 8];
        }
#pragma unroll
        for (int ms = 0; ms < 4; ++ms)
#pragma unroll
            for (int ns = 0; ns < 4; ++ns)
                acc[ms][ns] = __builtin_amdgcn_mfma_f32_16x16x32_f16(af[ms], bf[ns],
                                                                     acc[ms][ns], 0, 0, 0);
        __syncthreads();
    }

    int b = row0 / rows_per_batch;
#pragma unroll
    for (int ns = 0; ns < 4; ++ns) {
        int col = col0 + wn * 64 + ns * 16 + c16;
        float bv = bias ? bias[col] : 0.f;
        float b2v = bias2d ? bias2d[(size_t)b * N + col] : 0.f;
        float mx = -3e38f;
#pragma unroll
        for (int ms = 0; ms < 4; ++ms) {
#pragma unroll
            for (int j = 0; j < 4; ++j) {
                float v = acc[ms][ns][j] + bv + b2v;
                if (bng) v = (v - bnm[col]) * rsqrtf(bnv[col] + 1e-5f) * bng[col] + bnb[col];
                if (relu) v = fmaxf(v, 0.f);
                if (Cout)
                    Cout[(size_t)(row0 + wm * 64 + ms * 16 + quad * 4 + j) * N + col] = (f16)v;
                mx = fmaxf(mx, v);
            }
        }
        if (maxkey) {
            mx = fmaxf(mx, __shfl_xor(mx, 16, 64));
            mx = fmaxf(mx, __shfl_xor(mx, 32, 64));
            if (quad == 0) atomicMax(&maxkey[(size_t)b * N + col], fkey(mx));
        }
    }
}

// ---------- skinny GEMM v3: wave/column, optional inline fkey decode of A ----------
__global__ void skinny_v2_kernel(const float* __restrict__ A, const float* __restrict__ W,
                                 int ldw, int woff, const float* __restrict__ bias,
                                 float* __restrict__ C, int K, int N, int relu, int akey) {
    int wave = threadIdx.x >> 6, lane = threadIdx.x & 63;
    int col = blockIdx.x * 4 + wave;
    if (col >= N) return;
    const float* w = W + (size_t)col * ldw + woff;
    float acc[16];
#pragma unroll
    for (int m = 0; m < 16; ++m) acc[m] = 0.f;
    for (int k0 = 0; k0 < K; k0 += 256) {
        f32x4 wv = *(const f32x4*)(w + k0 + lane * 4);
#pragma unroll
        for (int m = 0; m < 16; ++m) {
            f32x4 av = *(const f32x4*)(A + (size_t)m * K + k0 + lane * 4);
            if (akey) {
#pragma unroll
                for (int u = 0; u < 4; ++u) av[u] = fkey_inv(__float_as_uint(av[u]));
            }
            acc[m] += av[0] * wv[0] + av[1] * wv[1] + av[2] * wv[2] + av[3] * wv[3];
        }
    }
#pragma unroll
    for (int m = 0; m < 16; ++m)
#pragma unroll
        for (int s = 1; s < 64; s <<= 1) acc[m] += __shfl_xor(acc[m], s, 64);
    if (lane == 0) {
        float bv = bias[col];
#pragma unroll
        for (int m = 0; m < 16; ++m) {
            float v = acc[m] + bv;
            if (relu) v = fmaxf(v, 0.f);
            C[(size_t)m * N + col] = v;
        }
    }
}

// ---------- chamfer v3: thread-per-A-point, B in LDS (uniform broadcast) ----------
// R6 counters: 130 µs, VALUBusy 74% -> VALU-issue-bound at ~12-16 instr/pair
// (3 scalar loads + |b|^2 recompute + addressing per pair).
// v3: packed float4 {x,y,z,|b|^2} staged in LDS once per block; all 64 lanes read
// the SAME Bl[j] (uniform ds_read_b128 broadcast, conflict-free); aa folded out of
// the min (fp-add monotone): inner loop = 3 FMA + 1 fmin per pair, 4 independent
// min chains. 199M pairs x 4 instr / 64 lanes ~ 10 us VALU floor.
// Jobs: 0:[0,128) r0p4(2048) vs gap4(2432); 1:[128,288) gap4(2432) vs r0p4(2048);
//       2:[288,352) r1p4(1024) vs gbp4(1216); 3:[352,432) gbp4(1216) vs r1p4(1024).
__global__ __launch_bounds__(256) void chamfer4_kernel(const f32x4* __restrict__ r0p4,
                                                       const f32x4* __restrict__ gap4,
                                                       const f32x4* __restrict__ r1p4,
                                                       const f32x4* __restrict__ gbp4,
                                                       float* __restrict__ accum) {
    __shared__ __align__(16) float Bl[2432 * 4];   // 38.9 KB max
    int blk = blockIdx.x;
    const f32x4 *A4, *B4; int na, nb, base, bpb; float* slot;
    if (blk < 128)      { A4 = r0p4; na = 2048; B4 = gap4; nb = 2432; slot = accum + 0; base = 0;   bpb = 8; }
    else if (blk < 288) { A4 = gap4; na = 2432; B4 = r0p4; nb = 2048; slot = accum + 1; base = 128; bpb = 10; }
    else if (blk < 352) { A4 = r1p4; na = 1024; B4 = gbp4; nb = 1216; slot = accum + 2; base = 288; bpb = 4; }
    else                { A4 = gbp4; na = 1216; B4 = r1p4; nb = 1024; slot = accum + 3; base = 352; bpb = 5; }
    int rel = blk - base;
    int b = rel / bpb, chunk = rel - b * bpb;
    for (int i = threadIdx.x; i < nb; i += 256)
        ((f32x4*)Bl)[i] = B4[(size_t)b * nb + i];
    __syncthreads();
    int aidx = chunk * 256 + threadIdx.x;
    float val = 0.f;
    if (aidx < na) {
        f32x4 a = A4[(size_t)b * na + aidx];
        float m2x = -2.f * a[0], m2y = -2.f * a[1], m2z = -2.f * a[2];
        float m0 = 3e38f, m1 = 3e38f, m2 = 3e38f, m3 = 3e38f;   // 4 indep chains
        for (int j = 0; j < nb; j += 4) {                       // nb % 4 == 0 always
            f32x4 b0 = ((const f32x4*)Bl)[j + 0];
            f32x4 b1 = ((const f32x4*)Bl)[j + 1];
            f32x4 b2 = ((const f32x4*)Bl)[j + 2];
            f32x4 b3 = ((const f32x4*)Bl)[j + 3];
            float t0 = fmaf(m2z, b0[2], fmaf(m2y, b0[1], fmaf(m2x, b0[0], b0[3])));
            float t1 = fmaf(m2z, b1[2], fmaf(m2y, b1[1], fmaf(m2x, b1[0], b1[3])));
            float t2 = fmaf(m2z, b2[2], fmaf(m2y, b2[1], fmaf(m2x, b2[0], b2[3])));
            float t3 = fmaf(m2z, b3[2], fmaf(m2y, b3[1], fmaf(m2x, b3[0], b3[3])));
            m0 = fminf(m0, t0); m1 = fminf(m1, t1);
            m2 = fminf(m2, t2); m3 = fminf(m3, t3);
        }
        float m = fminf(fminf(m0, m1), fminf(m2, m3));
        val = sqrtf(fmaxf(a[3] + m, 1e-12f));
    }
    __shared__ float sdata[256];
    sdata[threadIdx.x] = val;
    __syncthreads();
    for (int s = 128; s > 0; s >>= 1) {
        if (threadIdx.x < s) sdata[threadIdx.x] += sdata[threadIdx.x + s];
        __syncthreads();
    }
    if (threadIdx.x == 0) atomicAdd(slot, sdata[0]);
}

// ---------- smooth-L1 latent loss: inline fkey decode of both operands ----------
__global__ void latent_kernel(const unsigned* __restrict__ k1,
                              const unsigned* __restrict__ k2,
                              int n, float* __restrict__ slot) {
    int t = blockIdx.x * blockDim.x + threadIdx.x;
    float val = 0.f;
    if (t < n) {
        float d = fkey_inv(k1[t]) - fkey_inv(k2[t]);
        float ad = fabsf(d);
        val = (ad < 1.f) ? (0.5f * d * d) : (ad - 0.5f);
    }
    __shared__ float sdata[256];
    sdata[threadIdx.x] = val;
    __syncthreads();
    for (int s = 128; s > 0; s >>= 1) {
        if (threadIdx.x < s) sdata[threadIdx.x] += sdata[threadIdx.x + s];
        __syncthreads();
    }
    if (threadIdx.x == 0) atomicAdd(slot, sdata[0]);
}

// ---------- 3x3 symmetric smallest eigenvector (double, analytic) ----------
__device__ void smallest_evec(double cxx, double cxy, double cxz,
                              double cyy, double cyz, double czz, double ev[3]) {
    double p1 = cxy * cxy + cxz * cxz + cyz * cyz;
    double q = (cxx + cyy + czz) / 3.0;
    double p2 = (cxx - q) * (cxx - q) + (cyy - q) * (cyy - q) + (czz - q) * (czz - q) + 2.0 * p1;
    double lam = q;
    if (p2 > 0.0) {
        double p = sqrt(p2 / 6.0);
        double b00 = (cxx - q) / p, b11 = (cyy - q) / p, b22 = (czz - q) / p;
        double b01 = cxy / p, b02 = cxz / p, b12 = cyz / p;
        double detB = b00 * (b11 * b22 - b12 * b12) - b01 * (b01 * b22 - b12 * b02)
                    + b02 * (b01 * b12 - b11 * b02);
        double r = detB * 0.5;
        r = r < -1.0 ? -1.0 : (r > 1.0 ? 1.0 : r);
        double phi = acos(r) / 3.0;
        lam = q + 2.0 * p * cos(phi + 2.0943951023931953);
    }
    double r0x = cxx - lam, r0y = cxy, r0z = cxz;
    double r1x = cxy, r1y = cyy - lam, r1z = cyz;
    double r2x = cxz, r2y = cyz, r2z = czz - lam;
    double c0x = r0y * r1z - r0z * r1y, c0y = r0z * r1x - r0x * r1z, c0z = r0x * r1y - r0y * r1x;
    double c1x = r0y * r2z - r0z * r2y, c1y = r0z * r2x - r0x * r2z, c1z = r0x * r2y - r0y * r2x;
    double c2x = r1y * r2z - r1z * r2y, c2y = r1z * r2x - r1x * r2z, c2z = r1x * r2y - r1y * r2x;
    double n0 = c0x * c0x + c0y * c0y + c0z * c0z;
    double n1 = c1x * c1x + c1y * c1y + c1z * c1z;
    double n2 = c2x * c2x + c2y * c2y + c2z * c2z;
    double bx = c0x, by = c0y, bz = c0z, bn = n0;
    if (n1 > bn) { bx = c1x; by = c1y; bz = c1z; bn = n1; }
    if (n2 > bn) { bx = c2x; by = c2y; bz = c2z; bn = n2; }
    if (bn < 1e-280) { ev[0] = 1.0; ev[1] = 0.0; ev[2] = 0.0; return; }
    double inv = 1.0 / sqrt(bn);
    ev[0] = bx * inv; ev[1] = by * inv; ev[2] = bz * inv;
}

// ---------- normals v2 (unchanged): single-pass moments ----------
__global__ __launch_bounds__(64) void normals_kernel(const float* __restrict__ pred,
                                                     const int* __restrict__ knn,
                                                     float* __restrict__ nrm) {
    int t = blockIdx.x * 64 + threadIdx.x;
    if (t >= BSZ * NPTS) return;
    int b = t / NPTS, i = t % NPTS;
    const float* P = pred + (size_t)b * NPTS * 3;
    const int* id = knn + (size_t)t * 32;
    double sx = 0, sy = 0, sz = 0;
    double sxx = 0, sxy = 0, sxz = 0, syy = 0, syz = 0, szz = 0;
#pragma unroll
    for (int k0 = 0; k0 < 32; k0 += 4) {
        int4 jj = *(const int4*)&id[k0];
#pragma unroll
        for (int u = 0; u < 4; ++u) {
            int j = (u == 0) ? jj.x : (u == 1) ? jj.y : (u == 2) ? jj.z : jj.w;
            double x = (double)P[j * 3 + 0];
            double y = (double)P[j * 3 + 1];
            double z = (double)P[j * 3 + 2];
            sx += x; sy += y; sz += z;
            sxx += x * x; sxy += x * y; sxz += x * z;
            syy += y * y; syz += y * z; szz += z * z;
        }
    }
    double mx = sx * (1.0 / 32.0), my = sy * (1.0 / 32.0), mz = sz * (1.0 / 32.0);
    double cxx = sxx * (1.0 / 32.0) - mx * mx;
    double cxy = sxy * (1.0 / 32.0) - mx * my;
    double cxz = sxz * (1.0 / 32.0) - mx * mz;
    double cyy = syy * (1.0 / 32.0) - my * my;
    double cyz = syz * (1.0 / 32.0) - my * mz;
    double czz = szz * (1.0 / 32.0) - mz * mz;
    double ev[3];
    smallest_evec(cxx, cxy, cxz, cyy, cyz, czz, ev);
    float qx = P[i * 3 + 0], qy = P[i * 3 + 1], qz = P[i * 3 + 2];
    double proj = (sx - 32.0 * (double)qx) * ev[0] + (sy - 32.0 * (double)qy) * ev[1]
                + (sz - 32.0 * (double)qz) * ev[2];
    double s = (proj >= 0.0) ? 1.0 : -1.0;
    nrm[(size_t)t * 3 + 0] = (float)(ev[0] * s);
    nrm[(size_t)t * 3 + 1] = (float)(ev[1] * s);
    nrm[(size_t)t * 3 + 2] = (float)(ev[2] * s);
}

// ---------- manifold loss: reads first 8 of the 32-NN list ----------
__global__ void manifold_kernel(const float* __restrict__ nrm, const int* __restrict__ knn,
                                int kstride, float* __restrict__ slot) {
    int t = blockIdx.x * blockDim.x + threadIdx.x;
    float val = 0.f;
    if (t < BSZ * NPTS) {
        int b = t / NPTS;
        const float* NB = nrm + (size_t)b * NPTS * 3;
        const int* id = knn + (size_t)t * kstride;
        int j0 = id[0];
        float ax = NB[j0 * 3 + 0], ay = NB[j0 * 3 + 1], az = NB[j0 * 3 + 2];
        float an = fmaxf(sqrtf(ax * ax + ay * ay + az * az), 1e-6f);
        float x[8]; float s = 0.f;
        for (int k = 0; k < 8; ++k) {
            int j = id[k];
            float bx = NB[j * 3 + 0], by = NB[j * 3 + 1], bz = NB[j * 3 + 2];
            float bn_ = fmaxf(sqrtf(bx * bx + by * by + bz * bz), 1e-6f);
            float c = (ax * bx + ay * by + az * bz) / (an * bn_);
            x[k] = 1.f - c; s += x[k];
        }
        float mean = s / 8.f;
        float var = 0.f;
        for (int k = 0; k < 8; ++k) { float d = x[k] - mean; var += d * d; }
        val = sqrtf(var / 7.f);
    }
    __shared__ float sdata[256];
    sdata[threadIdx.x] = val;
    __syncthreads();
    for (int s2 = 128; s2 > 0; s2 >>= 1) {
        if (threadIdx.x < s2) sdata[threadIdx.x] += sdata[threadIdx.x + s2];
        __syncthreads();
    }
    if (threadIdx.x == 0) atomicAdd(slot, sdata[0]);
}

__global__ void finalize_kernel(const float* __restrict__ acc, float* __restrict__ out) {
    float l_recon = 0.5f * (acc[0] / (16.f * 2048.f) + acc[1] / (16.f * 2432.f));
    float l_match = 0.5f * (acc[2] / (16.f * 1024.f) + acc[3] / (16.f * 1216.f));
    float l_latent = acc[4] / (16.f * 1024.f);
    float l_man = 0.1f * (acc[5] / (16.f * 2048.f));
    out[0] = l_recon + l_match + l_latent + l_man;
    out[1] = l_recon;
    out[2] = l_match;
    out[3] = l_latent;
    out[4] = l_man;
}

// ================= host =================
extern "C" void kernel_launch(void* const* d_in, const int* in_sizes, int n_in,
                              void* d_out, int out_size, void* d_ws, size_t ws_size,
                              hipStream_t stream) {
    (void)in_sizes; (void)n_in; (void)out_size; (void)ws_size;
    const float* pts = (const float*)d_in[0];
    const float* W1 = (const float*)d_in[1];
    const float* b1 = (const float*)d_in[2];
    const float* g1 = (const float*)d_in[3];
    const float* be1 = (const float*)d_in[4];
    const float* m1 = (const float*)d_in[5];
    const float* v1 = (const float*)d_in[6];
    const float* W2 = (const float*)d_in[7];
    const float* b2 = (const float*)d_in[8];
    const float* W3 = (const float*)d_in[9];
    const float* b3 = (const float*)d_in[10];
    const float* g2 = (const float*)d_in[11];
    const float* be2 = (const float*)d_in[12];
    const float* m2 = (const float*)d_in[13];
    const float* v2 = (const float*)d_in[14];
    const float* W4 = (const float*)d_in[15];
    const float* b4 = (const float*)d_in[16];
    const float* D1W = (const float*)d_in[17];
    const float* D1b = (const float*)d_in[18];
    const float* D2W = (const float*)d_in[19];
    const float* D2b = (const float*)d_in[20];
    const float* D3W = (const float*)d_in[21];
    const float* D3b = (const float*)d_in[22];
    const float* D4W = (const float*)d_in[23];
    const float* D4b = (const float*)d_in[24];

    char* ws = (char*)d_ws;
    size_t off = 0;
    auto alloc = [&](size_t bytes) -> void* {
        void* p = ws + off;
        off += (bytes + 255) & ~(size_t)255;
        return p;
    };
    float* center   = (float*)alloc((size_t)BSZ * NG * 3 * 4);
    int*   knnc     = (int*)  alloc((size_t)BSZ * NG * GS * 4);
    float* rebuild0 = (float*)alloc((size_t)BSZ * 2048 * 3 * 4);
    float* rebuild1 = (float*)alloc((size_t)BSZ * 1024 * 3 * 4);
    f32x4* r0p4     = (f32x4*)alloc((size_t)BSZ * 2048 * 16);
    f32x4* r1p4     = (f32x4*)alloc((size_t)BSZ * 1024 * 16);
    f16*   W2h      = (f16*)  alloc((size_t)256 * 128 * 2);
    f16*   W3h      = (f16*)  alloc((size_t)512 * 256 * 2);
    f16*   W4h      = (f16*)  alloc((size_t)1024 * 512 * 2);
    f16*   H1h      = (f16*)  alloc((size_t)BSZ * 2048 * 128 * 2);
    f16*   H2h      = (f16*)  alloc((size_t)BSZ * 2048 * 256 * 2);
    f16*   H3h      = (f16*)  alloc((size_t)BSZ * 2048 * 512 * 2);
    // contiguous key region + accum: ONE memset covers all
    unsigned* keybase = (unsigned*)alloc(((size_t)BSZ * 2560 + 64) * 4);
    unsigned* gmaxkey1 = keybase;
    unsigned* gmaxkey2 = keybase + (size_t)BSZ * 256;
    unsigned* featkey1 = keybase + (size_t)BSZ * 512;
    unsigned* featkey2 = keybase + (size_t)BSZ * 512 + (size_t)BSZ * 1024;
    float* accum = (float*)(keybase + (size_t)BSZ * 2560);
    float* gpart    = (float*)alloc((size_t)BSZ * 512 * 4);
    float* dh1      = (float*)alloc((size_t)BSZ * 2048 * 4);
    float* dh2      = (float*)alloc((size_t)BSZ * 2048 * 4);
    float* dh3      = (float*)alloc((size_t)BSZ * 2048 * 4);
    float* pred     = (float*)alloc((size_t)BSZ * 6144 * 4);
    int*   idxa     = (int*)  alloc((size_t)BSZ * 64 * NBRK * 4);
    int*   idxb     = (int*)  alloc((size_t)BSZ * 32 * NBRK * 4);
    int*   idxc     = (int*)  alloc((size_t)BSZ * 32 * 32 * 4);
    f32x4* gap4     = (f32x4*)alloc((size_t)BSZ * 2432 * 16);
    f32x4* gbp4     = (f32x4*)alloc((size_t)BSZ * 1216 * 16);
    float* gathc    = (float*)alloc((size_t)BSZ * 1024 * 3 * 4);
    int*   knn32    = (int*)  alloc((size_t)BSZ * 2048 * 32 * 4);
    float* nrmbuf   = (float*)alloc((size_t)BSZ * 2048 * 3 * 4);

    // ONE memset: all atomicMax key buffers + accum slots
    hipMemsetAsync(keybase, 0, ((size_t)BSZ * 2560 + 8) * 4, stream);

    cvt_all_kernel<<<2688, 256, 0, stream>>>(W2, W3, W4, W2h, W3h, W4h);

    // FPS + grouping
    fps_kernel_v5<<<BSZ, 256, 0, stream>>>(pts, center);
    knn_kernel_v7<<<(BSZ * NG + 3) / 4, 256, 0, stream>>>(center, NG, 0, NG, pts, GS,
                                                          knnc, BSZ);
    gather_rebuild_kernel<<<(BSZ * 3072) / 256, 256, 0, stream>>>(pts, knnc, rebuild0,
                                                                  rebuild1, r0p4, r1p4);

    // encoder: 5 dispatches
    auto enc = [&](const float* X, int n, unsigned* gkey, unsigned* fkeyout) {
        int M = BSZ * n;
        layer1_kernel<<<M / 16, 256, 0, stream>>>(X, W1, b1, g1, be1, m1, v1, H1h, M);
        mfma_gemm_kernel<<<dim3(256 / 128, M / 128), 256, 0, stream>>>(
            H1h, W2h, 128, 256, b2, nullptr, nullptr, nullptr, nullptr, nullptr,
            H2h, gkey, n, 0);
        skinny_v2_kernel<<<(512 + 3) / 4, 256, 0, stream>>>(
            (const float*)gkey, W3, 512, 0, b3, gpart, 256, 512, 0, 1);
        mfma_gemm_kernel<<<dim3(512 / 128, M / 128), 256, 0, stream>>>(
            H2h, W3h, 256, 512, nullptr, gpart, g2, be2, m2, v2, H3h, nullptr, n, 1);
        mfma_gemm_kernel<<<dim3(1024 / 128, M / 128), 256, 0, stream>>>(
            H3h, W4h, 512, 1024, b4, nullptr, nullptr, nullptr, nullptr, nullptr,
            nullptr, fkeyout, n, 0);
    };

    enc(rebuild0, 2048, gmaxkey1, featkey1);

    // decoder (skinny M=16, fp32; D1 decodes featkey1 inline)
    skinny_v2_kernel<<<2048 / 4, 256, 0, stream>>>((const float*)featkey1, D1W, 1024, 0,
                                                   D1b, dh1, 1024, 2048, 1, 1);
    skinny_v2_kernel<<<2048 / 4, 256, 0, stream>>>(dh1, D2W, 2048, 0, D2b, dh2,
                                                   2048, 2048, 1, 0);
    skinny_v2_kernel<<<2048 / 4, 256, 0, stream>>>(dh2, D3W, 2048, 0, D3b, dh3,
                                                   2048, 2048, 1, 0);
    skinny_v2_kernel<<<6144 / 4, 256, 0, stream>>>(dh3, D4W, 2048, 0, D4b, pred,
                                                   2048, 6144, 0, 0);

    // all pred-database KNNs in one dispatch
    knn_post_kernel<<<512 + (BSZ * NPTS) / 4, 256, 0, stream>>>(center, pred, idxa,
                                                                idxb, idxc, knn32);
    gather_abc_kernel<<<(BSZ * 4672) / 256, 256, 0, stream>>>(pred, idxa, idxb, idxc,
                                                              gap4, gbp4, gathc);
    chamfer4_kernel<<<432, 256, 0, stream>>>(r0p4, gap4, r1p4, gbp4, accum);
    normals_kernel<<<(BSZ * NPTS) / 64, 64, 0, stream>>>(pred, knn32, nrmbuf);

    enc(gathc, 1024, gmaxkey2, featkey2);
    latent_kernel<<<(BSZ * 1024 + 255) / 256, 256, 0, stream>>>(featkey1, featkey2,
                                                                BSZ * 1024, accum + 4);
    manifold_kernel<<<(BSZ * 2048 + 255) / 256, 256, 0, stream>>>(nrmbuf, knn32, 32,
                                                                  accum + 5);

    finalize_kernel<<<1, 1, 0, stream>>>(accum, (float*)d_out);
}